// Round 1
// baseline (588.754 us; speedup 1.0000x reference)
//
#include <hip/hip_runtime.h>
#include <math.h>

#define BB 2
#define TT 2048
#define DD 512
#define FF 2048
#define HH 8
#define HD 64
#define BT 4096      // BB*TT
#define NC 32        // TT/64 chunks
#define CK 64        // chunk size

// ---------------------------------------------------------------- LayerNorm
__global__ __launch_bounds__(256) void ln_kernel(const float* __restrict__ x,
                                                 const float* __restrict__ g,
                                                 const float* __restrict__ bb,
                                                 float* __restrict__ out) {
  int row = blockIdx.x;
  int t = threadIdx.x;
  const float* xr = x + (size_t)row * DD;
  float v0 = xr[t], v1 = xr[t + 256];
  float s = v0 + v1, sq = v0 * v0 + v1 * v1;
  for (int o = 32; o; o >>= 1) { s += __shfl_down(s, o); sq += __shfl_down(sq, o); }
  __shared__ float red[8];
  __shared__ float mv[2];
  int w = t >> 6;
  if ((t & 63) == 0) { red[w] = s; red[4 + w] = sq; }
  __syncthreads();
  if (t == 0) {
    float S = red[0] + red[1] + red[2] + red[3];
    float Q = red[4] + red[5] + red[6] + red[7];
    float m = S * (1.f / 512.f);
    float var = Q * (1.f / 512.f) - m * m;
    mv[0] = m; mv[1] = rsqrtf(var + 1e-5f);
  }
  __syncthreads();
  float m = mv[0], r = mv[1];
  out[(size_t)row * DD + t]       = (v0 - m) * r * g[t] + bb[t];
  out[(size_t)row * DD + t + 256] = (v1 - m) * r * g[t + 256] + bb[t + 256];
}

// ---------------------------------------------------------------- GEMM C = A * W^T
// A: [M,K] row-major; W: [N,K] row-major. 64x64 tile, 256 thr, 4x4 per thread.
// modes: 1=elu+1(Q) 2=elu+1*pad(K) 3=*pad(V) 4=+bias+resid 5=+bias,gelu
__global__ __launch_bounds__(256) void gemm_kernel(
    const float* __restrict__ A, const float* __restrict__ W, float* __restrict__ Cm,
    int M, int N, int K, int mode,
    const float* __restrict__ bias, const float* __restrict__ resid,
    const unsigned char* __restrict__ mask) {
  __shared__ __align__(16) float As[16][68];
  __shared__ __align__(16) float Ws[16][68];
  int tid = threadIdx.x;
  int n0 = blockIdx.x * 64, m0 = blockIdx.y * 64;
  int tx = tid & 15, ty = tid >> 4;
  int lm = tid >> 2, lk = (tid & 3) * 4;
  float acc[4][4] = {};
  const float* Ap = A + (size_t)(m0 + lm) * K + lk;
  const float* Wp = W + (size_t)(n0 + lm) * K + lk;
  for (int k0 = 0; k0 < K; k0 += 16) {
    float4 a4 = *(const float4*)(Ap + k0);
    float4 w4 = *(const float4*)(Wp + k0);
    __syncthreads();
    As[lk][lm] = a4.x; As[lk + 1][lm] = a4.y; As[lk + 2][lm] = a4.z; As[lk + 3][lm] = a4.w;
    Ws[lk][lm] = w4.x; Ws[lk + 1][lm] = w4.y; Ws[lk + 2][lm] = w4.z; Ws[lk + 3][lm] = w4.w;
    __syncthreads();
#pragma unroll
    for (int kk = 0; kk < 16; kk++) {
      float4 af = *(const float4*)&As[kk][ty * 4];
      float4 wf = *(const float4*)&Ws[kk][tx * 4];
      float ar[4] = {af.x, af.y, af.z, af.w};
      float wr[4] = {wf.x, wf.y, wf.z, wf.w};
#pragma unroll
      for (int r = 0; r < 4; r++)
#pragma unroll
        for (int c = 0; c < 4; c++) acc[r][c] += ar[r] * wr[c];
    }
  }
#pragma unroll
  for (int r = 0; r < 4; r++) {
    int row = m0 + ty * 4 + r;
    size_t rowoff = (size_t)row * N + n0 + tx * 4;
    float v[4];
#pragma unroll
    for (int c = 0; c < 4; c++) v[c] = acc[r][c];
    if (mode == 1) {
#pragma unroll
      for (int c = 0; c < 4; c++) v[c] = v[c] > 0.f ? v[c] + 1.f : expf(v[c]);
    } else if (mode == 2) {
      float p = mask[row] ? 0.f : 1.f;
#pragma unroll
      for (int c = 0; c < 4; c++) { float t = v[c] > 0.f ? v[c] + 1.f : expf(v[c]); v[c] = t * p; }
    } else if (mode == 3) {
      float p = mask[row] ? 0.f : 1.f;
#pragma unroll
      for (int c = 0; c < 4; c++) v[c] *= p;
    } else if (mode == 4) {
      float4 rs4 = *(const float4*)(resid + rowoff);
      float rr[4] = {rs4.x, rs4.y, rs4.z, rs4.w};
#pragma unroll
      for (int c = 0; c < 4; c++) v[c] += bias[n0 + tx * 4 + c] + rr[c];
    } else if (mode == 5) {
#pragma unroll
      for (int c = 0; c < 4; c++) {
        float t = v[c] + bias[n0 + tx * 4 + c];
        v[c] = 0.5f * t * (1.f + erff(t * 0.70710678118654752f));
      }
    }
    *(float4*)(Cm + rowoff) = make_float4(v[0], v[1], v[2], v[3]);
  }
}

// ------------------------------------------------- Phase A: chunk summaries
// P[e1][e2] = sum_j w_j k_j[e1] v_j[e2],  w_j = lam^(63-j) fwd / lam^j bwd
__global__ __launch_bounds__(256) void chunk_summary_kernel(
    const float* __restrict__ Kb, const float* __restrict__ Vb,
    const float* __restrict__ dl, float* __restrict__ Sst, float* __restrict__ zst) {
  int chunk = blockIdx.x, bh = blockIdx.y, dir = blockIdx.z;
  int b = bh >> 3, h = bh & 7;
  int t0 = chunk * CK;
  int tid = threadIdx.x;
  __shared__ __align__(16) float Ks[64][64];
  __shared__ __align__(16) float Vs[64][64];
  __shared__ float pw[72];
  float lam = 1.f / (1.f + expf(-dl[h]));
  if (tid <= 64) pw[tid] = powf(lam, (float)tid);
  int lrow = tid >> 2, lq = tid & 3;
  for (int q = 0; q < 4; q++) {
    int e = lq * 4 + q * 16;
    size_t g = ((size_t)(b * TT + t0 + lrow)) * DD + (size_t)h * 64 + e;
    *(float4*)&Ks[lrow][e] = *(const float4*)(Kb + g);
    *(float4*)&Vs[lrow][e] = *(const float4*)(Vb + g);
  }
  __syncthreads();
  int e1 = tid & 63;
  int e2b = (tid >> 6) * 16;
  float acc[16];
#pragma unroll
  for (int r = 0; r < 16; r++) acc[r] = 0.f;
  float zacc = 0.f;
  for (int j = 0; j < 64; j++) {
    float wgt = pw[dir == 0 ? 63 - j : j];
    float kv = wgt * Ks[j][e1];
    if (tid < 64) zacc += kv;
#pragma unroll
    for (int r = 0; r < 16; r++) acc[r] += kv * Vs[j][e2b + r];
  }
  size_t base = ((((size_t)dir * 16 + bh) * NC + chunk) * 64 + e1) * 64 + e2b;
#pragma unroll
  for (int r = 0; r < 16; r += 4)
    *(float4*)(Sst + base + r) = make_float4(acc[r], acc[r + 1], acc[r + 2], acc[r + 3]);
  if (tid < 64) zst[(((size_t)dir * 16 + bh) * NC + chunk) * 64 + tid] = zacc;
}

// ------------------------------------------------- Phase B: scan over chunks
__global__ __launch_bounds__(256) void scan_kernel(float* __restrict__ Sst,
                                                   float* __restrict__ zst,
                                                   const float* __restrict__ dl) {
  int bh = blockIdx.x, dir = blockIdx.y;
  int h = bh & 7;
  int tid = threadIdx.x;
  float lam = 1.f / (1.f + expf(-dl[h]));
  float lamC = powf(lam, 64.f);
  size_t base = ((size_t)dir * 16 + bh) * (size_t)NC * 4096 + (size_t)tid * 16;
  float S[16];
#pragma unroll
  for (int r = 0; r < 16; r++) S[r] = 0.f;
  for (int s = 0; s < NC; s++) {
    int c = dir ? (NC - 1 - s) : s;
    float* p = Sst + base + (size_t)c * 4096;
#pragma unroll
    for (int r = 0; r < 16; r++) { S[r] = S[r] * lamC + p[r]; p[r] = S[r]; }
  }
  if (tid < 64) {
    size_t zb = ((size_t)dir * 16 + bh) * (size_t)NC * 64 + tid;
    float z = 0.f;
    for (int s = 0; s < NC; s++) {
      int c = dir ? (NC - 1 - s) : s;
      float* p = zst + zb + (size_t)c * 64;
      z = z * lamC + *p; *p = z;
    }
  }
}

// ------------------------------------------------- Phase C: chunk attention
__global__ __launch_bounds__(256) void chunk_attn_kernel(
    const float* __restrict__ Qb, const float* __restrict__ Kb, const float* __restrict__ Vb,
    const float* __restrict__ Sst, const float* __restrict__ zst, const float* __restrict__ dl,
    float* __restrict__ Y0, float* __restrict__ Y1,
    float* __restrict__ C0, float* __restrict__ C1) {
  int chunk = blockIdx.x, bh = blockIdx.y, dir = blockIdx.z;
  int b = bh >> 3, h = bh & 7;
  int t0 = chunk * CK;
  int tid = threadIdx.x;
  __shared__ __align__(16) float Qt[64][68];   // transposed [d][i]
  __shared__ __align__(16) float Kt[64][68];   // transposed [d][j]; reused as Ast[j][i]
  __shared__ __align__(16) float Vs[64][64];   // [j][e]
  __shared__ __align__(16) float Sp[64][64];   // [d][e]
  __shared__ float rowpart[64][16];
  __shared__ float zp[64];
  __shared__ float pw[72];
  float lam = 1.f / (1.f + expf(-dl[h]));
  if (tid <= 64) pw[tid] = powf(lam, (float)tid);
  int lrow = tid >> 2, lq = tid & 3;
  for (int q = 0; q < 4; q++) {
    int e = lq * 4 + q * 16;
    size_t g = ((size_t)(b * TT + t0 + lrow)) * DD + (size_t)h * 64 + e;
    float4 q4 = *(const float4*)(Qb + g);
    float4 k4 = *(const float4*)(Kb + g);
    float4 v4 = *(const float4*)(Vb + g);
    Qt[e][lrow] = q4.x; Qt[e + 1][lrow] = q4.y; Qt[e + 2][lrow] = q4.z; Qt[e + 3][lrow] = q4.w;
    Kt[e][lrow] = k4.x; Kt[e + 1][lrow] = k4.y; Kt[e + 2][lrow] = k4.z; Kt[e + 3][lrow] = k4.w;
    *(float4*)&Vs[lrow][e] = v4;
  }
  int cs = dir ? chunk + 1 : chunk - 1;
  bool has = dir ? (chunk < NC - 1) : (chunk > 0);
  if (has) {
    size_t sb = (((size_t)dir * 16 + bh) * NC + cs) * 4096;
    for (int q = 0; q < 4; q++) {
      int e = lq * 4 + q * 16;
      *(float4*)&Sp[lrow][e] = *(const float4*)(Sst + sb + (size_t)lrow * 64 + e);
    }
    if (tid < 64) zp[tid] = zst[(((size_t)dir * 16 + bh) * NC + cs) * 64 + tid];
  } else {
    for (int q = 0; q < 4; q++) {
      int e = lq * 4 + q * 16;
      *(float4*)&Sp[lrow][e] = make_float4(0.f, 0.f, 0.f, 0.f);
    }
    if (tid < 64) zp[tid] = 0.f;
  }
  __syncthreads();
  int tx = tid & 15, ty = tid >> 4;
  int i0 = ty * 4, j0 = tx * 4;
  // ---- A = Q K^T over d
  float acc[4][4] = {};
  for (int d = 0; d < 64; d++) {
    float4 qf = *(const float4*)&Qt[d][i0];
    float4 kf = *(const float4*)&Kt[d][j0];
    float qa[4] = {qf.x, qf.y, qf.z, qf.w};
    float ka[4] = {kf.x, kf.y, kf.z, kf.w};
#pragma unroll
    for (int r = 0; r < 4; r++)
#pragma unroll
      for (int c = 0; c < 4; c++) acc[r][c] += qa[r] * ka[c];
  }
  __syncthreads();  // everyone done reading Kt
  // ---- decay mask, halve diagonal; store A^T into Kt as Ast[j][i]; row partials
  float rs[4] = {0.f, 0.f, 0.f, 0.f};
  float colv[4][4];
#pragma unroll
  for (int r = 0; r < 4; r++) {
    int i = i0 + r;
#pragma unroll
    for (int c = 0; c < 4; c++) {
      int j = j0 + c;
      float v;
      if (dir == 0) v = (j <= i) ? acc[r][c] * pw[i - j] : 0.f;
      else          v = (j >= i) ? acc[r][c] * pw[j - i] : 0.f;
      if (i == j) v *= 0.5f;
      rs[r] += v;
      colv[c][r] = v;
    }
  }
#pragma unroll
  for (int c = 0; c < 4; c++)
    *(float4*)&Kt[j0 + c][i0] = make_float4(colv[c][0], colv[c][1], colv[c][2], colv[c][3]);
#pragma unroll
  for (int r = 0; r < 4; r++) rowpart[i0 + r][tx] = rs[r];
  __syncthreads();
  // ---- Y = Ast^T V + diag(lam^row) (Q Sprev)
  int e0 = tx * 4;
  float accY[4][4] = {}, accS[4][4] = {};
  for (int j = 0; j < 64; j++) {
    float4 af = *(const float4*)&Kt[j][i0];
    float4 vf = *(const float4*)&Vs[j][e0];
    float aa[4] = {af.x, af.y, af.z, af.w};
    float vv[4] = {vf.x, vf.y, vf.z, vf.w};
#pragma unroll
    for (int r = 0; r < 4; r++)
#pragma unroll
      for (int c = 0; c < 4; c++) accY[r][c] += aa[r] * vv[c];
  }
  for (int d = 0; d < 64; d++) {
    float4 qf = *(const float4*)&Qt[d][i0];
    float4 sf = *(const float4*)&Sp[d][e0];
    float qq[4] = {qf.x, qf.y, qf.z, qf.w};
    float ss[4] = {sf.x, sf.y, sf.z, sf.w};
#pragma unroll
    for (int r = 0; r < 4; r++)
#pragma unroll
      for (int c = 0; c < 4; c++) accS[r][c] += qq[r] * ss[c];
  }
  float* Yb = dir ? Y1 : Y0;
#pragma unroll
  for (int r = 0; r < 4; r++) {
    int i = i0 + r;
    float lr = dir ? pw[64 - i] : pw[i + 1];
    float4 o = make_float4(accY[r][0] + lr * accS[r][0], accY[r][1] + lr * accS[r][1],
                           accY[r][2] + lr * accS[r][2], accY[r][3] + lr * accS[r][3]);
    *(float4*)(Yb + ((size_t)(b * TT + t0 + i)) * DD + (size_t)h * 64 + e0) = o;
  }
  // ---- c_i = rowsum(A'') + lam^row * (q_i . z_prev)
  if (tid < 64) {
    int i = tid;
    float s = 0.f;
#pragma unroll
    for (int xx = 0; xx < 16; xx++) s += rowpart[i][xx];
    float cz = 0.f;
    for (int d = 0; d < 64; d++) cz += Qt[d][i] * zp[d];
    float lr = dir ? pw[64 - i] : pw[i + 1];
    s += lr * cz;
    float* Cb = dir ? C1 : C0;
    Cb[((size_t)(b * TT + t0 + i)) * HH + h] = s;
  }
}

// ---------------------------------------------------------------- combine
__global__ __launch_bounds__(256) void combine_kernel(
    const float* __restrict__ Y0, const float* __restrict__ Y1,
    const float* __restrict__ C0, const float* __restrict__ C1,
    float* __restrict__ attn) {
  size_t idx = ((size_t)blockIdx.x * 256 + threadIdx.x) * 4;
  size_t bt = idx >> 9;
  int o = (int)(idx & 511);
  int h = o >> 6;
  float den = C0[bt * HH + h] + C1[bt * HH + h];
  den = fmaxf(den, 1e-6f);
  float4 y0 = *(const float4*)(Y0 + idx);
  float4 y1 = *(const float4*)(Y1 + idx);
  float4 r = make_float4((y0.x + y1.x) / den, (y0.y + y1.y) / den,
                         (y0.z + y1.z) / den, (y0.w + y1.w) / den);
  *(float4*)(attn + idx) = r;
}

// ---------------------------------------------------------------- launch
extern "C" void kernel_launch(void* const* d_in, const int* in_sizes, int n_in,
                              void* d_out, int out_size, void* d_ws, size_t ws_size,
                              hipStream_t stream) {
  const float* x   = (const float*)d_in[0];
  const unsigned char* mask = (const unsigned char*)d_in[1];
  const float* Wq  = (const float*)d_in[2];
  const float* Wk  = (const float*)d_in[3];
  const float* Wv  = (const float*)d_in[4];
  const float* Wo  = (const float*)d_in[5];
  const float* bo  = (const float*)d_in[6];
  const float* g1  = (const float*)d_in[7];
  const float* b1  = (const float*)d_in[8];
  const float* g2  = (const float*)d_in[9];
  const float* b2  = (const float*)d_in[10];
  const float* W1  = (const float*)d_in[11];
  const float* bf1 = (const float*)d_in[12];
  const float* W2  = (const float*)d_in[13];
  const float* bf2 = (const float*)d_in[14];
  const float* dl  = (const float*)d_in[15];
  float* out = (float*)d_out;

  float* ws = (float*)d_ws;
  const size_t U = (size_t)BT * DD;  // 2097152 floats
  float* xn  = ws;            // reused as attn after projections
  float* Q   = ws + U;        // reused as h2 after recurrence
  float* Kb  = ws + 2 * U;
  float* Vb  = ws + 3 * U;
  float* Y0  = ws + 4 * U;
  float* Y1  = ws + 5 * U;
  float* x2  = ws + 6 * U;
  float* Sst = ws + 7 * U;                 // 2U floats
  float* zst = ws + 9 * U;                 // 65536
  float* C0  = ws + 9 * U + 65536;         // 32768
  float* C1  = C0 + 32768;                 // 32768
  float* ffn1 = ws + 2 * U;                // overlays Kb,Vb,Y0,Y1 (dead by then)
  float* attn = xn;
  float* h2 = Q;

  ln_kernel<<<BT, 256, 0, stream>>>(x, g1, b1, xn);
  gemm_kernel<<<dim3(8, 64), 256, 0, stream>>>(xn, Wq, Q,  BT, DD, DD, 1, nullptr, nullptr, nullptr);
  gemm_kernel<<<dim3(8, 64), 256, 0, stream>>>(xn, Wk, Kb, BT, DD, DD, 2, nullptr, nullptr, mask);
  gemm_kernel<<<dim3(8, 64), 256, 0, stream>>>(xn, Wv, Vb, BT, DD, DD, 3, nullptr, nullptr, mask);
  chunk_summary_kernel<<<dim3(NC, 16, 2), 256, 0, stream>>>(Kb, Vb, dl, Sst, zst);
  scan_kernel<<<dim3(16, 2), 256, 0, stream>>>(Sst, zst, dl);
  chunk_attn_kernel<<<dim3(NC, 16, 2), 256, 0, stream>>>(Q, Kb, Vb, Sst, zst, dl, Y0, Y1, C0, C1);
  combine_kernel<<<(BT * DD) / 1024, 256, 0, stream>>>(Y0, Y1, C0, C1, attn);
  gemm_kernel<<<dim3(8, 64), 256, 0, stream>>>(attn, Wo, x2, BT, DD, DD, 4, bo, x, nullptr);
  ln_kernel<<<BT, 256, 0, stream>>>(x2, g2, b2, h2);
  gemm_kernel<<<dim3(32, 64), 256, 0, stream>>>(h2, W1, ffn1, BT, FF, DD, 5, bf1, nullptr, nullptr);
  gemm_kernel<<<dim3(8, 64), 256, 0, stream>>>(ffn1, W2, out, BT, DD, FF, 4, bf2, x2, nullptr);
}

// Round 2
// 295.736 us; speedup vs baseline: 1.9908x; 1.9908x over previous
//
#include <hip/hip_runtime.h>
#include <math.h>

#define BB 2
#define TT 2048
#define DD 512
#define FF 2048
#define HH 8
#define BT 4096      // BB*TT
#define NC 32        // TT/64 chunks
#define CK 64        // chunk size

typedef __bf16 bf16_t;
typedef bf16_t bf16x8 __attribute__((ext_vector_type(8)));
typedef bf16_t bf16x4 __attribute__((ext_vector_type(4)));
typedef float f32x4 __attribute__((ext_vector_type(4)));

typedef const __attribute__((address_space(1))) void* gas_p;
typedef __attribute__((address_space(3))) void* las_p;

__device__ __forceinline__ void async16(const void* g, void* l) {
  __builtin_amdgcn_global_load_lds((gas_p)g, (las_p)l, 16, 0, 0);
}

// ---------------------------------------------------------------- LayerNorm (fp32 in, bf16 out)
__global__ __launch_bounds__(256) void ln_kernel(const float* __restrict__ x,
                                                 const float* __restrict__ g,
                                                 const float* __restrict__ bb,
                                                 bf16_t* __restrict__ out) {
  int row = blockIdx.x;
  int t = threadIdx.x;
  const float* xr = x + (size_t)row * DD;
  float v0 = xr[t], v1 = xr[t + 256];
  float s = v0 + v1, sq = v0 * v0 + v1 * v1;
  for (int o = 32; o; o >>= 1) { s += __shfl_down(s, o); sq += __shfl_down(sq, o); }
  __shared__ float red[8];
  __shared__ float mv[2];
  int w = t >> 6;
  if ((t & 63) == 0) { red[w] = s; red[4 + w] = sq; }
  __syncthreads();
  if (t == 0) {
    float S = red[0] + red[1] + red[2] + red[3];
    float Q = red[4] + red[5] + red[6] + red[7];
    float m = S * (1.f / 512.f);
    float var = Q * (1.f / 512.f) - m * m;
    mv[0] = m; mv[1] = rsqrtf(var + 1e-5f);
  }
  __syncthreads();
  float m = mv[0], r = mv[1];
  out[(size_t)row * DD + t]       = (bf16_t)((v0 - m) * r * g[t] + bb[t]);
  out[(size_t)row * DD + t + 256] = (bf16_t)((v1 - m) * r * g[t + 256] + bb[t + 256]);
}

// ---------------------------------------------------------------- weight cast fp32 -> bf16
// concat layout: Wq(262144) Wk Wv Wo W1(1048576) W2(1048576)
__global__ __launch_bounds__(256) void cast_weights(
    const float* __restrict__ Wq, const float* __restrict__ Wk,
    const float* __restrict__ Wv, const float* __restrict__ Wo,
    const float* __restrict__ W1, const float* __restrict__ W2,
    bf16_t* __restrict__ dst) {
  size_t i = ((size_t)blockIdx.x * 256 + threadIdx.x) * 8;
  const float* src; size_t off;
  if (i < 262144)       { src = Wq; off = i; }
  else if (i < 524288)  { src = Wk; off = i - 262144; }
  else if (i < 786432)  { src = Wv; off = i - 524288; }
  else if (i < 1048576) { src = Wo; off = i - 786432; }
  else if (i < 2097152) { src = W1; off = i - 1048576; }
  else                  { src = W2; off = i - 2097152; }
  float4 a = *(const float4*)(src + off);
  float4 b = *(const float4*)(src + off + 4);
  bf16x8 o;
  o[0] = (bf16_t)a.x; o[1] = (bf16_t)a.y; o[2] = (bf16_t)a.z; o[3] = (bf16_t)a.w;
  o[4] = (bf16_t)b.x; o[5] = (bf16_t)b.y; o[6] = (bf16_t)b.z; o[7] = (bf16_t)b.w;
  *(bf16x8*)(dst + i) = o;
}

// ---------------------------------------------------------------- MFMA GEMM  C = A * B^T
// A: [M,K] bf16 row-major; B: [N,K] bf16 row-major. 128x128 tile, BK=32, 256 thr.
// MODE 0: QKV fused epilogue (N=1536 -> Q/K/V fp32, elu+1 / pad)
// MODE 1: fp32 out = acc + bias[n] + resid   (N=512)
// MODE 2: bf16 out = gelu(acc + bias[n])     (N=2048)
template<int MODE>
__global__ __launch_bounds__(256) void mfma_gemm(
    const bf16_t* __restrict__ A, const bf16_t* __restrict__ B, int K,
    float* __restrict__ O0, float* __restrict__ O1, float* __restrict__ O2,
    bf16_t* __restrict__ Ob, const float* __restrict__ bias,
    const float* __restrict__ resid, const unsigned char* __restrict__ mask) {
  __shared__ __align__(16) bf16_t As[4096];
  __shared__ __align__(16) bf16_t Bs[4096];
  int tid = threadIdx.x;
  int n0 = blockIdx.x * 128, m0 = blockIdx.y * 128;
  int elt = tid * 8;
  int srow = elt >> 5, scol = elt & 31;
  const bf16_t* Ag = A + (size_t)(m0 + srow) * K + scol;
  const bf16_t* Bg = B + (size_t)(n0 + srow) * K + scol;
  size_t hstep = (size_t)64 * K;
  f32x4 acc[4][4] = {};
  int w = tid >> 6, l = tid & 63;
  int wm = (w >> 1) * 64, wn = (w & 1) * 64;
  int fr = l & 15, fk = (l >> 4) * 8;
  for (int k0 = 0; k0 < K; k0 += 32) {
    __syncthreads();
    async16(Ag + k0, As + elt);
    async16(Ag + k0 + hstep, As + 2048 + elt);
    async16(Bg + k0, Bs + elt);
    async16(Bg + k0 + hstep, Bs + 2048 + elt);
    __syncthreads();
    bf16x8 af[4], bfr[4];
#pragma unroll
    for (int i = 0; i < 4; i++) af[i] = *(const bf16x8*)&As[(wm + i * 16 + fr) * 32 + fk];
#pragma unroll
    for (int j = 0; j < 4; j++) bfr[j] = *(const bf16x8*)&Bs[(wn + j * 16 + fr) * 32 + fk];
#pragma unroll
    for (int i = 0; i < 4; i++)
#pragma unroll
      for (int j = 0; j < 4; j++)
        acc[i][j] = __builtin_amdgcn_mfma_f32_16x16x32_bf16(af[i], bfr[j], acc[i][j], 0, 0, 0);
  }
  int cn = l & 15, cr = (l >> 4) * 4;
#pragma unroll
  for (int i = 0; i < 4; i++) {
#pragma unroll
    for (int r = 0; r < 4; r++) {
      int m = m0 + wm + i * 16 + cr + r;
#pragma unroll
      for (int j = 0; j < 4; j++) {
        int n = n0 + wn + j * 16 + cn;
        float v = acc[i][j][r];
        if (MODE == 0) {
          float p = mask[m] ? 0.f : 1.f;
          int seg = n >> 9, nn = n & 511;
          size_t o = (size_t)m * 512 + nn;
          if (seg == 0)      O0[o] = v > 0.f ? v + 1.f : expf(v);
          else if (seg == 1) O1[o] = (v > 0.f ? v + 1.f : expf(v)) * p;
          else               O2[o] = v * p;
        } else if (MODE == 1) {
          size_t o = (size_t)m * 512 + n;
          O0[o] = v + bias[n] + resid[o];
        } else {
          float t = v + bias[n];
          Ob[(size_t)m * 2048 + n] = (bf16_t)(0.5f * t * (1.f + erff(t * 0.70710678118654752f)));
        }
      }
    }
  }
}

// ------------------------------------------------- Phase A: chunk summaries
__global__ __launch_bounds__(256) void chunk_summary_kernel(
    const float* __restrict__ Kb, const float* __restrict__ Vb,
    const float* __restrict__ dl, float* __restrict__ Sst, float* __restrict__ zst) {
  int chunk = blockIdx.x, bh = blockIdx.y, dir = blockIdx.z;
  int b = bh >> 3, h = bh & 7;
  int t0 = chunk * CK;
  int tid = threadIdx.x;
  __shared__ __align__(16) float Ks[64][64];
  __shared__ __align__(16) float Vs[64][64];
  __shared__ float pw[72];
  float lam = 1.f / (1.f + expf(-dl[h]));
  if (tid <= 64) pw[tid] = powf(lam, (float)tid);
  int lrow = tid >> 2, lq = tid & 3;
  for (int q = 0; q < 4; q++) {
    int e = lq * 4 + q * 16;
    size_t g = ((size_t)(b * TT + t0 + lrow)) * DD + (size_t)h * 64 + e;
    *(float4*)&Ks[lrow][e] = *(const float4*)(Kb + g);
    *(float4*)&Vs[lrow][e] = *(const float4*)(Vb + g);
  }
  __syncthreads();
  int e1 = tid & 63;
  int e2b = (tid >> 6) * 16;
  float acc[16];
#pragma unroll
  for (int r = 0; r < 16; r++) acc[r] = 0.f;
  float zacc = 0.f;
  for (int j = 0; j < 64; j++) {
    float wgt = pw[dir == 0 ? 63 - j : j];
    float kv = wgt * Ks[j][e1];
    if (tid < 64) zacc += kv;
#pragma unroll
    for (int r = 0; r < 16; r++) acc[r] += kv * Vs[j][e2b + r];
  }
  size_t base = ((((size_t)dir * 16 + bh) * NC + chunk) * 64 + e1) * 64 + e2b;
#pragma unroll
  for (int r = 0; r < 16; r += 4)
    *(float4*)(Sst + base + r) = make_float4(acc[r], acc[r + 1], acc[r + 2], acc[r + 3]);
  if (tid < 64) zst[(((size_t)dir * 16 + bh) * NC + chunk) * 64 + tid] = zacc;
}

// ------------------------------------------------- Phase B: scan over chunks
__global__ __launch_bounds__(256) void scan_kernel(float* __restrict__ Sst,
                                                   float* __restrict__ zst,
                                                   const float* __restrict__ dl) {
  int bh = blockIdx.x, dir = blockIdx.y;
  int h = bh & 7;
  int tid = threadIdx.x;
  float lam = 1.f / (1.f + expf(-dl[h]));
  float lamC = powf(lam, 64.f);
  size_t base = ((size_t)dir * 16 + bh) * (size_t)NC * 4096 + (size_t)tid * 16;
  float S[16];
#pragma unroll
  for (int r = 0; r < 16; r++) S[r] = 0.f;
  for (int s = 0; s < NC; s++) {
    int c = dir ? (NC - 1 - s) : s;
    float* p = Sst + base + (size_t)c * 4096;
#pragma unroll
    for (int r = 0; r < 16; r++) { S[r] = S[r] * lamC + p[r]; p[r] = S[r]; }
  }
  if (tid < 64) {
    size_t zb = ((size_t)dir * 16 + bh) * (size_t)NC * 64 + tid;
    float z = 0.f;
    for (int s = 0; s < NC; s++) {
      int c = dir ? (NC - 1 - s) : s;
      float* p = zst + zb + (size_t)c * 64;
      z = z * lamC + *p; *p = z;
    }
  }
}

// ------------------------------------------------- Phase C: chunk attention
__global__ __launch_bounds__(256) void chunk_attn_kernel(
    const float* __restrict__ Qb, const float* __restrict__ Kb, const float* __restrict__ Vb,
    const float* __restrict__ Sst, const float* __restrict__ zst, const float* __restrict__ dl,
    float* __restrict__ Y0, float* __restrict__ Y1,
    float* __restrict__ C0, float* __restrict__ C1) {
  int chunk = blockIdx.x, bh = blockIdx.y, dir = blockIdx.z;
  int b = bh >> 3, h = bh & 7;
  int t0 = chunk * CK;
  int tid = threadIdx.x;
  __shared__ __align__(16) float Qt[64][68];   // transposed [d][i]
  __shared__ __align__(16) float Kt[64][68];   // transposed [d][j]; reused as Ast[j][i]
  __shared__ __align__(16) float Vs[64][64];   // [j][e]
  __shared__ __align__(16) float Sp[64][64];   // [d][e]
  __shared__ float rowpart[64][16];
  __shared__ float zp[64];
  __shared__ float pw[72];
  float lam = 1.f / (1.f + expf(-dl[h]));
  if (tid <= 64) pw[tid] = powf(lam, (float)tid);
  int lrow = tid >> 2, lq = tid & 3;
  for (int q = 0; q < 4; q++) {
    int e = lq * 4 + q * 16;
    size_t g = ((size_t)(b * TT + t0 + lrow)) * DD + (size_t)h * 64 + e;
    float4 q4 = *(const float4*)(Qb + g);
    float4 k4 = *(const float4*)(Kb + g);
    float4 v4 = *(const float4*)(Vb + g);
    Qt[e][lrow] = q4.x; Qt[e + 1][lrow] = q4.y; Qt[e + 2][lrow] = q4.z; Qt[e + 3][lrow] = q4.w;
    Kt[e][lrow] = k4.x; Kt[e + 1][lrow] = k4.y; Kt[e + 2][lrow] = k4.z; Kt[e + 3][lrow] = k4.w;
    *(float4*)&Vs[lrow][e] = v4;
  }
  int cs = dir ? chunk + 1 : chunk - 1;
  bool has = dir ? (chunk < NC - 1) : (chunk > 0);
  if (has) {
    size_t sb = (((size_t)dir * 16 + bh) * NC + cs) * 4096;
    for (int q = 0; q < 4; q++) {
      int e = lq * 4 + q * 16;
      *(float4*)&Sp[lrow][e] = *(const float4*)(Sst + sb + (size_t)lrow * 64 + e);
    }
    if (tid < 64) zp[tid] = zst[(((size_t)dir * 16 + bh) * NC + cs) * 64 + tid];
  } else {
    for (int q = 0; q < 4; q++) {
      int e = lq * 4 + q * 16;
      *(float4*)&Sp[lrow][e] = make_float4(0.f, 0.f, 0.f, 0.f);
    }
    if (tid < 64) zp[tid] = 0.f;
  }
  __syncthreads();
  int tx = tid & 15, ty = tid >> 4;
  int i0 = ty * 4, j0 = tx * 4;
  // ---- A = Q K^T over d
  float acc[4][4] = {};
  for (int d = 0; d < 64; d++) {
    float4 qf = *(const float4*)&Qt[d][i0];
    float4 kf = *(const float4*)&Kt[d][j0];
    float qa[4] = {qf.x, qf.y, qf.z, qf.w};
    float ka[4] = {kf.x, kf.y, kf.z, kf.w};
#pragma unroll
    for (int r = 0; r < 4; r++)
#pragma unroll
      for (int c = 0; c < 4; c++) acc[r][c] += qa[r] * ka[c];
  }
  __syncthreads();
  float rs[4] = {0.f, 0.f, 0.f, 0.f};
  float colv[4][4];
#pragma unroll
  for (int r = 0; r < 4; r++) {
    int i = i0 + r;
#pragma unroll
    for (int c = 0; c < 4; c++) {
      int j = j0 + c;
      float v;
      if (dir == 0) v = (j <= i) ? acc[r][c] * pw[i - j] : 0.f;
      else          v = (j >= i) ? acc[r][c] * pw[j - i] : 0.f;
      if (i == j) v *= 0.5f;
      rs[r] += v;
      colv[c][r] = v;
    }
  }
#pragma unroll
  for (int c = 0; c < 4; c++)
    *(float4*)&Kt[j0 + c][i0] = make_float4(colv[c][0], colv[c][1], colv[c][2], colv[c][3]);
#pragma unroll
  for (int r = 0; r < 4; r++) rowpart[i0 + r][tx] = rs[r];
  __syncthreads();
  int e0 = tx * 4;
  float accY[4][4] = {}, accS[4][4] = {};
  for (int j = 0; j < 64; j++) {
    float4 af = *(const float4*)&Kt[j][i0];
    float4 vf = *(const float4*)&Vs[j][e0];
    float aa[4] = {af.x, af.y, af.z, af.w};
    float vv[4] = {vf.x, vf.y, vf.z, vf.w};
#pragma unroll
    for (int r = 0; r < 4; r++)
#pragma unroll
      for (int c = 0; c < 4; c++) accY[r][c] += aa[r] * vv[c];
  }
  for (int d = 0; d < 64; d++) {
    float4 qf = *(const float4*)&Qt[d][i0];
    float4 sf = *(const float4*)&Sp[d][e0];
    float qq[4] = {qf.x, qf.y, qf.z, qf.w};
    float ss[4] = {sf.x, sf.y, sf.z, sf.w};
#pragma unroll
    for (int r = 0; r < 4; r++)
#pragma unroll
      for (int c = 0; c < 4; c++) accS[r][c] += qq[r] * ss[c];
  }
  float* Yb = dir ? Y1 : Y0;
#pragma unroll
  for (int r = 0; r < 4; r++) {
    int i = i0 + r;
    float lr = dir ? pw[64 - i] : pw[i + 1];
    float4 o = make_float4(accY[r][0] + lr * accS[r][0], accY[r][1] + lr * accS[r][1],
                           accY[r][2] + lr * accS[r][2], accY[r][3] + lr * accS[r][3]);
    *(float4*)(Yb + ((size_t)(b * TT + t0 + i)) * DD + (size_t)h * 64 + e0) = o;
  }
  if (tid < 64) {
    int i = tid;
    float s = 0.f;
#pragma unroll
    for (int xx = 0; xx < 16; xx++) s += rowpart[i][xx];
    float cz = 0.f;
    for (int d = 0; d < 64; d++) cz += Qt[d][i] * zp[d];
    float lr = dir ? pw[64 - i] : pw[i + 1];
    s += lr * cz;
    float* Cb = dir ? C1 : C0;
    Cb[((size_t)(b * TT + t0 + i)) * HH + h] = s;
  }
}

// ---------------------------------------------------------------- combine (fp32 in, bf16 out)
__global__ __launch_bounds__(256) void combine_kernel(
    const float* __restrict__ Y0, const float* __restrict__ Y1,
    const float* __restrict__ C0, const float* __restrict__ C1,
    bf16_t* __restrict__ attn) {
  size_t idx = ((size_t)blockIdx.x * 256 + threadIdx.x) * 4;
  size_t bt = idx >> 9;
  int o = (int)(idx & 511);
  int h = o >> 6;
  float den = C0[bt * HH + h] + C1[bt * HH + h];
  den = fmaxf(den, 1e-6f);
  float4 y0 = *(const float4*)(Y0 + idx);
  float4 y1 = *(const float4*)(Y1 + idx);
  bf16x4 r;
  r[0] = (bf16_t)((y0.x + y1.x) / den);
  r[1] = (bf16_t)((y0.y + y1.y) / den);
  r[2] = (bf16_t)((y0.z + y1.z) / den);
  r[3] = (bf16_t)((y0.w + y1.w) / den);
  *(bf16x4*)(attn + idx) = r;
}

// ---------------------------------------------------------------- launch
extern "C" void kernel_launch(void* const* d_in, const int* in_sizes, int n_in,
                              void* d_out, int out_size, void* d_ws, size_t ws_size,
                              hipStream_t stream) {
  const float* x   = (const float*)d_in[0];
  const unsigned char* mask = (const unsigned char*)d_in[1];
  const float* Wq  = (const float*)d_in[2];
  const float* Wk  = (const float*)d_in[3];
  const float* Wv  = (const float*)d_in[4];
  const float* Wo  = (const float*)d_in[5];
  const float* bo  = (const float*)d_in[6];
  const float* g1  = (const float*)d_in[7];
  const float* b1  = (const float*)d_in[8];
  const float* g2  = (const float*)d_in[9];
  const float* b2  = (const float*)d_in[10];
  const float* W1  = (const float*)d_in[11];
  const float* bf1 = (const float*)d_in[12];
  const float* W2  = (const float*)d_in[13];
  const float* bf2 = (const float*)d_in[14];
  const float* dl  = (const float*)d_in[15];
  float* out = (float*)d_out;

  float* ws = (float*)d_ws;
  const size_t U = (size_t)BT * DD;  // 2097152 floats
  float* Qf  = ws;
  float* Kf  = ws + U;
  float* Vf  = ws + 2 * U;
  float* Y0  = ws + 3 * U;
  float* Y1  = ws + 4 * U;
  float* x2  = ws + 5 * U;
  float* Sst = ws + 6 * U;                 // 2U floats
  float* zst = ws + 8 * U;                 // 65536
  float* C0  = ws + 8 * U + 65536;         // 32768
  float* C1  = C0 + 32768;                 // 32768
  bf16_t* wall  = (bf16_t*)(ws + 8 * U + 131072);  // 3145728 bf16
  // bf16 overlays on dead fp32 regions:
  bf16_t* xnb   = (bf16_t*)Y0;   // live: ln1 .. QKV gemm (Y0 written later)
  bf16_t* attnb = (bf16_t*)Vf;   // live: combine .. Wo gemm (Vf dead after chunk_attn)
  bf16_t* h2b   = (bf16_t*)Qf;   // live: ln2 .. FFN1 (Qf dead)
  bf16_t* ffn1b = (bf16_t*)Kf;   // 8M bf16 spans Kf+Vf (both dead)
  bf16_t* Wob = wall + 786432;
  bf16_t* W1b = wall + 1048576;
  bf16_t* W2b = wall + 2097152;

  cast_weights<<<1536, 256, 0, stream>>>(Wq, Wk, Wv, Wo, W1, W2, wall);
  ln_kernel<<<BT, 256, 0, stream>>>(x, g1, b1, xnb);
  mfma_gemm<0><<<dim3(12, 32), 256, 0, stream>>>(xnb, wall, 512, Qf, Kf, Vf,
                                                 nullptr, nullptr, nullptr, mask);
  chunk_summary_kernel<<<dim3(NC, 16, 2), 256, 0, stream>>>(Kf, Vf, dl, Sst, zst);
  scan_kernel<<<dim3(16, 2), 256, 0, stream>>>(Sst, zst, dl);
  chunk_attn_kernel<<<dim3(NC, 16, 2), 256, 0, stream>>>(Qf, Kf, Vf, Sst, zst, dl, Y0, Y1, C0, C1);
  combine_kernel<<<2048, 256, 0, stream>>>(Y0, Y1, C0, C1, attnb);
  mfma_gemm<1><<<dim3(4, 32), 256, 0, stream>>>(attnb, Wob, 512, x2,
                                                nullptr, nullptr, nullptr, bo, x, nullptr);
  ln_kernel<<<BT, 256, 0, stream>>>(x2, g2, b2, h2b);
  mfma_gemm<2><<<dim3(16, 32), 256, 0, stream>>>(h2b, W1b, 512, nullptr,
                                                 nullptr, nullptr, ffn1b, bf1, nullptr, nullptr);
  mfma_gemm<1><<<dim3(4, 32), 256, 0, stream>>>(ffn1b, W2b, 2048, out,
                                                nullptr, nullptr, nullptr, bf2, x2, nullptr);
}

// Round 3
// 284.215 us; speedup vs baseline: 2.0715x; 1.0405x over previous
//
#include <hip/hip_runtime.h>
#include <math.h>

#define BB 2
#define TT 2048
#define DD 512
#define FF 2048
#define HH 8
#define BT 4096      // BB*TT
#define NC 32        // TT/64 chunks
#define CK 64        // chunk size

typedef __bf16 bf16_t;
typedef bf16_t bf16x8 __attribute__((ext_vector_type(8)));
typedef bf16_t bf16x4 __attribute__((ext_vector_type(4)));
typedef float f32x4 __attribute__((ext_vector_type(4)));

typedef const __attribute__((address_space(1))) void* gas_p;
typedef __attribute__((address_space(3))) void* las_p;

__device__ __forceinline__ void async16(const void* g, void* l) {
  __builtin_amdgcn_global_load_lds((gas_p)g, (las_p)l, 16, 0, 0);
}

// ---------------------------------------------------------------- LayerNorm (fp32 in, bf16 out)
__global__ __launch_bounds__(256) void ln_kernel(const float* __restrict__ x,
                                                 const float* __restrict__ g,
                                                 const float* __restrict__ bb,
                                                 bf16_t* __restrict__ out) {
  int row = blockIdx.x;
  int t = threadIdx.x;
  const float* xr = x + (size_t)row * DD;
  float v0 = xr[t], v1 = xr[t + 256];
  float s = v0 + v1, sq = v0 * v0 + v1 * v1;
  for (int o = 32; o; o >>= 1) { s += __shfl_down(s, o); sq += __shfl_down(sq, o); }
  __shared__ float red[8];
  __shared__ float mv[2];
  int w = t >> 6;
  if ((t & 63) == 0) { red[w] = s; red[4 + w] = sq; }
  __syncthreads();
  if (t == 0) {
    float S = red[0] + red[1] + red[2] + red[3];
    float Q = red[4] + red[5] + red[6] + red[7];
    float m = S * (1.f / 512.f);
    float var = Q * (1.f / 512.f) - m * m;
    mv[0] = m; mv[1] = rsqrtf(var + 1e-5f);
  }
  __syncthreads();
  float m = mv[0], r = mv[1];
  out[(size_t)row * DD + t]       = (bf16_t)((v0 - m) * r * g[t] + bb[t]);
  out[(size_t)row * DD + t + 256] = (bf16_t)((v1 - m) * r * g[t + 256] + bb[t + 256]);
}

// ---------------------------------------------------------------- weight cast fp32 -> bf16
__global__ __launch_bounds__(256) void cast_weights(
    const float* __restrict__ Wq, const float* __restrict__ Wk,
    const float* __restrict__ Wv, const float* __restrict__ Wo,
    const float* __restrict__ W1, const float* __restrict__ W2,
    bf16_t* __restrict__ dst) {
  size_t i = ((size_t)blockIdx.x * 256 + threadIdx.x) * 8;
  const float* src; size_t off;
  if (i < 262144)       { src = Wq; off = i; }
  else if (i < 524288)  { src = Wk; off = i - 262144; }
  else if (i < 786432)  { src = Wv; off = i - 524288; }
  else if (i < 1048576) { src = Wo; off = i - 786432; }
  else if (i < 2097152) { src = W1; off = i - 1048576; }
  else                  { src = W2; off = i - 2097152; }
  float4 a = *(const float4*)(src + off);
  float4 b = *(const float4*)(src + off + 4);
  bf16x8 o;
  o[0] = (bf16_t)a.x; o[1] = (bf16_t)a.y; o[2] = (bf16_t)a.z; o[3] = (bf16_t)a.w;
  o[4] = (bf16_t)b.x; o[5] = (bf16_t)b.y; o[6] = (bf16_t)b.z; o[7] = (bf16_t)b.w;
  *(bf16x8*)(dst + i) = o;
}

// ---------------------------------------------------------------- MFMA GEMM  C = A * B^T
// 128x128 tile, BK=32, 256 thr.
// MODE 0: QKV fused epilogue (N=1536 -> Q/K/V fp32, elu+1 / pad)
// MODE 2: bf16 out = gelu(acc + bias[n])     (N=2048)
template<int MODE>
__global__ __launch_bounds__(256) void mfma_gemm(
    const bf16_t* __restrict__ A, const bf16_t* __restrict__ B, int K,
    float* __restrict__ O0, float* __restrict__ O1, float* __restrict__ O2,
    bf16_t* __restrict__ Ob, const float* __restrict__ bias,
    const unsigned char* __restrict__ mask) {
  __shared__ __align__(16) bf16_t As[4096];
  __shared__ __align__(16) bf16_t Bs[4096];
  int tid = threadIdx.x;
  int n0 = blockIdx.x * 128, m0 = blockIdx.y * 128;
  int elt = tid * 8;
  int srow = elt >> 5, scol = elt & 31;
  const bf16_t* Ag = A + (size_t)(m0 + srow) * K + scol;
  const bf16_t* Bg = B + (size_t)(n0 + srow) * K + scol;
  size_t hstep = (size_t)64 * K;
  f32x4 acc[4][4] = {};
  int w = tid >> 6, l = tid & 63;
  int wm = (w >> 1) * 64, wn = (w & 1) * 64;
  int fr = l & 15, fk = (l >> 4) * 8;
  for (int k0 = 0; k0 < K; k0 += 32) {
    __syncthreads();
    async16(Ag + k0, As + elt);
    async16(Ag + k0 + hstep, As + 2048 + elt);
    async16(Bg + k0, Bs + elt);
    async16(Bg + k0 + hstep, Bs + 2048 + elt);
    __syncthreads();
    bf16x8 af[4], bfr[4];
#pragma unroll
    for (int i = 0; i < 4; i++) af[i] = *(const bf16x8*)&As[(wm + i * 16 + fr) * 32 + fk];
#pragma unroll
    for (int j = 0; j < 4; j++) bfr[j] = *(const bf16x8*)&Bs[(wn + j * 16 + fr) * 32 + fk];
#pragma unroll
    for (int i = 0; i < 4; i++)
#pragma unroll
      for (int j = 0; j < 4; j++)
        acc[i][j] = __builtin_amdgcn_mfma_f32_16x16x32_bf16(af[i], bfr[j], acc[i][j], 0, 0, 0);
  }
  int cn = l & 15, cr = (l >> 4) * 4;
#pragma unroll
  for (int i = 0; i < 4; i++) {
#pragma unroll
    for (int r = 0; r < 4; r++) {
      int m = m0 + wm + i * 16 + cr + r;
#pragma unroll
      for (int j = 0; j < 4; j++) {
        int n = n0 + wn + j * 16 + cn;
        float v = acc[i][j][r];
        if (MODE == 0) {
          float p = mask[m] ? 0.f : 1.f;
          int seg = n >> 9, nn = n & 511;
          size_t o = (size_t)m * 512 + nn;
          if (seg == 0)      O0[o] = v > 0.f ? v + 1.f : expf(v);
          else if (seg == 1) O1[o] = (v > 0.f ? v + 1.f : expf(v)) * p;
          else               O2[o] = v * p;
        } else {
          float t = v + bias[n];
          Ob[(size_t)m * 2048 + n] = (bf16_t)(0.5f * t * (1.f + erff(t * 0.70710678118654752f)));
        }
      }
    }
  }
}

// ---------------------------------------------------------------- split-K MFMA GEMM (N=512)
// partial[z][m][n] = sum over K-slice; z = blockIdx.z selects P0..P3
template<int KPER>
__global__ __launch_bounds__(256) void mfma_gemm_pk(
    const bf16_t* __restrict__ A, const bf16_t* __restrict__ B, int Kst,
    float* __restrict__ P0, float* __restrict__ P1,
    float* __restrict__ P2, float* __restrict__ P3) {
  __shared__ __align__(16) bf16_t As[4096];
  __shared__ __align__(16) bf16_t Bs[4096];
  int tid = threadIdx.x;
  int n0 = blockIdx.x * 128, m0 = blockIdx.y * 128;
  int kb = blockIdx.z * KPER;
  float* P = blockIdx.z == 0 ? P0 : blockIdx.z == 1 ? P1 : blockIdx.z == 2 ? P2 : P3;
  int elt = tid * 8;
  int srow = elt >> 5, scol = elt & 31;
  const bf16_t* Ag = A + (size_t)(m0 + srow) * Kst + scol;
  const bf16_t* Bg = B + (size_t)(n0 + srow) * Kst + scol;
  size_t hstep = (size_t)64 * Kst;
  f32x4 acc[4][4] = {};
  int w = tid >> 6, l = tid & 63;
  int wm = (w >> 1) * 64, wn = (w & 1) * 64;
  int fr = l & 15, fk = (l >> 4) * 8;
  for (int k0 = kb; k0 < kb + KPER; k0 += 32) {
    __syncthreads();
    async16(Ag + k0, As + elt);
    async16(Ag + k0 + hstep, As + 2048 + elt);
    async16(Bg + k0, Bs + elt);
    async16(Bg + k0 + hstep, Bs + 2048 + elt);
    __syncthreads();
    bf16x8 af[4], bfr[4];
#pragma unroll
    for (int i = 0; i < 4; i++) af[i] = *(const bf16x8*)&As[(wm + i * 16 + fr) * 32 + fk];
#pragma unroll
    for (int j = 0; j < 4; j++) bfr[j] = *(const bf16x8*)&Bs[(wn + j * 16 + fr) * 32 + fk];
#pragma unroll
    for (int i = 0; i < 4; i++)
#pragma unroll
      for (int j = 0; j < 4; j++)
        acc[i][j] = __builtin_amdgcn_mfma_f32_16x16x32_bf16(af[i], bfr[j], acc[i][j], 0, 0, 0);
  }
  int cn = l & 15, cr = (l >> 4) * 4;
#pragma unroll
  for (int i = 0; i < 4; i++)
#pragma unroll
    for (int r = 0; r < 4; r++) {
      int m = m0 + wm + i * 16 + cr + r;
#pragma unroll
      for (int j = 0; j < 4; j++) {
        int n = n0 + wn + j * 16 + cn;
        P[(size_t)m * 512 + n] = acc[i][j][r];
      }
    }
}

// ---------------------------------------------------------------- reduce 4 partials + bias + resid
__global__ __launch_bounds__(256) void reduce4_kernel(
    const float* __restrict__ P0, const float* __restrict__ P1,
    const float* __restrict__ P2, const float* __restrict__ P3,
    const float* __restrict__ bias, const float* __restrict__ resid,
    float* __restrict__ o) {
  size_t idx = ((size_t)blockIdx.x * 256 + threadIdx.x) * 4;
  int n = (int)(idx & 511);
  float4 a = *(const float4*)(P0 + idx);
  float4 b = *(const float4*)(P1 + idx);
  float4 c = *(const float4*)(P2 + idx);
  float4 d = *(const float4*)(P3 + idx);
  float4 rr = *(const float4*)(resid + idx);
  float4 bi = *(const float4*)(bias + n);
  *(float4*)(o + idx) = make_float4(a.x + b.x + c.x + d.x + bi.x + rr.x,
                                    a.y + b.y + c.y + d.y + bi.y + rr.y,
                                    a.z + b.z + c.z + d.z + bi.z + rr.z,
                                    a.w + b.w + c.w + d.w + bi.w + rr.w);
}

// ------------------------------------------------- Phase A: chunk summaries
__global__ __launch_bounds__(256) void chunk_summary_kernel(
    const float* __restrict__ Kb, const float* __restrict__ Vb,
    const float* __restrict__ dl, float* __restrict__ Sst, float* __restrict__ zst) {
  int chunk = blockIdx.x, bh = blockIdx.y, dir = blockIdx.z;
  int b = bh >> 3, h = bh & 7;
  int t0 = chunk * CK;
  int tid = threadIdx.x;
  __shared__ __align__(16) float Ks[64][64];
  __shared__ __align__(16) float Vs[64][64];
  __shared__ float pw[72];
  float lam = 1.f / (1.f + expf(-dl[h]));
  if (tid <= 64) pw[tid] = powf(lam, (float)tid);
  int lrow = tid >> 2, lq = tid & 3;
  for (int q = 0; q < 4; q++) {
    int e = lq * 4 + q * 16;
    size_t g = ((size_t)(b * TT + t0 + lrow)) * DD + (size_t)h * 64 + e;
    *(float4*)&Ks[lrow][e] = *(const float4*)(Kb + g);
    *(float4*)&Vs[lrow][e] = *(const float4*)(Vb + g);
  }
  __syncthreads();
  int e1 = tid & 63;
  int e2b = (tid >> 6) * 16;
  float acc[16];
#pragma unroll
  for (int r = 0; r < 16; r++) acc[r] = 0.f;
  float zacc = 0.f;
  for (int j = 0; j < 64; j++) {
    float wgt = pw[dir == 0 ? 63 - j : j];
    float kv = wgt * Ks[j][e1];
    if (tid < 64) zacc += kv;
#pragma unroll
    for (int r = 0; r < 16; r++) acc[r] += kv * Vs[j][e2b + r];
  }
  size_t base = ((((size_t)dir * 16 + bh) * NC + chunk) * 64 + e1) * 64 + e2b;
#pragma unroll
  for (int r = 0; r < 16; r += 4)
    *(float4*)(Sst + base + r) = make_float4(acc[r], acc[r + 1], acc[r + 2], acc[r + 3]);
  if (tid < 64) zst[(((size_t)dir * 16 + bh) * NC + chunk) * 64 + tid] = zacc;
}

// ------------------------------------------------- Phase B: scan over chunks
__global__ __launch_bounds__(256) void scan_kernel(float* __restrict__ Sst,
                                                   float* __restrict__ zst,
                                                   const float* __restrict__ dl) {
  int bh = blockIdx.x, dir = blockIdx.y;
  int h = bh & 7;
  int tid = threadIdx.x;
  float lam = 1.f / (1.f + expf(-dl[h]));
  float lamC = powf(lam, 64.f);
  size_t base = ((size_t)dir * 16 + bh) * (size_t)NC * 4096 + (size_t)tid * 16;
  float S[16];
#pragma unroll
  for (int r = 0; r < 16; r++) S[r] = 0.f;
  for (int s = 0; s < NC; s++) {
    int c = dir ? (NC - 1 - s) : s;
    float* p = Sst + base + (size_t)c * 4096;
#pragma unroll
    for (int r = 0; r < 16; r++) { S[r] = S[r] * lamC + p[r]; p[r] = S[r]; }
  }
  if (tid < 64) {
    size_t zb = ((size_t)dir * 16 + bh) * (size_t)NC * 64 + tid;
    float z = 0.f;
    for (int s = 0; s < NC; s++) {
      int c = dir ? (NC - 1 - s) : s;
      float* p = zst + zb + (size_t)c * 64;
      z = z * lamC + *p; *p = z;
    }
  }
}

// ------------------------------------------------- Phase C: chunk attention
__global__ __launch_bounds__(256) void chunk_attn_kernel(
    const float* __restrict__ Qb, const float* __restrict__ Kb, const float* __restrict__ Vb,
    const float* __restrict__ Sst, const float* __restrict__ zst, const float* __restrict__ dl,
    float* __restrict__ Y0, float* __restrict__ Y1,
    float* __restrict__ C0, float* __restrict__ C1) {
  int chunk = blockIdx.x, bh = blockIdx.y, dir = blockIdx.z;
  int b = bh >> 3, h = bh & 7;
  int t0 = chunk * CK;
  int tid = threadIdx.x;
  __shared__ __align__(16) float Qt[64][68];
  __shared__ __align__(16) float Kt[64][68];
  __shared__ __align__(16) float Vs[64][64];
  __shared__ __align__(16) float Sp[64][64];
  __shared__ float rowpart[64][16];
  __shared__ float zp[64];
  __shared__ float pw[72];
  float lam = 1.f / (1.f + expf(-dl[h]));
  if (tid <= 64) pw[tid] = powf(lam, (float)tid);
  int lrow = tid >> 2, lq = tid & 3;
  for (int q = 0; q < 4; q++) {
    int e = lq * 4 + q * 16;
    size_t g = ((size_t)(b * TT + t0 + lrow)) * DD + (size_t)h * 64 + e;
    float4 q4 = *(const float4*)(Qb + g);
    float4 k4 = *(const float4*)(Kb + g);
    float4 v4 = *(const float4*)(Vb + g);
    Qt[e][lrow] = q4.x; Qt[e + 1][lrow] = q4.y; Qt[e + 2][lrow] = q4.z; Qt[e + 3][lrow] = q4.w;
    Kt[e][lrow] = k4.x; Kt[e + 1][lrow] = k4.y; Kt[e + 2][lrow] = k4.z; Kt[e + 3][lrow] = k4.w;
    *(float4*)&Vs[lrow][e] = v4;
  }
  int cs = dir ? chunk + 1 : chunk - 1;
  bool has = dir ? (chunk < NC - 1) : (chunk > 0);
  if (has) {
    size_t sb = (((size_t)dir * 16 + bh) * NC + cs) * 4096;
    for (int q = 0; q < 4; q++) {
      int e = lq * 4 + q * 16;
      *(float4*)&Sp[lrow][e] = *(const float4*)(Sst + sb + (size_t)lrow * 64 + e);
    }
    if (tid < 64) zp[tid] = zst[(((size_t)dir * 16 + bh) * NC + cs) * 64 + tid];
  } else {
    for (int q = 0; q < 4; q++) {
      int e = lq * 4 + q * 16;
      *(float4*)&Sp[lrow][e] = make_float4(0.f, 0.f, 0.f, 0.f);
    }
    if (tid < 64) zp[tid] = 0.f;
  }
  __syncthreads();
  int tx = tid & 15, ty = tid >> 4;
  int i0 = ty * 4, j0 = tx * 4;
  float acc[4][4] = {};
  for (int d = 0; d < 64; d++) {
    float4 qf = *(const float4*)&Qt[d][i0];
    float4 kf = *(const float4*)&Kt[d][j0];
    float qa[4] = {qf.x, qf.y, qf.z, qf.w};
    float ka[4] = {kf.x, kf.y, kf.z, kf.w};
#pragma unroll
    for (int r = 0; r < 4; r++)
#pragma unroll
      for (int c = 0; c < 4; c++) acc[r][c] += qa[r] * ka[c];
  }
  __syncthreads();
  float rs[4] = {0.f, 0.f, 0.f, 0.f};
  float colv[4][4];
#pragma unroll
  for (int r = 0; r < 4; r++) {
    int i = i0 + r;
#pragma unroll
    for (int c = 0; c < 4; c++) {
      int j = j0 + c;
      float v;
      if (dir == 0) v = (j <= i) ? acc[r][c] * pw[i - j] : 0.f;
      else          v = (j >= i) ? acc[r][c] * pw[j - i] : 0.f;
      if (i == j) v *= 0.5f;
      rs[r] += v;
      colv[c][r] = v;
    }
  }
#pragma unroll
  for (int c = 0; c < 4; c++)
    *(float4*)&Kt[j0 + c][i0] = make_float4(colv[c][0], colv[c][1], colv[c][2], colv[c][3]);
#pragma unroll
  for (int r = 0; r < 4; r++) rowpart[i0 + r][tx] = rs[r];
  __syncthreads();
  int e0 = tx * 4;
  float accY[4][4] = {}, accS[4][4] = {};
  for (int j = 0; j < 64; j++) {
    float4 af = *(const float4*)&Kt[j][i0];
    float4 vf = *(const float4*)&Vs[j][e0];
    float aa[4] = {af.x, af.y, af.z, af.w};
    float vv[4] = {vf.x, vf.y, vf.z, vf.w};
#pragma unroll
    for (int r = 0; r < 4; r++)
#pragma unroll
      for (int c = 0; c < 4; c++) accY[r][c] += aa[r] * vv[c];
  }
  for (int d = 0; d < 64; d++) {
    float4 qf = *(const float4*)&Qt[d][i0];
    float4 sf = *(const float4*)&Sp[d][e0];
    float qq[4] = {qf.x, qf.y, qf.z, qf.w};
    float ss[4] = {sf.x, sf.y, sf.z, sf.w};
#pragma unroll
    for (int r = 0; r < 4; r++)
#pragma unroll
      for (int c = 0; c < 4; c++) accS[r][c] += qq[r] * ss[c];
  }
  float* Yb = dir ? Y1 : Y0;
#pragma unroll
  for (int r = 0; r < 4; r++) {
    int i = i0 + r;
    float lr = dir ? pw[64 - i] : pw[i + 1];
    float4 o = make_float4(accY[r][0] + lr * accS[r][0], accY[r][1] + lr * accS[r][1],
                           accY[r][2] + lr * accS[r][2], accY[r][3] + lr * accS[r][3]);
    *(float4*)(Yb + ((size_t)(b * TT + t0 + i)) * DD + (size_t)h * 64 + e0) = o;
  }
  if (tid < 64) {
    int i = tid;
    float s = 0.f;
#pragma unroll
    for (int xx = 0; xx < 16; xx++) s += rowpart[i][xx];
    float cz = 0.f;
    for (int d = 0; d < 64; d++) cz += Qt[d][i] * zp[d];
    float lr = dir ? pw[64 - i] : pw[i + 1];
    s += lr * cz;
    float* Cb = dir ? C1 : C0;
    Cb[((size_t)(b * TT + t0 + i)) * HH + h] = s;
  }
}

// ---------------------------------------------------------------- combine (fp32 in, bf16 out)
__global__ __launch_bounds__(256) void combine_kernel(
    const float* __restrict__ Y0, const float* __restrict__ Y1,
    const float* __restrict__ C0, const float* __restrict__ C1,
    bf16_t* __restrict__ attn) {
  size_t idx = ((size_t)blockIdx.x * 256 + threadIdx.x) * 4;
  size_t bt = idx >> 9;
  int o = (int)(idx & 511);
  int h = o >> 6;
  float den = C0[bt * HH + h] + C1[bt * HH + h];
  den = fmaxf(den, 1e-6f);
  float4 y0 = *(const float4*)(Y0 + idx);
  float4 y1 = *(const float4*)(Y1 + idx);
  bf16x4 r;
  r[0] = (bf16_t)((y0.x + y1.x) / den);
  r[1] = (bf16_t)((y0.y + y1.y) / den);
  r[2] = (bf16_t)((y0.z + y1.z) / den);
  r[3] = (bf16_t)((y0.w + y1.w) / den);
  *(bf16x4*)(attn + idx) = r;
}

// ---------------------------------------------------------------- launch
extern "C" void kernel_launch(void* const* d_in, const int* in_sizes, int n_in,
                              void* d_out, int out_size, void* d_ws, size_t ws_size,
                              hipStream_t stream) {
  const float* x   = (const float*)d_in[0];
  const unsigned char* mask = (const unsigned char*)d_in[1];
  const float* Wq  = (const float*)d_in[2];
  const float* Wk  = (const float*)d_in[3];
  const float* Wv  = (const float*)d_in[4];
  const float* Wo  = (const float*)d_in[5];
  const float* bo  = (const float*)d_in[6];
  const float* g1  = (const float*)d_in[7];
  const float* b1  = (const float*)d_in[8];
  const float* g2  = (const float*)d_in[9];
  const float* b2  = (const float*)d_in[10];
  const float* W1  = (const float*)d_in[11];
  const float* bf1 = (const float*)d_in[12];
  const float* W2  = (const float*)d_in[13];
  const float* bf2 = (const float*)d_in[14];
  const float* dl  = (const float*)d_in[15];
  float* out = (float*)d_out;

  float* ws = (float*)d_ws;
  const size_t U = (size_t)BT * DD;  // 2097152 floats
  float* Qf  = ws;
  float* Kf  = ws + U;
  float* Vf  = ws + 2 * U;
  float* Y0  = ws + 3 * U;
  float* Y1  = ws + 4 * U;
  float* x2  = ws + 5 * U;
  float* Sst = ws + 6 * U;                 // 2U floats
  float* zst = ws + 8 * U;                 // 65536
  float* C0  = ws + 8 * U + 65536;         // 32768
  float* C1  = C0 + 32768;                 // 32768
  bf16_t* wall  = (bf16_t*)(ws + 8 * U + 131072);  // 3145728 bf16
  // bf16 overlays on dead fp32 regions:
  bf16_t* xnb   = (bf16_t*)Y0;   // live: ln1 .. QKV gemm
  bf16_t* attnb = (bf16_t*)Vf;   // live: combine .. Wo gemm
  bf16_t* h2b   = (bf16_t*)Qf;   // live: ln2 .. FFN1
  bf16_t* ffn1b = (bf16_t*)Kf;   // spans Kf+Vf (both dead by then)
  bf16_t* Wob = wall + 786432;
  bf16_t* W1b = wall + 1048576;
  bf16_t* W2b = wall + 2097152;
  // split-K partial slots (all dead fp32 regions at their use time):
  float* Ps0 = ws;            // Qf dead after chunk_attn; h2b written after wo reduce
  float* Ps1 = ws + 3 * U;    // Y0 dead after combine
  float* Ps2 = ws + 4 * U;    // Y1 dead after combine
  float* Ps3 = ws + 6 * U;    // Sst dead after chunk_attn

  cast_weights<<<1536, 256, 0, stream>>>(Wq, Wk, Wv, Wo, W1, W2, wall);
  ln_kernel<<<BT, 256, 0, stream>>>(x, g1, b1, xnb);
  mfma_gemm<0><<<dim3(12, 32), 256, 0, stream>>>(xnb, wall, 512, Qf, Kf, Vf,
                                                 nullptr, nullptr, mask);
  chunk_summary_kernel<<<dim3(NC, 16, 2), 256, 0, stream>>>(Kf, Vf, dl, Sst, zst);
  scan_kernel<<<dim3(16, 2), 256, 0, stream>>>(Sst, zst, dl);
  chunk_attn_kernel<<<dim3(NC, 16, 2), 256, 0, stream>>>(Qf, Kf, Vf, Sst, zst, dl, Y0, Y1, C0, C1);
  combine_kernel<<<2048, 256, 0, stream>>>(Y0, Y1, C0, C1, attnb);
  // Wo: M=4096 N=512 K=512, split-K=4 (Kper=128) -> 512 blocks
  mfma_gemm_pk<128><<<dim3(4, 32, 4), 256, 0, stream>>>(attnb, Wob, 512, Ps0, Ps1, Ps2, Ps3);
  reduce4_kernel<<<2048, 256, 0, stream>>>(Ps0, Ps1, Ps2, Ps3, bo, x, x2);
  ln_kernel<<<BT, 256, 0, stream>>>(x2, g2, b2, h2b);
  mfma_gemm<2><<<dim3(16, 32), 256, 0, stream>>>(h2b, W1b, 512, nullptr,
                                                 nullptr, nullptr, ffn1b, bf1, nullptr);
  // FFN2: M=4096 N=512 K=2048, split-K=4 (Kper=512) -> 512 blocks
  mfma_gemm_pk<512><<<dim3(4, 32, 4), 256, 0, stream>>>(ffn1b, W2b, 2048, Ps0, Ps1, Ps2, Ps3);
  reduce4_kernel<<<2048, 256, 0, stream>>>(Ps0, Ps1, Ps2, Ps3, bf2, x2, out);
}

// Round 4
// 243.747 us; speedup vs baseline: 2.4154x; 1.1660x over previous
//
#include <hip/hip_runtime.h>
#include <math.h>

#define BB 2
#define TT 2048
#define DD 512
#define FF 2048
#define HH 8
#define BT 4096      // BB*TT
#define NC 32        // TT/64 chunks
#define CK 64        // chunk size

typedef __bf16 bf16_t;
typedef bf16_t bf16x8 __attribute__((ext_vector_type(8)));
typedef bf16_t bf16x4 __attribute__((ext_vector_type(4)));
typedef float f32x4 __attribute__((ext_vector_type(4)));

typedef const __attribute__((address_space(1))) void* gas_p;
typedef __attribute__((address_space(3))) void* las_p;

__device__ __forceinline__ void async16(const void* g, void* l) {
  __builtin_amdgcn_global_load_lds((gas_p)g, (las_p)l, 16, 0, 0);
}

// ---------------------------------------------------------------- LayerNorm (fp32 in, bf16 out)
__global__ __launch_bounds__(256) void ln_kernel(const float* __restrict__ x,
                                                 const float* __restrict__ g,
                                                 const float* __restrict__ bb,
                                                 bf16_t* __restrict__ out) {
  int row = blockIdx.x;
  int t = threadIdx.x;
  const float* xr = x + (size_t)row * DD;
  float v0 = xr[t], v1 = xr[t + 256];
  float s = v0 + v1, sq = v0 * v0 + v1 * v1;
  for (int o = 32; o; o >>= 1) { s += __shfl_down(s, o); sq += __shfl_down(sq, o); }
  __shared__ float red[8];
  __shared__ float mv[2];
  int w = t >> 6;
  if ((t & 63) == 0) { red[w] = s; red[4 + w] = sq; }
  __syncthreads();
  if (t == 0) {
    float S = red[0] + red[1] + red[2] + red[3];
    float Q = red[4] + red[5] + red[6] + red[7];
    float m = S * (1.f / 512.f);
    float var = Q * (1.f / 512.f) - m * m;
    mv[0] = m; mv[1] = rsqrtf(var + 1e-5f);
  }
  __syncthreads();
  float m = mv[0], r = mv[1];
  out[(size_t)row * DD + t]       = (bf16_t)((v0 - m) * r * g[t] + bb[t]);
  out[(size_t)row * DD + t + 256] = (bf16_t)((v1 - m) * r * g[t + 256] + bb[t + 256]);
}

// ---------------------------------------------------------------- weight cast fp32 -> bf16
__global__ __launch_bounds__(256) void cast_weights(
    const float* __restrict__ Wq, const float* __restrict__ Wk,
    const float* __restrict__ Wv, const float* __restrict__ Wo,
    const float* __restrict__ W1, const float* __restrict__ W2,
    bf16_t* __restrict__ dst) {
  size_t i = ((size_t)blockIdx.x * 256 + threadIdx.x) * 8;
  const float* src; size_t off;
  if (i < 262144)       { src = Wq; off = i; }
  else if (i < 524288)  { src = Wk; off = i - 262144; }
  else if (i < 786432)  { src = Wv; off = i - 524288; }
  else if (i < 1048576) { src = Wo; off = i - 786432; }
  else if (i < 2097152) { src = W1; off = i - 1048576; }
  else                  { src = W2; off = i - 2097152; }
  float4 a = *(const float4*)(src + off);
  float4 b = *(const float4*)(src + off + 4);
  bf16x8 o;
  o[0] = (bf16_t)a.x; o[1] = (bf16_t)a.y; o[2] = (bf16_t)a.z; o[3] = (bf16_t)a.w;
  o[4] = (bf16_t)b.x; o[5] = (bf16_t)b.y; o[6] = (bf16_t)b.z; o[7] = (bf16_t)b.w;
  *(bf16x8*)(dst + i) = o;
}

// ---------------------------------------------------------------- MFMA GEMM  C = A * B^T
// 128(M)x64(N) tile, BK=32, 256 thr, 4 waves in 2x2; wave = 64x32 (4x2 MFMA).
// MODE 0: QKV fused epilogue (N=1536 -> Q/K/V fp32, elu+1 / pad)
// MODE 2: bf16 out = gelu(acc + bias[n])     (N=2048)
template<int MODE>
__global__ __launch_bounds__(256) void mfma_gemm(
    const bf16_t* __restrict__ A, const bf16_t* __restrict__ B, int K,
    float* __restrict__ O0, float* __restrict__ O1, float* __restrict__ O2,
    bf16_t* __restrict__ Ob, const float* __restrict__ bias,
    const unsigned char* __restrict__ mask) {
  __shared__ __align__(16) bf16_t As[4096];
  __shared__ __align__(16) bf16_t Bs[2048];
  int tid = threadIdx.x;
  int n0 = blockIdx.x * 64, m0 = blockIdx.y * 128;
  int elt = tid * 8;
  int srow = elt >> 5, scol = elt & 31;
  const bf16_t* Ag = A + (size_t)(m0 + srow) * K + scol;
  const bf16_t* Bg = B + (size_t)(n0 + srow) * K + scol;
  size_t hstep = (size_t)64 * K;
  f32x4 acc[4][2] = {};
  int w = tid >> 6, l = tid & 63;
  int wm = (w >> 1) * 64, wn = (w & 1) * 32;
  int fr = l & 15, fk = (l >> 4) * 8;
  for (int k0 = 0; k0 < K; k0 += 32) {
    __syncthreads();
    async16(Ag + k0, As + elt);
    async16(Ag + k0 + hstep, As + 2048 + elt);
    async16(Bg + k0, Bs + elt);
    __syncthreads();
    bf16x8 af[4], bfr[2];
#pragma unroll
    for (int i = 0; i < 4; i++) af[i] = *(const bf16x8*)&As[(wm + i * 16 + fr) * 32 + fk];
#pragma unroll
    for (int j = 0; j < 2; j++) bfr[j] = *(const bf16x8*)&Bs[(wn + j * 16 + fr) * 32 + fk];
#pragma unroll
    for (int i = 0; i < 4; i++)
#pragma unroll
      for (int j = 0; j < 2; j++)
        acc[i][j] = __builtin_amdgcn_mfma_f32_16x16x32_bf16(af[i], bfr[j], acc[i][j], 0, 0, 0);
  }
  int cn = l & 15, cr = (l >> 4) * 4;
#pragma unroll
  for (int i = 0; i < 4; i++) {
#pragma unroll
    for (int r = 0; r < 4; r++) {
      int m = m0 + wm + i * 16 + cr + r;
#pragma unroll
      for (int j = 0; j < 2; j++) {
        int n = n0 + wn + j * 16 + cn;
        float v = acc[i][j][r];
        if (MODE == 0) {
          float p = mask[m] ? 0.f : 1.f;
          int seg = n >> 9, nn = n & 511;
          size_t o = (size_t)m * 512 + nn;
          if (seg == 0)      O0[o] = v > 0.f ? v + 1.f : expf(v);
          else if (seg == 1) O1[o] = (v > 0.f ? v + 1.f : expf(v)) * p;
          else               O2[o] = v * p;
        } else {
          float t = v + bias[n];
          Ob[(size_t)m * 2048 + n] = (bf16_t)(0.5f * t * (1.f + erff(t * 0.70710678118654752f)));
        }
      }
    }
  }
}

// ---------------------------------------------------------------- split-K MFMA GEMM (N=512), z in {0,1}
template<int KPER>
__global__ __launch_bounds__(256) void mfma_gemm_pk(
    const bf16_t* __restrict__ A, const bf16_t* __restrict__ B, int Kst,
    float* __restrict__ P0, float* __restrict__ P1) {
  __shared__ __align__(16) bf16_t As[4096];
  __shared__ __align__(16) bf16_t Bs[2048];
  int tid = threadIdx.x;
  int n0 = blockIdx.x * 64, m0 = blockIdx.y * 128;
  int kb = blockIdx.z * KPER;
  float* P = blockIdx.z ? P1 : P0;
  int elt = tid * 8;
  int srow = elt >> 5, scol = elt & 31;
  const bf16_t* Ag = A + (size_t)(m0 + srow) * Kst + scol;
  const bf16_t* Bg = B + (size_t)(n0 + srow) * Kst + scol;
  size_t hstep = (size_t)64 * Kst;
  f32x4 acc[4][2] = {};
  int w = tid >> 6, l = tid & 63;
  int wm = (w >> 1) * 64, wn = (w & 1) * 32;
  int fr = l & 15, fk = (l >> 4) * 8;
  for (int k0 = kb; k0 < kb + KPER; k0 += 32) {
    __syncthreads();
    async16(Ag + k0, As + elt);
    async16(Ag + k0 + hstep, As + 2048 + elt);
    async16(Bg + k0, Bs + elt);
    __syncthreads();
    bf16x8 af[4], bfr[2];
#pragma unroll
    for (int i = 0; i < 4; i++) af[i] = *(const bf16x8*)&As[(wm + i * 16 + fr) * 32 + fk];
#pragma unroll
    for (int j = 0; j < 2; j++) bfr[j] = *(const bf16x8*)&Bs[(wn + j * 16 + fr) * 32 + fk];
#pragma unroll
    for (int i = 0; i < 4; i++)
#pragma unroll
      for (int j = 0; j < 2; j++)
        acc[i][j] = __builtin_amdgcn_mfma_f32_16x16x32_bf16(af[i], bfr[j], acc[i][j], 0, 0, 0);
  }
  int cn = l & 15, cr = (l >> 4) * 4;
#pragma unroll
  for (int i = 0; i < 4; i++)
#pragma unroll
    for (int r = 0; r < 4; r++) {
      int m = m0 + wm + i * 16 + cr + r;
#pragma unroll
      for (int j = 0; j < 2; j++) {
        int n = n0 + wn + j * 16 + cn;
        P[(size_t)m * 512 + n] = acc[i][j][r];
      }
    }
}

// ---------------------------------------------------------------- reduce 2 partials + bias + resid
__global__ __launch_bounds__(256) void reduce2_kernel(
    const float* __restrict__ P0, const float* __restrict__ P1,
    const float* __restrict__ bias, const float* __restrict__ resid,
    float* __restrict__ o) {
  size_t idx = ((size_t)blockIdx.x * 256 + threadIdx.x) * 4;
  int n = (int)(idx & 511);
  float4 a = *(const float4*)(P0 + idx);
  float4 b = *(const float4*)(P1 + idx);
  float4 rr = *(const float4*)(resid + idx);
  float4 bi = *(const float4*)(bias + n);
  *(float4*)(o + idx) = make_float4(a.x + b.x + bi.x + rr.x, a.y + b.y + bi.y + rr.y,
                                    a.z + b.z + bi.z + rr.z, a.w + b.w + bi.w + rr.w);
}

// ------------------------------------------------- Phase A: chunk summaries, both dirs
__global__ __launch_bounds__(256) void chunk_summary_kernel(
    const float* __restrict__ Kb, const float* __restrict__ Vb,
    const float* __restrict__ dl, float* __restrict__ Sst, float* __restrict__ zst) {
  int chunk = blockIdx.x, bh = blockIdx.y;
  int b = bh >> 3, h = bh & 7;
  int t0 = chunk * CK;
  int tid = threadIdx.x;
  __shared__ __align__(16) float Ks[64][64];
  __shared__ __align__(16) float Vs[64][64];
  __shared__ float pw[72];
  float lam = 1.f / (1.f + expf(-dl[h]));
  if (tid <= 64) pw[tid] = powf(lam, (float)tid);
  int lrow = tid >> 2, lq = tid & 3;
  for (int q = 0; q < 4; q++) {
    int e = lq * 4 + q * 16;
    size_t g = ((size_t)(b * TT + t0 + lrow)) * DD + (size_t)h * 64 + e;
    *(float4*)&Ks[lrow][e] = *(const float4*)(Kb + g);
    *(float4*)&Vs[lrow][e] = *(const float4*)(Vb + g);
  }
  __syncthreads();
  int e1 = tid & 63;
  int e2b = (tid >> 6) * 16;
  float af_[16], ab_[16];
#pragma unroll
  for (int r = 0; r < 16; r++) { af_[r] = 0.f; ab_[r] = 0.f; }
  float zf = 0.f, zb = 0.f;
  for (int j = 0; j < 64; j++) {
    float kj = Ks[j][e1];
    float kf = pw[63 - j] * kj;
    float kb2 = pw[j] * kj;
    if (tid < 64) { zf += kf; zb += kb2; }
#pragma unroll
    for (int r = 0; r < 16; r++) {
      float v = Vs[j][e2b + r];
      af_[r] += kf * v;
      ab_[r] += kb2 * v;
    }
  }
  size_t bf_ = (((size_t)bh * NC + chunk) * 64 + e1) * 64 + e2b;
  size_t bb_ = ((((size_t)16 + bh) * NC + chunk) * 64 + e1) * 64 + e2b;
#pragma unroll
  for (int r = 0; r < 16; r += 4) {
    *(float4*)(Sst + bf_ + r) = make_float4(af_[r], af_[r + 1], af_[r + 2], af_[r + 3]);
    *(float4*)(Sst + bb_ + r) = make_float4(ab_[r], ab_[r + 1], ab_[r + 2], ab_[r + 3]);
  }
  if (tid < 64) {
    zst[((size_t)bh * NC + chunk) * 64 + tid] = zf;
    zst[(((size_t)16 + bh) * NC + chunk) * 64 + tid] = zb;
  }
}

// ------------------------------------------------- Phase B: scan over chunks (batched loads)
__global__ __launch_bounds__(1024) void scan_kernel(float* __restrict__ Sst,
                                                    float* __restrict__ zst,
                                                    const float* __restrict__ dl) {
  int bh = blockIdx.x, dir = blockIdx.y;
  int h = bh & 7;
  int tid = threadIdx.x;
  float lam = 1.f / (1.f + expf(-dl[h]));
  float lamC = powf(lam, 64.f);
  size_t base = ((size_t)dir * 16 + bh) * (size_t)NC * 4096 + (size_t)tid * 4;
  float4 S = make_float4(0.f, 0.f, 0.f, 0.f);
  for (int g = 0; g < 4; g++) {
    float4 L[8];
#pragma unroll
    for (int i = 0; i < 8; i++) {
      int s = g * 8 + i;
      int c = dir ? (NC - 1 - s) : s;
      L[i] = *(float4*)(Sst + base + (size_t)c * 4096);
    }
#pragma unroll
    for (int i = 0; i < 8; i++) {
      int s = g * 8 + i;
      int c = dir ? (NC - 1 - s) : s;
      S.x = S.x * lamC + L[i].x;
      S.y = S.y * lamC + L[i].y;
      S.z = S.z * lamC + L[i].z;
      S.w = S.w * lamC + L[i].w;
      *(float4*)(Sst + base + (size_t)c * 4096) = S;
    }
  }
  if (tid < 64) {
    size_t zb = ((size_t)dir * 16 + bh) * (size_t)NC * 64 + tid;
    float z = 0.f;
    for (int g = 0; g < 4; g++) {
      float zL[8];
#pragma unroll
      for (int i = 0; i < 8; i++) {
        int s = g * 8 + i;
        int c = dir ? (NC - 1 - s) : s;
        zL[i] = zst[zb + (size_t)c * 64];
      }
#pragma unroll
      for (int i = 0; i < 8; i++) {
        int s = g * 8 + i;
        int c = dir ? (NC - 1 - s) : s;
        z = z * lamC + zL[i];
        zst[zb + (size_t)c * 64] = z;
      }
    }
  }
}

// ------------------------------------------------- Phase C: fused chunk attention (both dirs + combine)
__global__ __launch_bounds__(256) void chunk_attn_kernel(
    const float* __restrict__ Qb, const float* __restrict__ Kb, const float* __restrict__ Vb,
    const float* __restrict__ Sst, const float* __restrict__ zst, const float* __restrict__ dl,
    bf16_t* __restrict__ attnb) {
  int chunk = blockIdx.x, bh = blockIdx.y;
  int b = bh >> 3, h = bh & 7;
  int t0 = chunk * CK;
  int tid = threadIdx.x;
  __shared__ __align__(16) float Qt[64][68];   // Q^T [d][i]
  __shared__ __align__(16) float KtA[64][68];  // K^T [d][j], reused as Ast[j][i]
  __shared__ __align__(16) float Vs[64][64];   // [j][e]
  __shared__ __align__(16) float Sp[64][64];   // [d][e] (per dir)
  __shared__ float rowpart[64][16];
  __shared__ float zp[64];
  __shared__ float den[2][64];
  __shared__ float pw[72];
  float lam = 1.f / (1.f + expf(-dl[h]));
  if (tid <= 64) pw[tid] = powf(lam, (float)tid);
  int lrow = tid >> 2, lq = tid & 3;
  for (int q = 0; q < 4; q++) {
    int e = lq * 4 + q * 16;
    size_t g = ((size_t)(b * TT + t0 + lrow)) * DD + (size_t)h * 64 + e;
    float4 q4 = *(const float4*)(Qb + g);
    float4 k4 = *(const float4*)(Kb + g);
    float4 v4 = *(const float4*)(Vb + g);
    Qt[e][lrow] = q4.x; Qt[e + 1][lrow] = q4.y; Qt[e + 2][lrow] = q4.z; Qt[e + 3][lrow] = q4.w;
    KtA[e][lrow] = k4.x; KtA[e + 1][lrow] = k4.y; KtA[e + 2][lrow] = k4.z; KtA[e + 3][lrow] = k4.w;
    *(float4*)&Vs[lrow][e] = v4;
  }
  // load Sp/zp for dir 0 (prev chunk)
  {
    int cs = chunk - 1;
    bool has = chunk > 0;
    if (has) {
      size_t sb = ((size_t)bh * NC + cs) * 4096;
      for (int q = 0; q < 4; q++) {
        int e = lq * 4 + q * 16;
        *(float4*)&Sp[lrow][e] = *(const float4*)(Sst + sb + (size_t)lrow * 64 + e);
      }
      if (tid < 64) zp[tid] = zst[((size_t)bh * NC + cs) * 64 + tid];
    } else {
      for (int q = 0; q < 4; q++) {
        int e = lq * 4 + q * 16;
        *(float4*)&Sp[lrow][e] = make_float4(0.f, 0.f, 0.f, 0.f);
      }
      if (tid < 64) zp[tid] = 0.f;
    }
  }
  __syncthreads();
  int tx = tid & 15, ty = tid >> 4;
  int i0 = ty * 4, j0 = tx * 4;
  int e0 = tx * 4;
  // ---- A = Q K^T over d (shared by both directions)
  float acc[4][4] = {};
  for (int d = 0; d < 64; d++) {
    float4 qf = *(const float4*)&Qt[d][i0];
    float4 kf = *(const float4*)&KtA[d][j0];
    float qa[4] = {qf.x, qf.y, qf.z, qf.w};
    float ka[4] = {kf.x, kf.y, kf.z, kf.w};
#pragma unroll
    for (int r = 0; r < 4; r++)
#pragma unroll
      for (int c = 0; c < 4; c++) acc[r][c] += qa[r] * ka[c];
  }
  __syncthreads();  // KtA free for reuse as Ast
  float y[2][4][4];
  for (int dir = 0; dir < 2; dir++) {
    if (dir == 1) {
      // load Sp/zp for dir 1 (next chunk); prior iteration ended with a barrier
      int cs = chunk + 1;
      bool has = chunk < NC - 1;
      if (has) {
        size_t sb = (((size_t)16 + bh) * NC + cs) * 4096;
        for (int q = 0; q < 4; q++) {
          int e = lq * 4 + q * 16;
          *(float4*)&Sp[lrow][e] = *(const float4*)(Sst + sb + (size_t)lrow * 64 + e);
        }
        if (tid < 64) zp[tid] = zst[(((size_t)16 + bh) * NC + cs) * 64 + tid];
      } else {
        for (int q = 0; q < 4; q++) {
          int e = lq * 4 + q * 16;
          *(float4*)&Sp[lrow][e] = make_float4(0.f, 0.f, 0.f, 0.f);
        }
        if (tid < 64) zp[tid] = 0.f;
      }
    }
    // ---- decay mask + halve diagonal; Ast[j][i] into KtA; row partial sums
    float rs[4] = {0.f, 0.f, 0.f, 0.f};
    float colv[4][4];
#pragma unroll
    for (int r = 0; r < 4; r++) {
      int i = i0 + r;
#pragma unroll
      for (int c = 0; c < 4; c++) {
        int j = j0 + c;
        float v;
        if (dir == 0) v = (j <= i) ? acc[r][c] * pw[i - j] : 0.f;
        else          v = (j >= i) ? acc[r][c] * pw[j - i] : 0.f;
        if (i == j) v *= 0.5f;
        rs[r] += v;
        colv[c][r] = v;
      }
    }
#pragma unroll
    for (int c = 0; c < 4; c++)
      *(float4*)&KtA[j0 + c][i0] = make_float4(colv[c][0], colv[c][1], colv[c][2], colv[c][3]);
#pragma unroll
    for (int r = 0; r < 4; r++) rowpart[i0 + r][tx] = rs[r];
    __syncthreads();  // Ast/rowpart/Sp visible
    // ---- Y = Ast^T V + diag(lam^row) (Q Sprev)
    float accY[4][4] = {}, accS[4][4] = {};
    for (int j = 0; j < 64; j++) {
      float4 af = *(const float4*)&KtA[j][i0];
      float4 vf = *(const float4*)&Vs[j][e0];
      float aa[4] = {af.x, af.y, af.z, af.w};
      float vv[4] = {vf.x, vf.y, vf.z, vf.w};
#pragma unroll
      for (int r = 0; r < 4; r++)
#pragma unroll
        for (int c = 0; c < 4; c++) accY[r][c] += aa[r] * vv[c];
    }
    for (int d = 0; d < 64; d++) {
      float4 qf = *(const float4*)&Qt[d][i0];
      float4 sf = *(const float4*)&Sp[d][e0];
      float qq[4] = {qf.x, qf.y, qf.z, qf.w};
      float ss[4] = {sf.x, sf.y, sf.z, sf.w};
#pragma unroll
      for (int r = 0; r < 4; r++)
#pragma unroll
        for (int c = 0; c < 4; c++) accS[r][c] += qq[r] * ss[c];
    }
#pragma unroll
    for (int r = 0; r < 4; r++) {
      int i = i0 + r;
      float lr = dir ? pw[64 - i] : pw[i + 1];
#pragma unroll
      for (int c = 0; c < 4; c++) y[dir][r][c] = accY[r][c] + lr * accS[r][c];
    }
    if (tid < 64) {
      int i = tid;
      float s = 0.f;
#pragma unroll
      for (int xx = 0; xx < 16; xx++) s += rowpart[i][xx];
      float cz = 0.f;
      for (int d = 0; d < 64; d++) cz += Qt[d][i] * zp[d];
      float lr = dir ? pw[64 - i] : pw[i + 1];
      den[dir][i] = s + lr * cz;
    }
    __syncthreads();  // den visible; Ast/Sp/zp/rowpart free for next dir
  }
  // ---- combine + write bf16
#pragma unroll
  for (int r = 0; r < 4; r++) {
    int i = i0 + r;
    float dd = fmaxf(den[0][i] + den[1][i], 1e-6f);
    float inv = 1.f / dd;
    bf16x4 o;
#pragma unroll
    for (int c = 0; c < 4; c++) o[c] = (bf16_t)((y[0][r][c] + y[1][r][c]) * inv);
    *(bf16x4*)(attnb + ((size_t)(b * TT + t0 + i)) * DD + (size_t)h * 64 + e0) = o;
  }
}

// ---------------------------------------------------------------- launch
extern "C" void kernel_launch(void* const* d_in, const int* in_sizes, int n_in,
                              void* d_out, int out_size, void* d_ws, size_t ws_size,
                              hipStream_t stream) {
  const float* x   = (const float*)d_in[0];
  const unsigned char* mask = (const unsigned char*)d_in[1];
  const float* Wq  = (const float*)d_in[2];
  const float* Wk  = (const float*)d_in[3];
  const float* Wv  = (const float*)d_in[4];
  const float* Wo  = (const float*)d_in[5];
  const float* bo  = (const float*)d_in[6];
  const float* g1  = (const float*)d_in[7];
  const float* b1  = (const float*)d_in[8];
  const float* g2  = (const float*)d_in[9];
  const float* b2  = (const float*)d_in[10];
  const float* W1  = (const float*)d_in[11];
  const float* bf1 = (const float*)d_in[12];
  const float* W2  = (const float*)d_in[13];
  const float* bf2 = (const float*)d_in[14];
  const float* dl  = (const float*)d_in[15];
  float* out = (float*)d_out;

  float* ws = (float*)d_ws;
  const size_t U = (size_t)BT * DD;  // 2097152 floats
  float* Qf  = ws;            // fp32 Q features
  float* Kf  = ws + U;
  float* Vf  = ws + 2 * U;
  float* R3  = ws + 3 * U;    // xnb (bf16) then Ps0
  float* R4  = ws + 4 * U;    // Ps1
  float* x2  = ws + 5 * U;    // attnb (bf16) then x2 fp32
  float* Sst = ws + 6 * U;    // 2U floats
  float* zst = ws + 8 * U;    // 131072 floats
  bf16_t* wall = (bf16_t*)(ws + 8 * U + 131072);  // 3145728 bf16
  bf16_t* xnb   = (bf16_t*)R3;   // live: ln1 .. QKV gemm
  bf16_t* attnb = (bf16_t*)x2;   // live: chunk_attn .. Wo gemm (x2 written after)
  bf16_t* h2b   = (bf16_t*)Qf;   // live: ln2 .. FFN1 (Qf dead after chunk_attn)
  bf16_t* ffn1b = (bf16_t*)Kf;   // spans Kf+Vf (dead after chunk_attn)
  bf16_t* Wob = wall + 786432;
  bf16_t* W1b = wall + 1048576;
  bf16_t* W2b = wall + 2097152;
  float* Ps0 = R3;               // xnb dead after QKV
  float* Ps1 = R4;

  cast_weights<<<1536, 256, 0, stream>>>(Wq, Wk, Wv, Wo, W1, W2, wall);
  ln_kernel<<<BT, 256, 0, stream>>>(x, g1, b1, xnb);
  // QKV: M=4096 N=1536 K=512 -> 24x32 = 768 blocks
  mfma_gemm<0><<<dim3(24, 32), 256, 0, stream>>>(xnb, wall, 512, Qf, Kf, Vf,
                                                 nullptr, nullptr, mask);
  chunk_summary_kernel<<<dim3(NC, 16), 256, 0, stream>>>(Kf, Vf, dl, Sst, zst);
  scan_kernel<<<dim3(16, 2), 1024, 0, stream>>>(Sst, zst, dl);
  chunk_attn_kernel<<<dim3(NC, 16), 256, 0, stream>>>(Qf, Kf, Vf, Sst, zst, dl, attnb);
  // Wo: M=4096 N=512 K=512, split-K=2 (Kper=256) -> 8x32x2 = 512 blocks
  mfma_gemm_pk<256><<<dim3(8, 32, 2), 256, 0, stream>>>(attnb, Wob, 512, Ps0, Ps1);
  reduce2_kernel<<<2048, 256, 0, stream>>>(Ps0, Ps1, bo, x, x2);
  ln_kernel<<<BT, 256, 0, stream>>>(x2, g2, b2, h2b);
  // FFN1: M=4096 N=2048 K=512 -> 32x32 = 1024 blocks
  mfma_gemm<2><<<dim3(32, 32), 256, 0, stream>>>(h2b, W1b, 512, nullptr,
                                                 nullptr, nullptr, ffn1b, bf1, nullptr);
  // FFN2: M=4096 N=512 K=2048, split-K=2 (Kper=1024) -> 512 blocks
  mfma_gemm_pk<1024><<<dim3(8, 32, 2), 256, 0, stream>>>(ffn1b, W2b, 2048, Ps0, Ps1);
  reduce2_kernel<<<2048, 256, 0, stream>>>(Ps0, Ps1, bf2, x2, out);
}

// Round 8
// 230.568 us; speedup vs baseline: 2.5535x; 1.0572x over previous
//
#include <hip/hip_runtime.h>
#include <math.h>

#define BB 2
#define TT 2048
#define DD 512
#define FF 2048
#define HH 8
#define BT 4096      // BB*TT
#define NC 32        // TT/64 chunks
#define CK 64        // chunk size

typedef __bf16 bf16_t;
typedef bf16_t bf16x8 __attribute__((ext_vector_type(8)));
typedef bf16_t bf16x4 __attribute__((ext_vector_type(4)));
typedef float f32x4 __attribute__((ext_vector_type(4)));

typedef const __attribute__((address_space(1))) void* gas_p;
typedef __attribute__((address_space(3))) void* las_p;

__device__ __forceinline__ void async16(const void* g, void* l) {
  __builtin_amdgcn_global_load_lds((gas_p)g, (las_p)l, 16, 0, 0);
}

// Pipelined barrier: partial-vmcnt wait + s_barrier as ONE asm block with a
// "memory" clobber (compiler-level fence: no LDS access may be reordered across).
// lgkmcnt(0): this wave's ds_reads drained before the barrier, so after the
// barrier every wave may safely overwrite the (i-1) stage. vmcnt(N) leaves the
// prefetch DMA stages in flight — the whole point of the pipeline.
#define PIPE_SYNC(vm) asm volatile("s_waitcnt lgkmcnt(0) vmcnt(" vm ")\n\ts_barrier" ::: "memory")

// ---------------------------------------------------------------- LN1 + weight cast fused
__global__ __launch_bounds__(256) void ln_cast_kernel(
    const float* __restrict__ x, const float* __restrict__ g, const float* __restrict__ bb,
    bf16_t* __restrict__ out,
    const float* __restrict__ Wq, const float* __restrict__ Wk,
    const float* __restrict__ Wv, const float* __restrict__ Wo,
    const float* __restrict__ W1, const float* __restrict__ W2,
    bf16_t* __restrict__ wdst) {
  int t = threadIdx.x;
  if (blockIdx.x >= BT) {
    size_t i = ((size_t)(blockIdx.x - BT) * 256 + t) * 8;
    const float* src; size_t off;
    if (i < 262144)       { src = Wq; off = i; }
    else if (i < 524288)  { src = Wk; off = i - 262144; }
    else if (i < 786432)  { src = Wv; off = i - 524288; }
    else if (i < 1048576) { src = Wo; off = i - 786432; }
    else if (i < 2097152) { src = W1; off = i - 1048576; }
    else                  { src = W2; off = i - 2097152; }
    float4 a = *(const float4*)(src + off);
    float4 b = *(const float4*)(src + off + 4);
    bf16x8 o;
    o[0] = (bf16_t)a.x; o[1] = (bf16_t)a.y; o[2] = (bf16_t)a.z; o[3] = (bf16_t)a.w;
    o[4] = (bf16_t)b.x; o[5] = (bf16_t)b.y; o[6] = (bf16_t)b.z; o[7] = (bf16_t)b.w;
    *(bf16x8*)(wdst + i) = o;
    return;
  }
  int row = blockIdx.x;
  const float* xr = x + (size_t)row * DD;
  float v0 = xr[t], v1 = xr[t + 256];
  float s = v0 + v1, sq = v0 * v0 + v1 * v1;
  for (int o = 32; o; o >>= 1) { s += __shfl_down(s, o); sq += __shfl_down(sq, o); }
  __shared__ float red[8];
  __shared__ float mv[2];
  int w = t >> 6;
  if ((t & 63) == 0) { red[w] = s; red[4 + w] = sq; }
  __syncthreads();
  if (t == 0) {
    float S = red[0] + red[1] + red[2] + red[3];
    float Q = red[4] + red[5] + red[6] + red[7];
    float m = S * (1.f / 512.f);
    float var = Q * (1.f / 512.f) - m * m;
    mv[0] = m; mv[1] = rsqrtf(var + 1e-5f);
  }
  __syncthreads();
  float m = mv[0], r = mv[1];
  out[(size_t)row * DD + t]       = (bf16_t)((v0 - m) * r * g[t] + bb[t]);
  out[(size_t)row * DD + t + 256] = (bf16_t)((v1 - m) * r * g[t + 256] + bb[t + 256]);
}

// ---------------------------------------------------------------- pipelined MFMA GEMM  C = A*B^T
// 128(M)x64(N) tile, BK=32, depth-3 prefetch, 4 LDS stages, XCD-swizzled 1D grid.
// grid MUST be 32*NT blocks (NT = N/64).
template<int MODE>
__global__ __launch_bounds__(256) void mfma_gemm(
    const bf16_t* __restrict__ A, const bf16_t* __restrict__ B, int K, int NT,
    float* __restrict__ O0, float* __restrict__ O1, float* __restrict__ O2,
    bf16_t* __restrict__ Ob, const float* __restrict__ bias,
    const unsigned char* __restrict__ mask) {
  __shared__ __align__(16) bf16_t smem[4 * 6144];
  int tid = threadIdx.x;
  int bid = blockIdx.x;
  int xcd = bid & 7;
  int tmp = bid >> 3;
  int nt = tmp % NT;
  int mt = (tmp / NT) * 8 + xcd;
  int n0 = nt * 64, m0 = mt * 128;
  int elt = tid * 8;
  int arow = elt >> 5, acol = elt & 31;
  const bf16_t* Ag = A + (size_t)(m0 + arow) * K + acol;
  const bf16_t* Bg = B + (size_t)(n0 + arow) * K + acol;
  size_t hstep = (size_t)64 * K;
  int NS = K >> 5;
#define ISSUE(s) { bf16_t* st = smem + ((s) & 3) * 6144; int k0 = (s) * 32; \
    async16(Ag + k0, st + elt); async16(Ag + k0 + hstep, st + 2048 + elt); \
    async16(Bg + k0, st + 4096 + elt); }
  ISSUE(0); ISSUE(1); ISSUE(2);
  f32x4 acc[4][2] = {};
  int w = tid >> 6, l = tid & 63;
  int wm = (w >> 1) * 64, wn = (w & 1) * 32;
  int fr = l & 15, fk = (l >> 4) * 8;
  for (int i = 0; i < NS; i++) {
    int rem = NS - 1 - i;
    if (rem >= 2)      PIPE_SYNC("6");
    else if (rem == 1) PIPE_SYNC("3");
    else               PIPE_SYNC("0");
    if (i + 3 < NS) ISSUE(i + 3);
    const bf16_t* As = smem + (i & 3) * 6144;
    const bf16_t* Bs = As + 4096;
    bf16x8 af[4], bfr[2];
#pragma unroll
    for (int ii = 0; ii < 4; ii++) af[ii] = *(const bf16x8*)&As[(wm + ii * 16 + fr) * 32 + fk];
#pragma unroll
    for (int j = 0; j < 2; j++) bfr[j] = *(const bf16x8*)&Bs[(wn + j * 16 + fr) * 32 + fk];
#pragma unroll
    for (int ii = 0; ii < 4; ii++)
#pragma unroll
      for (int j = 0; j < 2; j++)
        acc[ii][j] = __builtin_amdgcn_mfma_f32_16x16x32_bf16(af[ii], bfr[j], acc[ii][j], 0, 0, 0);
  }
#undef ISSUE
  int cn = l & 15, cr = (l >> 4) * 4;
#pragma unroll
  for (int i = 0; i < 4; i++) {
#pragma unroll
    for (int r = 0; r < 4; r++) {
      int m = m0 + wm + i * 16 + cr + r;
#pragma unroll
      for (int j = 0; j < 2; j++) {
        int n = n0 + wn + j * 16 + cn;
        float v = acc[i][j][r];
        if (MODE == 0) {
          float p = mask[m] ? 0.f : 1.f;
          int seg = n >> 9, nn = n & 511;
          size_t o = (size_t)m * 512 + nn;
          if (seg == 0)      O0[o] = v > 0.f ? v + 1.f : expf(v);
          else if (seg == 1) O1[o] = (v > 0.f ? v + 1.f : expf(v)) * p;
          else               O2[o] = v * p;
        } else {
          float t = v + bias[n];
          Ob[(size_t)m * 2048 + n] = (bf16_t)(0.5f * t * (1.f + erff(t * 0.70710678118654752f)));
        }
      }
    }
  }
}

// ---------------------------------------------------------------- pipelined split-K GEMM (N=512)
template<int KPER>
__global__ __launch_bounds__(256) void mfma_gemm_pk(
    const bf16_t* __restrict__ A, const bf16_t* __restrict__ B, int Kst,
    float* __restrict__ P0, float* __restrict__ P1) {
  __shared__ __align__(16) bf16_t smem[4 * 6144];
  int tid = threadIdx.x;
  int bid = blockIdx.x;
  int xcd = bid & 7;
  int tmp = bid >> 3;
  int nt = tmp & 7;
  int mt = (tmp >> 3) * 8 + xcd;
  int n0 = nt * 64, m0 = mt * 128;
  int kb = blockIdx.y * KPER;
  float* P = blockIdx.y ? P1 : P0;
  int elt = tid * 8;
  int arow = elt >> 5, acol = elt & 31;
  const bf16_t* Ag = A + (size_t)(m0 + arow) * Kst + acol;
  const bf16_t* Bg = B + (size_t)(n0 + arow) * Kst + acol;
  size_t hstep = (size_t)64 * Kst;
  const int NS = KPER >> 5;
#define ISSUE(s) { bf16_t* st = smem + ((s) & 3) * 6144; int k0 = kb + (s) * 32; \
    async16(Ag + k0, st + elt); async16(Ag + k0 + hstep, st + 2048 + elt); \
    async16(Bg + k0, st + 4096 + elt); }
  ISSUE(0); ISSUE(1); ISSUE(2);
  f32x4 acc[4][2] = {};
  int w = tid >> 6, l = tid & 63;
  int wm = (w >> 1) * 64, wn = (w & 1) * 32;
  int fr = l & 15, fk = (l >> 4) * 8;
  for (int i = 0; i < NS; i++) {
    int rem = NS - 1 - i;
    if (rem >= 2)      PIPE_SYNC("6");
    else if (rem == 1) PIPE_SYNC("3");
    else               PIPE_SYNC("0");
    if (i + 3 < NS) ISSUE(i + 3);
    const bf16_t* As = smem + (i & 3) * 6144;
    const bf16_t* Bs = As + 4096;
    bf16x8 af[4], bfr[2];
#pragma unroll
    for (int ii = 0; ii < 4; ii++) af[ii] = *(const bf16x8*)&As[(wm + ii * 16 + fr) * 32 + fk];
#pragma unroll
    for (int j = 0; j < 2; j++) bfr[j] = *(const bf16x8*)&Bs[(wn + j * 16 + fr) * 32 + fk];
#pragma unroll
    for (int ii = 0; ii < 4; ii++)
#pragma unroll
      for (int j = 0; j < 2; j++)
        acc[ii][j] = __builtin_amdgcn_mfma_f32_16x16x32_bf16(af[ii], bfr[j], acc[ii][j], 0, 0, 0);
  }
#undef ISSUE
  int cn = l & 15, cr = (l >> 4) * 4;
#pragma unroll
  for (int i = 0; i < 4; i++)
#pragma unroll
    for (int r = 0; r < 4; r++) {
      int m = m0 + wm + i * 16 + cr + r;
#pragma unroll
      for (int j = 0; j < 2; j++) {
        int n = n0 + wn + j * 16 + cn;
        P[(size_t)m * 512 + n] = acc[i][j][r];
      }
    }
}

// ---------------------------------------------------------------- reduce 2 partials + bias + resid (fp32 out)
__global__ __launch_bounds__(256) void reduce2_kernel(
    const float* __restrict__ P0, const float* __restrict__ P1,
    const float* __restrict__ bias, const float* __restrict__ resid,
    float* __restrict__ o) {
  size_t idx = ((size_t)blockIdx.x * 256 + threadIdx.x) * 4;
  int n = (int)(idx & 511);
  float4 a = *(const float4*)(P0 + idx);
  float4 b = *(const float4*)(P1 + idx);
  float4 rr = *(const float4*)(resid + idx);
  float4 bi = *(const float4*)(bias + n);
  *(float4*)(o + idx) = make_float4(a.x + b.x + bi.x + rr.x, a.y + b.y + bi.y + rr.y,
                                    a.z + b.z + bi.z + rr.z, a.w + b.w + bi.w + rr.w);
}

// ---------------------------------------------------------------- reduce2 + LayerNorm fused
__global__ __launch_bounds__(256) void reduce_ln_kernel(
    const float* __restrict__ P0, const float* __restrict__ P1,
    const float* __restrict__ bias, const float* __restrict__ resid,
    float* __restrict__ x2, const float* __restrict__ g, const float* __restrict__ bb,
    bf16_t* __restrict__ out) {
  int row = blockIdx.x;
  int t = threadIdx.x;
  size_t o0 = (size_t)row * DD + t;
  size_t o1 = o0 + 256;
  float v0 = P0[o0] + P1[o0] + bias[t] + resid[o0];
  float v1 = P0[o1] + P1[o1] + bias[t + 256] + resid[o1];
  x2[o0] = v0; x2[o1] = v1;
  float s = v0 + v1, sq = v0 * v0 + v1 * v1;
  for (int o = 32; o; o >>= 1) { s += __shfl_down(s, o); sq += __shfl_down(sq, o); }
  __shared__ float red[8];
  __shared__ float mv[2];
  int w = t >> 6;
  if ((t & 63) == 0) { red[w] = s; red[4 + w] = sq; }
  __syncthreads();
  if (t == 0) {
    float S = red[0] + red[1] + red[2] + red[3];
    float Q = red[4] + red[5] + red[6] + red[7];
    float m = S * (1.f / 512.f);
    float var = Q * (1.f / 512.f) - m * m;
    mv[0] = m; mv[1] = rsqrtf(var + 1e-5f);
  }
  __syncthreads();
  float m = mv[0], r = mv[1];
  out[o0] = (bf16_t)((v0 - m) * r * g[t] + bb[t]);
  out[o1] = (bf16_t)((v1 - m) * r * g[t + 256] + bb[t + 256]);
}

// ------------------------------------------------- Phase A: chunk summaries, both dirs
__global__ __launch_bounds__(256) void chunk_summary_kernel(
    const float* __restrict__ Kb, const float* __restrict__ Vb,
    const float* __restrict__ dl, float* __restrict__ Sst, float* __restrict__ zst) {
  int chunk = blockIdx.x, bh = blockIdx.y;
  int b = bh >> 3, h = bh & 7;
  int t0 = chunk * CK;
  int tid = threadIdx.x;
  __shared__ __align__(16) float Ks[64][64];
  __shared__ __align__(16) float Vs[64][64];
  __shared__ float pw[72];
  float lam = 1.f / (1.f + expf(-dl[h]));
  if (tid <= 64) pw[tid] = powf(lam, (float)tid);
  int lrow = tid >> 2, lq = tid & 3;
  for (int q = 0; q < 4; q++) {
    int e = lq * 4 + q * 16;
    size_t g = ((size_t)(b * TT + t0 + lrow)) * DD + (size_t)h * 64 + e;
    *(float4*)&Ks[lrow][e] = *(const float4*)(Kb + g);
    *(float4*)&Vs[lrow][e] = *(const float4*)(Vb + g);
  }
  __syncthreads();
  int e1 = tid & 63;
  int e2b = (tid >> 6) * 16;
  float af_[16], ab_[16];
#pragma unroll
  for (int r = 0; r < 16; r++) { af_[r] = 0.f; ab_[r] = 0.f; }
  float zf = 0.f, zb = 0.f;
  for (int j = 0; j < 64; j++) {
    float kj = Ks[j][e1];
    float kf = pw[63 - j] * kj;
    float kb2 = pw[j] * kj;
    if (tid < 64) { zf += kf; zb += kb2; }
#pragma unroll
    for (int r = 0; r < 16; r++) {
      float v = Vs[j][e2b + r];
      af_[r] += kf * v;
      ab_[r] += kb2 * v;
    }
  }
  size_t bf_ = (((size_t)bh * NC + chunk) * 64 + e1) * 64 + e2b;
  size_t bb_ = ((((size_t)16 + bh) * NC + chunk) * 64 + e1) * 64 + e2b;
#pragma unroll
  for (int r = 0; r < 16; r += 4) {
    *(float4*)(Sst + bf_ + r) = make_float4(af_[r], af_[r + 1], af_[r + 2], af_[r + 3]);
    *(float4*)(Sst + bb_ + r) = make_float4(ab_[r], ab_[r + 1], ab_[r + 2], ab_[r + 3]);
  }
  if (tid < 64) {
    zst[((size_t)bh * NC + chunk) * 64 + tid] = zf;
    zst[(((size_t)16 + bh) * NC + chunk) * 64 + tid] = zb;
  }
}

// ------------------------------------------------- Phase B: scan over chunks (batched loads)
__global__ __launch_bounds__(1024) void scan_kernel(float* __restrict__ Sst,
                                                    float* __restrict__ zst,
                                                    const float* __restrict__ dl) {
  int bh = blockIdx.x, dir = blockIdx.y;
  int h = bh & 7;
  int tid = threadIdx.x;
  float lam = 1.f / (1.f + expf(-dl[h]));
  float lamC = powf(lam, 64.f);
  size_t base = ((size_t)dir * 16 + bh) * (size_t)NC * 4096 + (size_t)tid * 4;
  float4 S = make_float4(0.f, 0.f, 0.f, 0.f);
  for (int g = 0; g < 4; g++) {
    float4 L[8];
#pragma unroll
    for (int i = 0; i < 8; i++) {
      int s = g * 8 + i;
      int c = dir ? (NC - 1 - s) : s;
      L[i] = *(float4*)(Sst + base + (size_t)c * 4096);
    }
#pragma unroll
    for (int i = 0; i < 8; i++) {
      int s = g * 8 + i;
      int c = dir ? (NC - 1 - s) : s;
      S.x = S.x * lamC + L[i].x;
      S.y = S.y * lamC + L[i].y;
      S.z = S.z * lamC + L[i].z;
      S.w = S.w * lamC + L[i].w;
      *(float4*)(Sst + base + (size_t)c * 4096) = S;
    }
  }
  if (tid < 64) {
    size_t zb = ((size_t)dir * 16 + bh) * (size_t)NC * 64 + tid;
    float z = 0.f;
    for (int g = 0; g < 4; g++) {
      float zL[8];
#pragma unroll
      for (int i = 0; i < 8; i++) {
        int s = g * 8 + i;
        int c = dir ? (NC - 1 - s) : s;
        zL[i] = zst[zb + (size_t)c * 64];
      }
#pragma unroll
      for (int i = 0; i < 8; i++) {
        int s = g * 8 + i;
        int c = dir ? (NC - 1 - s) : s;
        z = z * lamC + zL[i];
        zst[zb + (size_t)c * 64] = z;
      }
    }
  }
}

// ------------------------------------------------- Phase C: fused chunk attention (both dirs + combine)
__global__ __launch_bounds__(256) void chunk_attn_kernel(
    const float* __restrict__ Qb, const float* __restrict__ Kb, const float* __restrict__ Vb,
    const float* __restrict__ Sst, const float* __restrict__ zst, const float* __restrict__ dl,
    bf16_t* __restrict__ attnb) {
  int chunk = blockIdx.x, bh = blockIdx.y;
  int b = bh >> 3, h = bh & 7;
  int t0 = chunk * CK;
  int tid = threadIdx.x;
  __shared__ __align__(16) float Qt[64][68];
  __shared__ __align__(16) float KtA[64][68];
  __shared__ __align__(16) float Vs[64][64];
  __shared__ __align__(16) float Sp[64][64];
  __shared__ float rowpart[64][16];
  __shared__ float zp[64];
  __shared__ float den[2][64];
  __shared__ float pw[72];
  float lam = 1.f / (1.f + expf(-dl[h]));
  if (tid <= 64) pw[tid] = powf(lam, (float)tid);
  int lrow = tid >> 2, lq = tid & 3;
  for (int q = 0; q < 4; q++) {
    int e = lq * 4 + q * 16;
    size_t g = ((size_t)(b * TT + t0 + lrow)) * DD + (size_t)h * 64 + e;
    float4 q4 = *(const float4*)(Qb + g);
    float4 k4 = *(const float4*)(Kb + g);
    float4 v4 = *(const float4*)(Vb + g);
    Qt[e][lrow] = q4.x; Qt[e + 1][lrow] = q4.y; Qt[e + 2][lrow] = q4.z; Qt[e + 3][lrow] = q4.w;
    KtA[e][lrow] = k4.x; KtA[e + 1][lrow] = k4.y; KtA[e + 2][lrow] = k4.z; KtA[e + 3][lrow] = k4.w;
    *(float4*)&Vs[lrow][e] = v4;
  }
  {
    int cs = chunk - 1;
    bool has = chunk > 0;
    if (has) {
      size_t sb = ((size_t)bh * NC + cs) * 4096;
      for (int q = 0; q < 4; q++) {
        int e = lq * 4 + q * 16;
        *(float4*)&Sp[lrow][e] = *(const float4*)(Sst + sb + (size_t)lrow * 64 + e);
      }
      if (tid < 64) zp[tid] = zst[((size_t)bh * NC + cs) * 64 + tid];
    } else {
      for (int q = 0; q < 4; q++) {
        int e = lq * 4 + q * 16;
        *(float4*)&Sp[lrow][e] = make_float4(0.f, 0.f, 0.f, 0.f);
      }
      if (tid < 64) zp[tid] = 0.f;
    }
  }
  __syncthreads();
  int tx = tid & 15, ty = tid >> 4;
  int i0 = ty * 4, j0 = tx * 4;
  int e0 = tx * 4;
  float acc[4][4] = {};
  for (int d = 0; d < 64; d++) {
    float4 qf = *(const float4*)&Qt[d][i0];
    float4 kf = *(const float4*)&KtA[d][j0];
    float qa[4] = {qf.x, qf.y, qf.z, qf.w};
    float ka[4] = {kf.x, kf.y, kf.z, kf.w};
#pragma unroll
    for (int r = 0; r < 4; r++)
#pragma unroll
      for (int c = 0; c < 4; c++) acc[r][c] += qa[r] * ka[c];
  }
  __syncthreads();
  float y[2][4][4];
  for (int dir = 0; dir < 2; dir++) {
    if (dir == 1) {
      int cs = chunk + 1;
      bool has = chunk < NC - 1;
      if (has) {
        size_t sb = (((size_t)16 + bh) * NC + cs) * 4096;
        for (int q = 0; q < 4; q++) {
          int e = lq * 4 + q * 16;
          *(float4*)&Sp[lrow][e] = *(const float4*)(Sst + sb + (size_t)lrow * 64 + e);
        }
        if (tid < 64) zp[tid] = zst[(((size_t)16 + bh) * NC + cs) * 64 + tid];
      } else {
        for (int q = 0; q < 4; q++) {
          int e = lq * 4 + q * 16;
          *(float4*)&Sp[lrow][e] = make_float4(0.f, 0.f, 0.f, 0.f);
        }
        if (tid < 64) zp[tid] = 0.f;
      }
    }
    float rs[4] = {0.f, 0.f, 0.f, 0.f};
    float colv[4][4];
#pragma unroll
    for (int r = 0; r < 4; r++) {
      int i = i0 + r;
#pragma unroll
      for (int c = 0; c < 4; c++) {
        int j = j0 + c;
        float v;
        if (dir == 0) v = (j <= i) ? acc[r][c] * pw[i - j] : 0.f;
        else          v = (j >= i) ? acc[r][c] * pw[j - i] : 0.f;
        if (i == j) v *= 0.5f;
        rs[r] += v;
        colv[c][r] = v;
      }
    }
#pragma unroll
    for (int c = 0; c < 4; c++)
      *(float4*)&KtA[j0 + c][i0] = make_float4(colv[c][0], colv[c][1], colv[c][2], colv[c][3]);
#pragma unroll
    for (int r = 0; r < 4; r++) rowpart[i0 + r][tx] = rs[r];
    __syncthreads();
    float accY[4][4] = {}, accS[4][4] = {};
    for (int j = 0; j < 64; j++) {
      float4 af = *(const float4*)&KtA[j][i0];
      float4 vf = *(const float4*)&Vs[j][e0];
      float aa[4] = {af.x, af.y, af.z, af.w};
      float vv[4] = {vf.x, vf.y, vf.z, vf.w};
#pragma unroll
      for (int r = 0; r < 4; r++)
#pragma unroll
        for (int c = 0; c < 4; c++) accY[r][c] += aa[r] * vv[c];
    }
    for (int d = 0; d < 64; d++) {
      float4 qf = *(const float4*)&Qt[d][i0];
      float4 sf = *(const float4*)&Sp[d][e0];
      float qq[4] = {qf.x, qf.y, qf.z, qf.w};
      float ss[4] = {sf.x, sf.y, sf.z, sf.w};
#pragma unroll
      for (int r = 0; r < 4; r++)
#pragma unroll
        for (int c = 0; c < 4; c++) accS[r][c] += qq[r] * ss[c];
    }
#pragma unroll
    for (int r = 0; r < 4; r++) {
      int i = i0 + r;
      float lr = dir ? pw[64 - i] : pw[i + 1];
#pragma unroll
      for (int c = 0; c < 4; c++) y[dir][r][c] = accY[r][c] + lr * accS[r][c];
    }
    if (tid < 64) {
      int i = tid;
      float s = 0.f;
#pragma unroll
      for (int xx = 0; xx < 16; xx++) s += rowpart[i][xx];
      float cz = 0.f;
      for (int d = 0; d < 64; d++) cz += Qt[d][i] * zp[d];
      float lr = dir ? pw[64 - i] : pw[i + 1];
      den[dir][i] = s + lr * cz;
    }
    __syncthreads();
  }
#pragma unroll
  for (int r = 0; r < 4; r++) {
    int i = i0 + r;
    float dd = fmaxf(den[0][i] + den[1][i], 1e-6f);
    float inv = 1.f / dd;
    bf16x4 o;
#pragma unroll
    for (int c = 0; c < 4; c++) o[c] = (bf16_t)((y[0][r][c] + y[1][r][c]) * inv);
    *(bf16x4*)(attnb + ((size_t)(b * TT + t0 + i)) * DD + (size_t)h * 64 + e0) = o;
  }
}

// ---------------------------------------------------------------- launch
extern "C" void kernel_launch(void* const* d_in, const int* in_sizes, int n_in,
                              void* d_out, int out_size, void* d_ws, size_t ws_size,
                              hipStream_t stream) {
  const float* x   = (const float*)d_in[0];
  const unsigned char* mask = (const unsigned char*)d_in[1];
  const float* Wq  = (const float*)d_in[2];
  const float* Wk  = (const float*)d_in[3];
  const float* Wv  = (const float*)d_in[4];
  const float* Wo  = (const float*)d_in[5];
  const float* bo  = (const float*)d_in[6];
  const float* g1  = (const float*)d_in[7];
  const float* b1  = (const float*)d_in[8];
  const float* g2  = (const float*)d_in[9];
  const float* b2  = (const float*)d_in[10];
  const float* W1  = (const float*)d_in[11];
  const float* bf1 = (const float*)d_in[12];
  const float* W2  = (const float*)d_in[13];
  const float* bf2 = (const float*)d_in[14];
  const float* dl  = (const float*)d_in[15];
  float* out = (float*)d_out;

  float* ws = (float*)d_ws;
  const size_t U = (size_t)BT * DD;  // 2097152 floats
  float* Qf  = ws;
  float* Kf  = ws + U;
  float* Vf  = ws + 2 * U;
  float* R3  = ws + 3 * U;
  float* R4  = ws + 4 * U;
  float* x2  = ws + 5 * U;
  float* Sst = ws + 6 * U;
  float* zst = ws + 8 * U;
  bf16_t* wall = (bf16_t*)(ws + 8 * U + 131072);
  bf16_t* xnb   = (bf16_t*)R3;
  bf16_t* attnb = (bf16_t*)x2;
  bf16_t* h2b   = (bf16_t*)Qf;
  bf16_t* ffn1b = (bf16_t*)Kf;
  bf16_t* Wob = wall + 786432;
  bf16_t* W1b = wall + 1048576;
  bf16_t* W2b = wall + 2097152;
  float* Ps0 = R3;
  float* Ps1 = R4;

  ln_cast_kernel<<<BT + 1536, 256, 0, stream>>>(x, g1, b1, xnb, Wq, Wk, Wv, Wo, W1, W2, wall);
  // QKV: M=4096 N=1536 K=512 -> NT=24, 24*32 = 768 blocks  (round-5 bug: was 384/NT=12)
  mfma_gemm<0><<<768, 256, 0, stream>>>(xnb, wall, 512, 24, Qf, Kf, Vf,
                                        nullptr, nullptr, mask);
  chunk_summary_kernel<<<dim3(NC, 16), 256, 0, stream>>>(Kf, Vf, dl, Sst, zst);
  scan_kernel<<<dim3(16, 2), 1024, 0, stream>>>(Sst, zst, dl);
  chunk_attn_kernel<<<dim3(NC, 16), 256, 0, stream>>>(Qf, Kf, Vf, Sst, zst, dl, attnb);
  mfma_gemm_pk<256><<<dim3(256, 2), 256, 0, stream>>>(attnb, Wob, 512, Ps0, Ps1);
  reduce_ln_kernel<<<BT, 256, 0, stream>>>(Ps0, Ps1, bo, x, x2, g2, b2, h2b);
  mfma_gemm<2><<<1024, 256, 0, stream>>>(h2b, W1b, 512, 32, nullptr,
                                         nullptr, nullptr, ffn1b, bf1, nullptr);
  mfma_gemm_pk<1024><<<dim3(256, 2), 256, 0, stream>>>(ffn1b, W2b, 2048, Ps0, Ps1);
  reduce2_kernel<<<2048, 256, 0, stream>>>(Ps0, Ps1, bf2, x2, out);
}

// Round 9
// 229.732 us; speedup vs baseline: 2.5628x; 1.0036x over previous
//
#include <hip/hip_runtime.h>
#include <math.h>

#define BB 2
#define TT 2048
#define DD 512
#define FF 2048
#define HH 8
#define BT 4096      // BB*TT
#define NC 32        // TT/64 chunks
#define CK 64        // chunk size

typedef __bf16 bf16_t;
typedef bf16_t bf16x8 __attribute__((ext_vector_type(8)));
typedef bf16_t bf16x4 __attribute__((ext_vector_type(4)));
typedef float f32x4 __attribute__((ext_vector_type(4)));

typedef const __attribute__((address_space(1))) void* gas_p;
typedef __attribute__((address_space(3))) void* las_p;

__device__ __forceinline__ void async16(const void* g, void* l) {
  __builtin_amdgcn_global_load_lds((gas_p)g, (las_p)l, 16, 0, 0);
}

// Pipelined barrier: partial-vmcnt wait + s_barrier as ONE asm block with a
// "memory" clobber (compiler-level fence). lgkmcnt(0) drains this wave's
// ds_reads so the (i-1) stage may be overwritten after the barrier; vmcnt(N)
// keeps prefetch DMA in flight across the barrier.
#define PIPE_SYNC(vm) asm volatile("s_waitcnt lgkmcnt(0) vmcnt(" vm ")\n\ts_barrier" ::: "memory")

// ---------------------------------------------------------------- LN1 + weight cast fused
__global__ __launch_bounds__(256) void ln_cast_kernel(
    const float* __restrict__ x, const float* __restrict__ g, const float* __restrict__ bb,
    bf16_t* __restrict__ out,
    const float* __restrict__ Wq, const float* __restrict__ Wk,
    const float* __restrict__ Wv, const float* __restrict__ Wo,
    const float* __restrict__ W1, const float* __restrict__ W2,
    bf16_t* __restrict__ wdst) {
  int t = threadIdx.x;
  if (blockIdx.x >= BT) {
    size_t i = ((size_t)(blockIdx.x - BT) * 256 + t) * 8;
    const float* src; size_t off;
    if (i < 262144)       { src = Wq; off = i; }
    else if (i < 524288)  { src = Wk; off = i - 262144; }
    else if (i < 786432)  { src = Wv; off = i - 524288; }
    else if (i < 1048576) { src = Wo; off = i - 786432; }
    else if (i < 2097152) { src = W1; off = i - 1048576; }
    else                  { src = W2; off = i - 2097152; }
    float4 a = *(const float4*)(src + off);
    float4 b = *(const float4*)(src + off + 4);
    bf16x8 o;
    o[0] = (bf16_t)a.x; o[1] = (bf16_t)a.y; o[2] = (bf16_t)a.z; o[3] = (bf16_t)a.w;
    o[4] = (bf16_t)b.x; o[5] = (bf16_t)b.y; o[6] = (bf16_t)b.z; o[7] = (bf16_t)b.w;
    *(bf16x8*)(wdst + i) = o;
    return;
  }
  int row = blockIdx.x;
  const float* xr = x + (size_t)row * DD;
  float v0 = xr[t], v1 = xr[t + 256];
  float s = v0 + v1, sq = v0 * v0 + v1 * v1;
  for (int o = 32; o; o >>= 1) { s += __shfl_down(s, o); sq += __shfl_down(sq, o); }
  __shared__ float red[8];
  __shared__ float mv[2];
  int w = t >> 6;
  if ((t & 63) == 0) { red[w] = s; red[4 + w] = sq; }
  __syncthreads();
  if (t == 0) {
    float S = red[0] + red[1] + red[2] + red[3];
    float Q = red[4] + red[5] + red[6] + red[7];
    float m = S * (1.f / 512.f);
    float var = Q * (1.f / 512.f) - m * m;
    mv[0] = m; mv[1] = rsqrtf(var + 1e-5f);
  }
  __syncthreads();
  float m = mv[0], r = mv[1];
  out[(size_t)row * DD + t]       = (bf16_t)((v0 - m) * r * g[t] + bb[t]);
  out[(size_t)row * DD + t + 256] = (bf16_t)((v1 - m) * r * g[t + 256] + bb[t + 256]);
}

// ---------------------------------------------------------------- pipelined MFMA GEMM  C = A*B^T
// 128(M)x128(N) block tile, 64x64 wave tile (16 MFMA / 8 ds_read_b128), BK=32,
// 3 LDS stages (48KB), prefetch depth 2, XCD-swizzled 1D grid of 32*NT blocks.
// MODE 0: QKV epilogue -> bf16 Q/K/V (elu+1 / pad). MODE 2: bf16 gelu(acc+bias).
template<int MODE>
__global__ __launch_bounds__(256) void mfma_gemm(
    const bf16_t* __restrict__ A, const bf16_t* __restrict__ B, int K, int NT,
    bf16_t* __restrict__ Qo, bf16_t* __restrict__ Ko, bf16_t* __restrict__ Vo,
    bf16_t* __restrict__ Ob, const float* __restrict__ bias,
    const unsigned char* __restrict__ mask) {
  __shared__ __align__(16) bf16_t smem[3 * 8192];   // stage: A[128][32] + B[128][32]
  int tid = threadIdx.x;
  int bid = blockIdx.x;
  int xcd = bid & 7;
  int tmp = bid >> 3;
  int nt = tmp % NT;
  int mt = (tmp / NT) * 8 + xcd;
  int n0 = nt * 128, m0 = mt * 128;
  int elt = tid * 8;
  int srow = elt >> 5, scol = elt & 31;
  const bf16_t* Ag = A + (size_t)(m0 + srow) * K + scol;
  const bf16_t* Bg = B + (size_t)(n0 + srow) * K + scol;
  size_t hstep = (size_t)64 * K;
  int NS = K >> 5;
#define ISSUE(s) { bf16_t* st = smem + ((s) % 3) * 8192; int k0 = (s) * 32; \
    async16(Ag + k0, st + elt); async16(Ag + k0 + hstep, st + 2048 + elt); \
    async16(Bg + k0, st + 4096 + elt); async16(Bg + k0 + hstep, st + 6144 + elt); }
  ISSUE(0); ISSUE(1);
  f32x4 acc[4][4] = {};
  int w = tid >> 6, l = tid & 63;
  int wm = (w >> 1) * 64, wn = (w & 1) * 64;
  int fr = l & 15, fk = (l >> 4) * 8;
  for (int i = 0; i < NS; i++) {
    if (i < NS - 1) PIPE_SYNC("4");
    else            PIPE_SYNC("0");
    if (i + 2 < NS) ISSUE(i + 2);
    const bf16_t* As = smem + (i % 3) * 8192;
    const bf16_t* Bs = As + 4096;
    bf16x8 af[4], bfr[4];
#pragma unroll
    for (int ii = 0; ii < 4; ii++) af[ii] = *(const bf16x8*)&As[(wm + ii * 16 + fr) * 32 + fk];
#pragma unroll
    for (int j = 0; j < 4; j++) bfr[j] = *(const bf16x8*)&Bs[(wn + j * 16 + fr) * 32 + fk];
#pragma unroll
    for (int ii = 0; ii < 4; ii++)
#pragma unroll
      for (int j = 0; j < 4; j++)
        acc[ii][j] = __builtin_amdgcn_mfma_f32_16x16x32_bf16(af[ii], bfr[j], acc[ii][j], 0, 0, 0);
  }
#undef ISSUE
  int cn = l & 15, cr = (l >> 4) * 4;
#pragma unroll
  for (int i = 0; i < 4; i++) {
#pragma unroll
    for (int r = 0; r < 4; r++) {
      int m = m0 + wm + i * 16 + cr + r;
#pragma unroll
      for (int j = 0; j < 4; j++) {
        int n = n0 + wn + j * 16 + cn;
        float v = acc[i][j][r];
        if (MODE == 0) {
          float p = mask[m] ? 0.f : 1.f;
          int seg = n >> 9, nn = n & 511;
          size_t o = (size_t)m * 512 + nn;
          if (seg == 0)      Qo[o] = (bf16_t)(v > 0.f ? v + 1.f : expf(v));
          else if (seg == 1) Ko[o] = (bf16_t)((v > 0.f ? v + 1.f : expf(v)) * p);
          else               Vo[o] = (bf16_t)(v * p);
        } else {
          float t = v + bias[n];
          Ob[(size_t)m * 2048 + n] = (bf16_t)(0.5f * t * (1.f + erff(t * 0.70710678118654752f)));
        }
      }
    }
  }
}

// ---------------------------------------------------------------- pipelined split-K GEMM (N=512)
// 128x64 tile, 4 LDS stages, depth-3 — unchanged from round 8 (passing).
template<int KPER>
__global__ __launch_bounds__(256) void mfma_gemm_pk(
    const bf16_t* __restrict__ A, const bf16_t* __restrict__ B, int Kst,
    float* __restrict__ P0, float* __restrict__ P1) {
  __shared__ __align__(16) bf16_t smem[4 * 6144];
  int tid = threadIdx.x;
  int bid = blockIdx.x;
  int xcd = bid & 7;
  int tmp = bid >> 3;
  int nt = tmp & 7;
  int mt = (tmp >> 3) * 8 + xcd;
  int n0 = nt * 64, m0 = mt * 128;
  int kb = blockIdx.y * KPER;
  float* P = blockIdx.y ? P1 : P0;
  int elt = tid * 8;
  int arow = elt >> 5, acol = elt & 31;
  const bf16_t* Ag = A + (size_t)(m0 + arow) * Kst + acol;
  const bf16_t* Bg = B + (size_t)(n0 + arow) * Kst + acol;
  size_t hstep = (size_t)64 * Kst;
  const int NS = KPER >> 5;
#define ISSUE(s) { bf16_t* st = smem + ((s) & 3) * 6144; int k0 = kb + (s) * 32; \
    async16(Ag + k0, st + elt); async16(Ag + k0 + hstep, st + 2048 + elt); \
    async16(Bg + k0, st + 4096 + elt); }
  ISSUE(0); ISSUE(1); ISSUE(2);
  f32x4 acc[4][2] = {};
  int w = tid >> 6, l = tid & 63;
  int wm = (w >> 1) * 64, wn = (w & 1) * 32;
  int fr = l & 15, fk = (l >> 4) * 8;
  for (int i = 0; i < NS; i++) {
    int rem = NS - 1 - i;
    if (rem >= 2)      PIPE_SYNC("6");
    else if (rem == 1) PIPE_SYNC("3");
    else               PIPE_SYNC("0");
    if (i + 3 < NS) ISSUE(i + 3);
    const bf16_t* As = smem + (i & 3) * 6144;
    const bf16_t* Bs = As + 4096;
    bf16x8 af[4], bfr[2];
#pragma unroll
    for (int ii = 0; ii < 4; ii++) af[ii] = *(const bf16x8*)&As[(wm + ii * 16 + fr) * 32 + fk];
#pragma unroll
    for (int j = 0; j < 2; j++) bfr[j] = *(const bf16x8*)&Bs[(wn + j * 16 + fr) * 32 + fk];
#pragma unroll
    for (int ii = 0; ii < 4; ii++)
#pragma unroll
      for (int j = 0; j < 2; j++)
        acc[ii][j] = __builtin_amdgcn_mfma_f32_16x16x32_bf16(af[ii], bfr[j], acc[ii][j], 0, 0, 0);
  }
#undef ISSUE
  int cn = l & 15, cr = (l >> 4) * 4;
#pragma unroll
  for (int i = 0; i < 4; i++)
#pragma unroll
    for (int r = 0; r < 4; r++) {
      int m = m0 + wm + i * 16 + cr + r;
#pragma unroll
      for (int j = 0; j < 2; j++) {
        int n = n0 + wn + j * 16 + cn;
        P[(size_t)m * 512 + n] = acc[i][j][r];
      }
    }
}

// ---------------------------------------------------------------- reduce 2 partials + bias + resid (fp32 out)
__global__ __launch_bounds__(256) void reduce2_kernel(
    const float* __restrict__ P0, const float* __restrict__ P1,
    const float* __restrict__ bias, const float* __restrict__ resid,
    float* __restrict__ o) {
  size_t idx = ((size_t)blockIdx.x * 256 + threadIdx.x) * 4;
  int n = (int)(idx & 511);
  float4 a = *(const float4*)(P0 + idx);
  float4 b = *(const float4*)(P1 + idx);
  float4 rr = *(const float4*)(resid + idx);
  float4 bi = *(const float4*)(bias + n);
  *(float4*)(o + idx) = make_float4(a.x + b.x + bi.x + rr.x, a.y + b.y + bi.y + rr.y,
                                    a.z + b.z + bi.z + rr.z, a.w + b.w + bi.w + rr.w);
}

// ---------------------------------------------------------------- reduce2 + LayerNorm fused
__global__ __launch_bounds__(256) void reduce_ln_kernel(
    const float* __restrict__ P0, const float* __restrict__ P1,
    const float* __restrict__ bias, const float* __restrict__ resid,
    float* __restrict__ x2, const float* __restrict__ g, const float* __restrict__ bb,
    bf16_t* __restrict__ out) {
  int row = blockIdx.x;
  int t = threadIdx.x;
  size_t o0 = (size_t)row * DD + t;
  size_t o1 = o0 + 256;
  float v0 = P0[o0] + P1[o0] + bias[t] + resid[o0];
  float v1 = P0[o1] + P1[o1] + bias[t + 256] + resid[o1];
  x2[o0] = v0; x2[o1] = v1;
  float s = v0 + v1, sq = v0 * v0 + v1 * v1;
  for (int o = 32; o; o >>= 1) { s += __shfl_down(s, o); sq += __shfl_down(sq, o); }
  __shared__ float red[8];
  __shared__ float mv[2];
  int w = t >> 6;
  if ((t & 63) == 0) { red[w] = s; red[4 + w] = sq; }
  __syncthreads();
  if (t == 0) {
    float S = red[0] + red[1] + red[2] + red[3];
    float Q = red[4] + red[5] + red[6] + red[7];
    float m = S * (1.f / 512.f);
    float var = Q * (1.f / 512.f) - m * m;
    mv[0] = m; mv[1] = rsqrtf(var + 1e-5f);
  }
  __syncthreads();
  float m = mv[0], r = mv[1];
  out[o0] = (bf16_t)((v0 - m) * r * g[t] + bb[t]);
  out[o1] = (bf16_t)((v1 - m) * r * g[t + 256] + bb[t + 256]);
}

// ------------------------------------------------- Phase A: chunk summaries, both dirs (bf16 K/V in)
__global__ __launch_bounds__(256) void chunk_summary_kernel(
    const bf16_t* __restrict__ Kb, const bf16_t* __restrict__ Vb,
    const float* __restrict__ dl, float* __restrict__ Sst, float* __restrict__ zst) {
  int chunk = blockIdx.x, bh = blockIdx.y;
  int b = bh >> 3, h = bh & 7;
  int t0 = chunk * CK;
  int tid = threadIdx.x;
  __shared__ __align__(16) float Ks[64][64];
  __shared__ __align__(16) float Vs[64][64];
  __shared__ float pw[72];
  float lam = 1.f / (1.f + expf(-dl[h]));
  if (tid <= 64) pw[tid] = powf(lam, (float)tid);
  int lrow = tid >> 2, lq = tid & 3;
  for (int q = 0; q < 2; q++) {
    int c = lq * 16 + q * 8;
    size_t g = ((size_t)(b * TT + t0 + lrow)) * DD + (size_t)h * 64 + c;
    bf16x8 k8 = *(const bf16x8*)(Kb + g);
    bf16x8 v8 = *(const bf16x8*)(Vb + g);
#pragma unroll
    for (int u = 0; u < 8; u++) { Ks[lrow][c + u] = (float)k8[u]; Vs[lrow][c + u] = (float)v8[u]; }
  }
  __syncthreads();
  int e1 = tid & 63;
  int e2b = (tid >> 6) * 16;
  float af_[16], ab_[16];
#pragma unroll
  for (int r = 0; r < 16; r++) { af_[r] = 0.f; ab_[r] = 0.f; }
  float zf = 0.f, zb = 0.f;
  for (int j = 0; j < 64; j++) {
    float kj = Ks[j][e1];
    float kf = pw[63 - j] * kj;
    float kb2 = pw[j] * kj;
    if (tid < 64) { zf += kf; zb += kb2; }
#pragma unroll
    for (int r = 0; r < 16; r++) {
      float v = Vs[j][e2b + r];
      af_[r] += kf * v;
      ab_[r] += kb2 * v;
    }
  }
  size_t bf_ = (((size_t)bh * NC + chunk) * 64 + e1) * 64 + e2b;
  size_t bb_ = ((((size_t)16 + bh) * NC + chunk) * 64 + e1) * 64 + e2b;
#pragma unroll
  for (int r = 0; r < 16; r += 4) {
    *(float4*)(Sst + bf_ + r) = make_float4(af_[r], af_[r + 1], af_[r + 2], af_[r + 3]);
    *(float4*)(Sst + bb_ + r) = make_float4(ab_[r], ab_[r + 1], ab_[r + 2], ab_[r + 3]);
  }
  if (tid < 64) {
    zst[((size_t)bh * NC + chunk) * 64 + tid] = zf;
    zst[(((size_t)16 + bh) * NC + chunk) * 64 + tid] = zb;
  }
}

// ------------------------------------------------- Phase B: scan over chunks (batched loads)
__global__ __launch_bounds__(1024) void scan_kernel(float* __restrict__ Sst,
                                                    float* __restrict__ zst,
                                                    const float* __restrict__ dl) {
  int bh = blockIdx.x, dir = blockIdx.y;
  int h = bh & 7;
  int tid = threadIdx.x;
  float lam = 1.f / (1.f + expf(-dl[h]));
  float lamC = powf(lam, 64.f);
  size_t base = ((size_t)dir * 16 + bh) * (size_t)NC * 4096 + (size_t)tid * 4;
  float4 S = make_float4(0.f, 0.f, 0.f, 0.f);
  for (int g = 0; g < 4; g++) {
    float4 L[8];
#pragma unroll
    for (int i = 0; i < 8; i++) {
      int s = g * 8 + i;
      int c = dir ? (NC - 1 - s) : s;
      L[i] = *(float4*)(Sst + base + (size_t)c * 4096);
    }
#pragma unroll
    for (int i = 0; i < 8; i++) {
      int s = g * 8 + i;
      int c = dir ? (NC - 1 - s) : s;
      S.x = S.x * lamC + L[i].x;
      S.y = S.y * lamC + L[i].y;
      S.z = S.z * lamC + L[i].z;
      S.w = S.w * lamC + L[i].w;
      *(float4*)(Sst + base + (size_t)c * 4096) = S;
    }
  }
  if (tid < 64) {
    size_t zb = ((size_t)dir * 16 + bh) * (size_t)NC * 64 + tid;
    float z = 0.f;
    for (int g = 0; g < 4; g++) {
      float zL[8];
#pragma unroll
      for (int i = 0; i < 8; i++) {
        int s = g * 8 + i;
        int c = dir ? (NC - 1 - s) : s;
        zL[i] = zst[zb + (size_t)c * 64];
      }
#pragma unroll
      for (int i = 0; i < 8; i++) {
        int s = g * 8 + i;
        int c = dir ? (NC - 1 - s) : s;
        z = z * lamC + zL[i];
        zst[zb + (size_t)c * 64] = z;
      }
    }
  }
}

// ------------------------------------------------- Phase C: fused chunk attention (both dirs + combine, bf16 in)
__global__ __launch_bounds__(256) void chunk_attn_kernel(
    const bf16_t* __restrict__ Qb, const bf16_t* __restrict__ Kb, const bf16_t* __restrict__ Vb,
    const float* __restrict__ Sst, const float* __restrict__ zst, const float* __restrict__ dl,
    bf16_t* __restrict__ attnb) {
  int chunk = blockIdx.x, bh = blockIdx.y;
  int b = bh >> 3, h = bh & 7;
  int t0 = chunk * CK;
  int tid = threadIdx.x;
  __shared__ __align__(16) float Qt[64][68];
  __shared__ __align__(16) float KtA[64][68];
  __shared__ __align__(16) float Vs[64][64];
  __shared__ __align__(16) float Sp[64][64];
  __shared__ float rowpart[64][16];
  __shared__ float zp[64];
  __shared__ float den[2][64];
  __shared__ float pw[72];
  float lam = 1.f / (1.f + expf(-dl[h]));
  if (tid <= 64) pw[tid] = powf(lam, (float)tid);
  int lrow = tid >> 2, lq = tid & 3;
  for (int q = 0; q < 2; q++) {
    int c = lq * 16 + q * 8;
    size_t g = ((size_t)(b * TT + t0 + lrow)) * DD + (size_t)h * 64 + c;
    bf16x8 q8 = *(const bf16x8*)(Qb + g);
    bf16x8 k8 = *(const bf16x8*)(Kb + g);
    bf16x8 v8 = *(const bf16x8*)(Vb + g);
#pragma unroll
    for (int u = 0; u < 8; u++) {
      Qt[c + u][lrow] = (float)q8[u];
      KtA[c + u][lrow] = (float)k8[u];
      Vs[lrow][c + u] = (float)v8[u];
    }
  }
  {
    int cs = chunk - 1;
    bool has = chunk > 0;
    if (has) {
      size_t sb = ((size_t)bh * NC + cs) * 4096;
      for (int q = 0; q < 4; q++) {
        int e = (tid & 3) * 4 + q * 16;
        *(float4*)&Sp[lrow][e] = *(const float4*)(Sst + sb + (size_t)lrow * 64 + e);
      }
      if (tid < 64) zp[tid] = zst[((size_t)bh * NC + cs) * 64 + tid];
    } else {
      for (int q = 0; q < 4; q++) {
        int e = (tid & 3) * 4 + q * 16;
        *(float4*)&Sp[lrow][e] = make_float4(0.f, 0.f, 0.f, 0.f);
      }
      if (tid < 64) zp[tid] = 0.f;
    }
  }
  __syncthreads();
  int tx = tid & 15, ty = tid >> 4;
  int i0 = ty * 4, j0 = tx * 4;
  int e0 = tx * 4;
  float acc[4][4] = {};
  for (int d = 0; d < 64; d++) {
    float4 qf = *(const float4*)&Qt[d][i0];
    float4 kf = *(const float4*)&KtA[d][j0];
    float qa[4] = {qf.x, qf.y, qf.z, qf.w};
    float ka[4] = {kf.x, kf.y, kf.z, kf.w};
#pragma unroll
    for (int r = 0; r < 4; r++)
#pragma unroll
      for (int c = 0; c < 4; c++) acc[r][c] += qa[r] * ka[c];
  }
  __syncthreads();
  float y[2][4][4];
  for (int dir = 0; dir < 2; dir++) {
    if (dir == 1) {
      int cs = chunk + 1;
      bool has = chunk < NC - 1;
      if (has) {
        size_t sb = (((size_t)16 + bh) * NC + cs) * 4096;
        for (int q = 0; q < 4; q++) {
          int e = (tid & 3) * 4 + q * 16;
          *(float4*)&Sp[lrow][e] = *(const float4*)(Sst + sb + (size_t)lrow * 64 + e);
        }
        if (tid < 64) zp[tid] = zst[(((size_t)16 + bh) * NC + cs) * 64 + tid];
      } else {
        for (int q = 0; q < 4; q++) {
          int e = (tid & 3) * 4 + q * 16;
          *(float4*)&Sp[lrow][e] = make_float4(0.f, 0.f, 0.f, 0.f);
        }
        if (tid < 64) zp[tid] = 0.f;
      }
    }
    float rs[4] = {0.f, 0.f, 0.f, 0.f};
    float colv[4][4];
#pragma unroll
    for (int r = 0; r < 4; r++) {
      int i = i0 + r;
#pragma unroll
      for (int c = 0; c < 4; c++) {
        int j = j0 + c;
        float v;
        if (dir == 0) v = (j <= i) ? acc[r][c] * pw[i - j] : 0.f;
        else          v = (j >= i) ? acc[r][c] * pw[j - i] : 0.f;
        if (i == j) v *= 0.5f;
        rs[r] += v;
        colv[c][r] = v;
      }
    }
#pragma unroll
    for (int c = 0; c < 4; c++)
      *(float4*)&KtA[j0 + c][i0] = make_float4(colv[c][0], colv[c][1], colv[c][2], colv[c][3]);
#pragma unroll
    for (int r = 0; r < 4; r++) rowpart[i0 + r][tx] = rs[r];
    __syncthreads();
    float accY[4][4] = {}, accS[4][4] = {};
    for (int j = 0; j < 64; j++) {
      float4 af = *(const float4*)&KtA[j][i0];
      float4 vf = *(const float4*)&Vs[j][e0];
      float aa[4] = {af.x, af.y, af.z, af.w};
      float vv[4] = {vf.x, vf.y, vf.z, vf.w};
#pragma unroll
      for (int r = 0; r < 4; r++)
#pragma unroll
        for (int c = 0; c < 4; c++) accY[r][c] += aa[r] * vv[c];
    }
    for (int d = 0; d < 64; d++) {
      float4 qf = *(const float4*)&Qt[d][i0];
      float4 sf = *(const float4*)&Sp[d][e0];
      float qq[4] = {qf.x, qf.y, qf.z, qf.w};
      float ss[4] = {sf.x, sf.y, sf.z, sf.w};
#pragma unroll
      for (int r = 0; r < 4; r++)
#pragma unroll
        for (int c = 0; c < 4; c++) accS[r][c] += qq[r] * ss[c];
    }
#pragma unroll
    for (int r = 0; r < 4; r++) {
      int i = i0 + r;
      float lr = dir ? pw[64 - i] : pw[i + 1];
#pragma unroll
      for (int c = 0; c < 4; c++) y[dir][r][c] = accY[r][c] + lr * accS[r][c];
    }
    if (tid < 64) {
      int i = tid;
      float s = 0.f;
#pragma unroll
      for (int xx = 0; xx < 16; xx++) s += rowpart[i][xx];
      float cz = 0.f;
      for (int d = 0; d < 64; d++) cz += Qt[d][i] * zp[d];
      float lr = dir ? pw[64 - i] : pw[i + 1];
      den[dir][i] = s + lr * cz;
    }
    __syncthreads();
  }
#pragma unroll
  for (int r = 0; r < 4; r++) {
    int i = i0 + r;
    float dd = fmaxf(den[0][i] + den[1][i], 1e-6f);
    float inv = 1.f / dd;
    bf16x4 o;
#pragma unroll
    for (int c = 0; c < 4; c++) o[c] = (bf16_t)((y[0][r][c] + y[1][r][c]) * inv);
    *(bf16x4*)(attnb + ((size_t)(b * TT + t0 + i)) * DD + (size_t)h * 64 + e0) = o;
  }
}

// ---------------------------------------------------------------- launch
extern "C" void kernel_launch(void* const* d_in, const int* in_sizes, int n_in,
                              void* d_out, int out_size, void* d_ws, size_t ws_size,
                              hipStream_t stream) {
  const float* x   = (const float*)d_in[0];
  const unsigned char* mask = (const unsigned char*)d_in[1];
  const float* Wq  = (const float*)d_in[2];
  const float* Wk  = (const float*)d_in[3];
  const float* Wv  = (const float*)d_in[4];
  const float* Wo  = (const float*)d_in[5];
  const float* bo  = (const float*)d_in[6];
  const float* g1  = (const float*)d_in[7];
  const float* b1  = (const float*)d_in[8];
  const float* g2  = (const float*)d_in[9];
  const float* b2  = (const float*)d_in[10];
  const float* W1  = (const float*)d_in[11];
  const float* bf1 = (const float*)d_in[12];
  const float* W2  = (const float*)d_in[13];
  const float* bf2 = (const float*)d_in[14];
  const float* dl  = (const float*)d_in[15];
  float* out = (float*)d_out;

  float* ws = (float*)d_ws;
  const size_t U = (size_t)BT * DD;  // 2097152 floats
  float* Qr  = ws;            // bf16 Q features (half-used region)
  float* Kr  = ws + U;
  float* Vr  = ws + 2 * U;
  float* R3  = ws + 3 * U;
  float* R4  = ws + 4 * U;
  float* x2  = ws + 5 * U;
  float* Sst = ws + 6 * U;
  float* zst = ws + 8 * U;
  bf16_t* wall = (bf16_t*)(ws + 8 * U + 131072);
  bf16_t* Qb    = (bf16_t*)Qr;
  bf16_t* Kb    = (bf16_t*)Kr;
  bf16_t* Vb    = (bf16_t*)Vr;
  bf16_t* xnb   = (bf16_t*)R3;
  bf16_t* attnb = (bf16_t*)x2;   // x2 fp32 written after Wo reduce
  bf16_t* h2b   = (bf16_t*)Qr;   // Qb dead after chunk_attn
  bf16_t* ffn1b = (bf16_t*)Kr;   // Kb/Vb dead after chunk_attn
  bf16_t* Wob = wall + 786432;
  bf16_t* W1b = wall + 1048576;
  bf16_t* W2b = wall + 2097152;
  float* Ps0 = R3;               // xnb dead after QKV
  float* Ps1 = R4;

  ln_cast_kernel<<<BT + 1536, 256, 0, stream>>>(x, g1, b1, xnb, Wq, Wk, Wv, Wo, W1, W2, wall);
  // QKV: M=4096 N=1536 K=512, 128x128 tiles -> NT=12, 384 blocks
  mfma_gemm<0><<<384, 256, 0, stream>>>(xnb, wall, 512, 12, Qb, Kb, Vb,
                                        nullptr, nullptr, mask);
  chunk_summary_kernel<<<dim3(NC, 16), 256, 0, stream>>>(Kb, Vb, dl, Sst, zst);
  scan_kernel<<<dim3(16, 2), 1024, 0, stream>>>(Sst, zst, dl);
  chunk_attn_kernel<<<dim3(NC, 16), 256, 0, stream>>>(Qb, Kb, Vb, Sst, zst, dl, attnb);
  // Wo: M=4096 N=512 K=512, split-K=2 (KPER=256) -> (256,2) blocks
  mfma_gemm_pk<256><<<dim3(256, 2), 256, 0, stream>>>(attnb, Wob, 512, Ps0, Ps1);
  reduce_ln_kernel<<<BT, 256, 0, stream>>>(Ps0, Ps1, bo, x, x2, g2, b2, h2b);
  // FFN1: M=4096 N=2048 K=512, 128x128 tiles -> NT=16, 512 blocks
  mfma_gemm<2><<<512, 256, 0, stream>>>(h2b, W1b, 512, 16, nullptr, nullptr, nullptr,
                                        ffn1b, bf1, nullptr);
  // FFN2: M=4096 N=512 K=2048, split-K=2 (KPER=1024) -> (256,2) blocks
  mfma_gemm_pk<1024><<<dim3(256, 2), 256, 0, stream>>>(ffn1b, W2b, 2048, Ps0, Ps1);
  reduce2_kernel<<<2048, 256, 0, stream>>>(Ps0, Ps1, bf2, x2, out);
}

// Round 10
// 219.193 us; speedup vs baseline: 2.6860x; 1.0481x over previous
//
#include <hip/hip_runtime.h>
#include <math.h>

#define BB 2
#define TT 2048
#define DD 512
#define FF 2048
#define HH 8
#define BT 4096      // BB*TT
#define NC 32        // TT/64 chunks
#define CK 64        // chunk size

typedef __bf16 bf16_t;
typedef bf16_t bf16x8 __attribute__((ext_vector_type(8)));
typedef bf16_t bf16x4 __attribute__((ext_vector_type(4)));
typedef float f32x4 __attribute__((ext_vector_type(4)));

typedef const __attribute__((address_space(1))) void* gas_p;
typedef __attribute__((address_space(3))) void* las_p;

__device__ __forceinline__ void async16(const void* g, void* l) {
  __builtin_amdgcn_global_load_lds((gas_p)g, (las_p)l, 16, 0, 0);
}

// Pipelined barrier: partial-vmcnt wait + s_barrier as ONE asm block with a
// "memory" clobber (compiler-level fence). lgkmcnt(0) drains this wave's
// ds_reads so the (i-1) stage may be overwritten after the barrier; vmcnt(N)
// keeps prefetch DMA in flight across the barrier.
#define PIPE_SYNC(vm) asm volatile("s_waitcnt lgkmcnt(0) vmcnt(" vm ")\n\ts_barrier" ::: "memory")

// ---------------------------------------------------------------- LN1 + weight cast fused
__global__ __launch_bounds__(256) void ln_cast_kernel(
    const float* __restrict__ x, const float* __restrict__ g, const float* __restrict__ bb,
    bf16_t* __restrict__ out,
    const float* __restrict__ Wq, const float* __restrict__ Wk,
    const float* __restrict__ Wv, const float* __restrict__ Wo,
    const float* __restrict__ W1, const float* __restrict__ W2,
    bf16_t* __restrict__ wdst) {
  int t = threadIdx.x;
  if (blockIdx.x >= BT) {
    size_t i = ((size_t)(blockIdx.x - BT) * 256 + t) * 8;
    const float* src; size_t off;
    if (i < 262144)       { src = Wq; off = i; }
    else if (i < 524288)  { src = Wk; off = i - 262144; }
    else if (i < 786432)  { src = Wv; off = i - 524288; }
    else if (i < 1048576) { src = Wo; off = i - 786432; }
    else if (i < 2097152) { src = W1; off = i - 1048576; }
    else                  { src = W2; off = i - 2097152; }
    float4 a = *(const float4*)(src + off);
    float4 b = *(const float4*)(src + off + 4);
    bf16x8 o;
    o[0] = (bf16_t)a.x; o[1] = (bf16_t)a.y; o[2] = (bf16_t)a.z; o[3] = (bf16_t)a.w;
    o[4] = (bf16_t)b.x; o[5] = (bf16_t)b.y; o[6] = (bf16_t)b.z; o[7] = (bf16_t)b.w;
    *(bf16x8*)(wdst + i) = o;
    return;
  }
  int row = blockIdx.x;
  const float* xr = x + (size_t)row * DD;
  float v0 = xr[t], v1 = xr[t + 256];
  float s = v0 + v1, sq = v0 * v0 + v1 * v1;
  for (int o = 32; o; o >>= 1) { s += __shfl_down(s, o); sq += __shfl_down(sq, o); }
  __shared__ float red[8];
  __shared__ float mv[2];
  int w = t >> 6;
  if ((t & 63) == 0) { red[w] = s; red[4 + w] = sq; }
  __syncthreads();
  if (t == 0) {
    float S = red[0] + red[1] + red[2] + red[3];
    float Q = red[4] + red[5] + red[6] + red[7];
    float m = S * (1.f / 512.f);
    float var = Q * (1.f / 512.f) - m * m;
    mv[0] = m; mv[1] = rsqrtf(var + 1e-5f);
  }
  __syncthreads();
  float m = mv[0], r = mv[1];
  out[(size_t)row * DD + t]       = (bf16_t)((v0 - m) * r * g[t] + bb[t]);
  out[(size_t)row * DD + t + 256] = (bf16_t)((v1 - m) * r * g[t + 256] + bb[t + 256]);
}

// ---------------------------------------------------------------- pipelined MFMA GEMM  C = A*B^T
// 128x128 block tile, 64x64 wave tile, BK=32, 3 LDS stages, depth-2 prefetch.
template<int MODE>
__global__ __launch_bounds__(256) void mfma_gemm(
    const bf16_t* __restrict__ A, const bf16_t* __restrict__ B, int K, int NT,
    bf16_t* __restrict__ Qo, bf16_t* __restrict__ Ko, bf16_t* __restrict__ Vo,
    bf16_t* __restrict__ Ob, const float* __restrict__ bias,
    const unsigned char* __restrict__ mask) {
  __shared__ __align__(16) bf16_t smem[3 * 8192];
  int tid = threadIdx.x;
  int bid = blockIdx.x;
  int xcd = bid & 7;
  int tmp = bid >> 3;
  int nt = tmp % NT;
  int mt = (tmp / NT) * 8 + xcd;
  int n0 = nt * 128, m0 = mt * 128;
  int elt = tid * 8;
  int srow = elt >> 5, scol = elt & 31;
  const bf16_t* Ag = A + (size_t)(m0 + srow) * K + scol;
  const bf16_t* Bg = B + (size_t)(n0 + srow) * K + scol;
  size_t hstep = (size_t)64 * K;
  int NS = K >> 5;
#define ISSUE(s) { bf16_t* st = smem + ((s) % 3) * 8192; int k0 = (s) * 32; \
    async16(Ag + k0, st + elt); async16(Ag + k0 + hstep, st + 2048 + elt); \
    async16(Bg + k0, st + 4096 + elt); async16(Bg + k0 + hstep, st + 6144 + elt); }
  ISSUE(0); ISSUE(1);
  f32x4 acc[4][4] = {};
  int w = tid >> 6, l = tid & 63;
  int wm = (w >> 1) * 64, wn = (w & 1) * 64;
  int fr = l & 15, fk = (l >> 4) * 8;
  for (int i = 0; i < NS; i++) {
    if (i < NS - 1) PIPE_SYNC("4");
    else            PIPE_SYNC("0");
    if (i + 2 < NS) ISSUE(i + 2);
    const bf16_t* As = smem + (i % 3) * 8192;
    const bf16_t* Bs = As + 4096;
    bf16x8 af[4], bfr[4];
#pragma unroll
    for (int ii = 0; ii < 4; ii++) af[ii] = *(const bf16x8*)&As[(wm + ii * 16 + fr) * 32 + fk];
#pragma unroll
    for (int j = 0; j < 4; j++) bfr[j] = *(const bf16x8*)&Bs[(wn + j * 16 + fr) * 32 + fk];
#pragma unroll
    for (int ii = 0; ii < 4; ii++)
#pragma unroll
      for (int j = 0; j < 4; j++)
        acc[ii][j] = __builtin_amdgcn_mfma_f32_16x16x32_bf16(af[ii], bfr[j], acc[ii][j], 0, 0, 0);
  }
#undef ISSUE
  int cn = l & 15, cr = (l >> 4) * 4;
#pragma unroll
  for (int i = 0; i < 4; i++) {
#pragma unroll
    for (int r = 0; r < 4; r++) {
      int m = m0 + wm + i * 16 + cr + r;
#pragma unroll
      for (int j = 0; j < 4; j++) {
        int n = n0 + wn + j * 16 + cn;
        float v = acc[i][j][r];
        if (MODE == 0) {
          float p = mask[m] ? 0.f : 1.f;
          int seg = n >> 9, nn = n & 511;
          size_t o = (size_t)m * 512 + nn;
          if (seg == 0)      Qo[o] = (bf16_t)(v > 0.f ? v + 1.f : expf(v));
          else if (seg == 1) Ko[o] = (bf16_t)((v > 0.f ? v + 1.f : expf(v)) * p);
          else               Vo[o] = (bf16_t)(v * p);
        } else {
          float t = v + bias[n];
          Ob[(size_t)m * 2048 + n] = (bf16_t)(0.5f * t * (1.f + erff(t * 0.70710678118654752f)));
        }
      }
    }
  }
}

// ---------------------------------------------------------------- pipelined split-K GEMM (N=512)
template<int KPER>
__global__ __launch_bounds__(256) void mfma_gemm_pk(
    const bf16_t* __restrict__ A, const bf16_t* __restrict__ B, int Kst,
    float* __restrict__ P0, float* __restrict__ P1) {
  __shared__ __align__(16) bf16_t smem[4 * 6144];
  int tid = threadIdx.x;
  int bid = blockIdx.x;
  int xcd = bid & 7;
  int tmp = bid >> 3;
  int nt = tmp & 7;
  int mt = (tmp >> 3) * 8 + xcd;
  int n0 = nt * 64, m0 = mt * 128;
  int kb = blockIdx.y * KPER;
  float* P = blockIdx.y ? P1 : P0;
  int elt = tid * 8;
  int arow = elt >> 5, acol = elt & 31;
  const bf16_t* Ag = A + (size_t)(m0 + arow) * Kst + acol;
  const bf16_t* Bg = B + (size_t)(n0 + arow) * Kst + acol;
  size_t hstep = (size_t)64 * Kst;
  const int NS = KPER >> 5;
#define ISSUE(s) { bf16_t* st = smem + ((s) & 3) * 6144; int k0 = kb + (s) * 32; \
    async16(Ag + k0, st + elt); async16(Ag + k0 + hstep, st + 2048 + elt); \
    async16(Bg + k0, st + 4096 + elt); }
  ISSUE(0); ISSUE(1); ISSUE(2);
  f32x4 acc[4][2] = {};
  int w = tid >> 6, l = tid & 63;
  int wm = (w >> 1) * 64, wn = (w & 1) * 32;
  int fr = l & 15, fk = (l >> 4) * 8;
  for (int i = 0; i < NS; i++) {
    int rem = NS - 1 - i;
    if (rem >= 2)      PIPE_SYNC("6");
    else if (rem == 1) PIPE_SYNC("3");
    else               PIPE_SYNC("0");
    if (i + 3 < NS) ISSUE(i + 3);
    const bf16_t* As = smem + (i & 3) * 6144;
    const bf16_t* Bs = As + 4096;
    bf16x8 af[4], bfr[2];
#pragma unroll
    for (int ii = 0; ii < 4; ii++) af[ii] = *(const bf16x8*)&As[(wm + ii * 16 + fr) * 32 + fk];
#pragma unroll
    for (int j = 0; j < 2; j++) bfr[j] = *(const bf16x8*)&Bs[(wn + j * 16 + fr) * 32 + fk];
#pragma unroll
    for (int ii = 0; ii < 4; ii++)
#pragma unroll
      for (int j = 0; j < 2; j++)
        acc[ii][j] = __builtin_amdgcn_mfma_f32_16x16x32_bf16(af[ii], bfr[j], acc[ii][j], 0, 0, 0);
  }
#undef ISSUE
  int cn = l & 15, cr = (l >> 4) * 4;
#pragma unroll
  for (int i = 0; i < 4; i++)
#pragma unroll
    for (int r = 0; r < 4; r++) {
      int m = m0 + wm + i * 16 + cr + r;
#pragma unroll
      for (int j = 0; j < 2; j++) {
        int n = n0 + wn + j * 16 + cn;
        P[(size_t)m * 512 + n] = acc[i][j][r];
      }
    }
}

// ---------------------------------------------------------------- reduce 2 partials + bias + resid (fp32 out)
__global__ __launch_bounds__(256) void reduce2_kernel(
    const float* __restrict__ P0, const float* __restrict__ P1,
    const float* __restrict__ bias, const float* __restrict__ resid,
    float* __restrict__ o) {
  size_t idx = ((size_t)blockIdx.x * 256 + threadIdx.x) * 4;
  int n = (int)(idx & 511);
  float4 a = *(const float4*)(P0 + idx);
  float4 b = *(const float4*)(P1 + idx);
  float4 rr = *(const float4*)(resid + idx);
  float4 bi = *(const float4*)(bias + n);
  *(float4*)(o + idx) = make_float4(a.x + b.x + bi.x + rr.x, a.y + b.y + bi.y + rr.y,
                                    a.z + b.z + bi.z + rr.z, a.w + b.w + bi.w + rr.w);
}

// ---------------------------------------------------------------- reduce2 + LayerNorm fused
__global__ __launch_bounds__(256) void reduce_ln_kernel(
    const float* __restrict__ P0, const float* __restrict__ P1,
    const float* __restrict__ bias, const float* __restrict__ resid,
    float* __restrict__ x2, const float* __restrict__ g, const float* __restrict__ bb,
    bf16_t* __restrict__ out) {
  int row = blockIdx.x;
  int t = threadIdx.x;
  size_t o0 = (size_t)row * DD + t;
  size_t o1 = o0 + 256;
  float v0 = P0[o0] + P1[o0] + bias[t] + resid[o0];
  float v1 = P0[o1] + P1[o1] + bias[t + 256] + resid[o1];
  x2[o0] = v0; x2[o1] = v1;
  float s = v0 + v1, sq = v0 * v0 + v1 * v1;
  for (int o = 32; o; o >>= 1) { s += __shfl_down(s, o); sq += __shfl_down(sq, o); }
  __shared__ float red[8];
  __shared__ float mv[2];
  int w = t >> 6;
  if ((t & 63) == 0) { red[w] = s; red[4 + w] = sq; }
  __syncthreads();
  if (t == 0) {
    float S = red[0] + red[1] + red[2] + red[3];
    float Q = red[4] + red[5] + red[6] + red[7];
    float m = S * (1.f / 512.f);
    float var = Q * (1.f / 512.f) - m * m;
    mv[0] = m; mv[1] = rsqrtf(var + 1e-5f);
  }
  __syncthreads();
  float m = mv[0], r = mv[1];
  out[o0] = (bf16_t)((v0 - m) * r * g[t] + bb[t]);
  out[o1] = (bf16_t)((v1 - m) * r * g[t + 256] + bb[t + 256]);
}

// ------------------------------------------------- Phase A: chunk summaries, both dirs (bf16 K/V in, bf16 state out)
__global__ __launch_bounds__(256) void chunk_summary_kernel(
    const bf16_t* __restrict__ Kb, const bf16_t* __restrict__ Vb,
    const float* __restrict__ dl, bf16_t* __restrict__ Sst, float* __restrict__ zst) {
  int chunk = blockIdx.x, bh = blockIdx.y;
  int b = bh >> 3, h = bh & 7;
  int t0 = chunk * CK;
  int tid = threadIdx.x;
  __shared__ __align__(16) float Ks[64][64];
  __shared__ __align__(16) float Vs[64][64];
  __shared__ float pw[72];
  float lam = 1.f / (1.f + expf(-dl[h]));
  if (tid <= 64) pw[tid] = powf(lam, (float)tid);
  int lrow = tid >> 2, lq = tid & 3;
  for (int q = 0; q < 2; q++) {
    int c = lq * 16 + q * 8;
    size_t g = ((size_t)(b * TT + t0 + lrow)) * DD + (size_t)h * 64 + c;
    bf16x8 k8 = *(const bf16x8*)(Kb + g);
    bf16x8 v8 = *(const bf16x8*)(Vb + g);
#pragma unroll
    for (int u = 0; u < 8; u++) { Ks[lrow][c + u] = (float)k8[u]; Vs[lrow][c + u] = (float)v8[u]; }
  }
  __syncthreads();
  int e1 = tid & 63;
  int e2b = (tid >> 6) * 16;
  float af_[16], ab_[16];
#pragma unroll
  for (int r = 0; r < 16; r++) { af_[r] = 0.f; ab_[r] = 0.f; }
  float zf = 0.f, zb = 0.f;
  for (int j = 0; j < 64; j++) {
    float kj = Ks[j][e1];
    float kf = pw[63 - j] * kj;
    float kb2 = pw[j] * kj;
    if (tid < 64) { zf += kf; zb += kb2; }
#pragma unroll
    for (int r = 0; r < 16; r++) {
      float v = Vs[j][e2b + r];
      af_[r] += kf * v;
      ab_[r] += kb2 * v;
    }
  }
  size_t bf_ = (((size_t)bh * NC + chunk) * 64 + e1) * 64 + e2b;
  size_t bb_ = ((((size_t)16 + bh) * NC + chunk) * 64 + e1) * 64 + e2b;
  bf16x8 of0, of1, ob0, ob1;
#pragma unroll
  for (int u = 0; u < 8; u++) {
    of0[u] = (bf16_t)af_[u];     of1[u] = (bf16_t)af_[u + 8];
    ob0[u] = (bf16_t)ab_[u];     ob1[u] = (bf16_t)ab_[u + 8];
  }
  *(bf16x8*)(Sst + bf_) = of0;     *(bf16x8*)(Sst + bf_ + 8) = of1;
  *(bf16x8*)(Sst + bb_) = ob0;     *(bf16x8*)(Sst + bb_ + 8) = ob1;
  if (tid < 64) {
    zst[((size_t)bh * NC + chunk) * 64 + tid] = zf;
    zst[(((size_t)16 + bh) * NC + chunk) * 64 + tid] = zb;
  }
}

// ------------------------------------------------- Phase B: scan over chunks (bf16 state, fp32 register accum)
__global__ __launch_bounds__(1024) void scan_kernel(bf16_t* __restrict__ Sst,
                                                    float* __restrict__ zst,
                                                    const float* __restrict__ dl) {
  int bh = blockIdx.x, dir = blockIdx.y;
  int h = bh & 7;
  int tid = threadIdx.x;
  float lam = 1.f / (1.f + expf(-dl[h]));
  float lamC = powf(lam, 64.f);
  size_t base = ((size_t)dir * 16 + bh) * (size_t)NC * 4096 + (size_t)tid * 4;
  float s0 = 0.f, s1 = 0.f, s2 = 0.f, s3 = 0.f;
  for (int g = 0; g < 4; g++) {
    bf16x4 L[8];
#pragma unroll
    for (int i = 0; i < 8; i++) {
      int s = g * 8 + i;
      int c = dir ? (NC - 1 - s) : s;
      L[i] = *(bf16x4*)(Sst + base + (size_t)c * 4096);
    }
#pragma unroll
    for (int i = 0; i < 8; i++) {
      int s = g * 8 + i;
      int c = dir ? (NC - 1 - s) : s;
      s0 = s0 * lamC + (float)L[i][0];
      s1 = s1 * lamC + (float)L[i][1];
      s2 = s2 * lamC + (float)L[i][2];
      s3 = s3 * lamC + (float)L[i][3];
      bf16x4 o;
      o[0] = (bf16_t)s0; o[1] = (bf16_t)s1; o[2] = (bf16_t)s2; o[3] = (bf16_t)s3;
      *(bf16x4*)(Sst + base + (size_t)c * 4096) = o;
    }
  }
  if (tid < 64) {
    size_t zb = ((size_t)dir * 16 + bh) * (size_t)NC * 64 + tid;
    float z = 0.f;
    for (int g = 0; g < 4; g++) {
      float zL[8];
#pragma unroll
      for (int i = 0; i < 8; i++) {
        int s = g * 8 + i;
        int c = dir ? (NC - 1 - s) : s;
        zL[i] = zst[zb + (size_t)c * 64];
      }
#pragma unroll
      for (int i = 0; i < 8; i++) {
        int s = g * 8 + i;
        int c = dir ? (NC - 1 - s) : s;
        z = z * lamC + zL[i];
        zst[zb + (size_t)c * 64] = z;
      }
    }
  }
}

// ------------------------------------------------- Phase C: merged-direction chunk attention
// A_sum[i][j] = qk[i][j] * lam^|i-j|  (exact: fwd+bwd masks with halved diagonals sum to this).
// y_i = (A_sum V)_i + lrf_i (Q Spf)_i + lrb_i (Q Spb)_i;  den_i = rowsum(A_sum)_i + lrf_i q.zf + lrb_i q.zb
__global__ __launch_bounds__(256) void chunk_attn_kernel(
    const bf16_t* __restrict__ Qb, const bf16_t* __restrict__ Kb, const bf16_t* __restrict__ Vb,
    const bf16_t* __restrict__ Sst, const float* __restrict__ zst, const float* __restrict__ dl,
    bf16_t* __restrict__ attnb) {
  int chunk = blockIdx.x, bh = blockIdx.y;
  int b = bh >> 3, h = bh & 7;
  int t0 = chunk * CK;
  int tid = threadIdx.x;
  __shared__ __align__(16) float Qt[64][68];    // Q^T [d][i]
  __shared__ __align__(16) float KtA[64][68];   // K^T [d][j], reused as Ast[j][i]
  __shared__ __align__(16) float Vs[64][64];    // [j][e]
  __shared__ __align__(16) bf16_t Spf[64][64];  // fwd prev state [d][e]
  __shared__ __align__(16) bf16_t Spb[64][64];  // bwd next state [d][e]
  __shared__ float rowpart[64][16];
  __shared__ float zpf[64], zpb[64];
  __shared__ float den[64];
  __shared__ float pw[72];
  float lam = 1.f / (1.f + expf(-dl[h]));
  if (tid <= 64) pw[tid] = powf(lam, (float)tid);
  int lrow = tid >> 2, lq = tid & 3;
  for (int q = 0; q < 2; q++) {
    int c = lq * 16 + q * 8;
    size_t g = ((size_t)(b * TT + t0 + lrow)) * DD + (size_t)h * 64 + c;
    bf16x8 q8 = *(const bf16x8*)(Qb + g);
    bf16x8 k8 = *(const bf16x8*)(Kb + g);
    bf16x8 v8 = *(const bf16x8*)(Vb + g);
#pragma unroll
    for (int u = 0; u < 8; u++) {
      Qt[c + u][lrow] = (float)q8[u];
      KtA[c + u][lrow] = (float)k8[u];
      Vs[lrow][c + u] = (float)v8[u];
    }
  }
  {
    int c16 = lq * 16;
    if (chunk > 0) {
      const bf16_t* src = Sst + ((size_t)bh * NC + chunk - 1) * 4096 + (size_t)lrow * 64 + c16;
      *(bf16x8*)&Spf[lrow][c16] = *(const bf16x8*)src;
      *(bf16x8*)&Spf[lrow][c16 + 8] = *(const bf16x8*)(src + 8);
      if (tid < 64) zpf[tid] = zst[((size_t)bh * NC + chunk - 1) * 64 + tid];
    } else {
      bf16x8 z8 = {};
      *(bf16x8*)&Spf[lrow][c16] = z8;
      *(bf16x8*)&Spf[lrow][c16 + 8] = z8;
      if (tid < 64) zpf[tid] = 0.f;
    }
    if (chunk < NC - 1) {
      const bf16_t* src = Sst + (((size_t)16 + bh) * NC + chunk + 1) * 4096 + (size_t)lrow * 64 + c16;
      *(bf16x8*)&Spb[lrow][c16] = *(const bf16x8*)src;
      *(bf16x8*)&Spb[lrow][c16 + 8] = *(const bf16x8*)(src + 8);
      if (tid < 64) zpb[tid] = zst[(((size_t)16 + bh) * NC + chunk + 1) * 64 + tid];
    } else {
      bf16x8 z8 = {};
      *(bf16x8*)&Spb[lrow][c16] = z8;
      *(bf16x8*)&Spb[lrow][c16 + 8] = z8;
      if (tid < 64) zpb[tid] = 0.f;
    }
  }
  __syncthreads();
  int tx = tid & 15, ty = tid >> 4;
  int i0 = ty * 4, j0 = tx * 4;
  int e0 = tx * 4;
  // ---- qk = Q K^T over d
  float acc[4][4] = {};
  for (int d = 0; d < 64; d++) {
    float4 qf = *(const float4*)&Qt[d][i0];
    float4 kf = *(const float4*)&KtA[d][j0];
    float qa[4] = {qf.x, qf.y, qf.z, qf.w};
    float ka[4] = {kf.x, kf.y, kf.z, kf.w};
#pragma unroll
    for (int r = 0; r < 4; r++)
#pragma unroll
      for (int c = 0; c < 4; c++) acc[r][c] += qa[r] * ka[c];
  }
  __syncthreads();  // KtA free for reuse as Ast
  // ---- A_sum = qk * lam^|i-j| ; row sums; store A_sum^T into KtA
  float rs[4] = {0.f, 0.f, 0.f, 0.f};
  float colv[4][4];
#pragma unroll
  for (int r = 0; r < 4; r++) {
    int i = i0 + r;
#pragma unroll
    for (int c = 0; c < 4; c++) {
      int j = j0 + c;
      int dd = i > j ? i - j : j - i;
      float v = acc[r][c] * pw[dd];
      rs[r] += v;
      colv[c][r] = v;
    }
  }
#pragma unroll
  for (int c = 0; c < 4; c++)
    *(float4*)&KtA[j0 + c][i0] = make_float4(colv[c][0], colv[c][1], colv[c][2], colv[c][3]);
#pragma unroll
  for (int r = 0; r < 4; r++) rowpart[i0 + r][tx] = rs[r];
  __syncthreads();
  // ---- Y = Ast^T V + lrf*(Q Spf) + lrb*(Q Spb)
  float accY[4][4] = {}, accSf[4][4] = {}, accSb[4][4] = {};
  for (int j = 0; j < 64; j++) {
    float4 af = *(const float4*)&KtA[j][i0];
    float4 vf = *(const float4*)&Vs[j][e0];
    float aa[4] = {af.x, af.y, af.z, af.w};
    float vv[4] = {vf.x, vf.y, vf.z, vf.w};
#pragma unroll
    for (int r = 0; r < 4; r++)
#pragma unroll
      for (int c = 0; c < 4; c++) accY[r][c] += aa[r] * vv[c];
  }
  for (int d = 0; d < 64; d++) {
    float4 qf = *(const float4*)&Qt[d][i0];
    bf16x4 sf4 = *(const bf16x4*)&Spf[d][e0];
    bf16x4 sb4 = *(const bf16x4*)&Spb[d][e0];
    float qq[4] = {qf.x, qf.y, qf.z, qf.w};
    float sf[4] = {(float)sf4[0], (float)sf4[1], (float)sf4[2], (float)sf4[3]};
    float sb[4] = {(float)sb4[0], (float)sb4[1], (float)sb4[2], (float)sb4[3]};
#pragma unroll
    for (int r = 0; r < 4; r++)
#pragma unroll
      for (int c = 0; c < 4; c++) {
        accSf[r][c] += qq[r] * sf[c];
        accSb[r][c] += qq[r] * sb[c];
      }
  }
  if (tid < 64) {
    int i = tid;
    float s = 0.f;
#pragma unroll
    for (int xx = 0; xx < 16; xx++) s += rowpart[i][xx];
    float czf = 0.f, czb = 0.f;
    for (int d = 0; d < 64; d++) { czf += Qt[d][i] * zpf[d]; czb += Qt[d][i] * zpb[d]; }
    den[i] = s + pw[i + 1] * czf + pw[64 - i] * czb;
  }
  __syncthreads();
#pragma unroll
  for (int r = 0; r < 4; r++) {
    int i = i0 + r;
    float lrf = pw[i + 1], lrb = pw[64 - i];
    float inv = 1.f / fmaxf(den[i], 1e-6f);
    bf16x4 o;
#pragma unroll
    for (int c = 0; c < 4; c++)
      o[c] = (bf16_t)((accY[r][c] + lrf * accSf[r][c] + lrb * accSb[r][c]) * inv);
    *(bf16x4*)(attnb + ((size_t)(b * TT + t0 + i)) * DD + (size_t)h * 64 + e0) = o;
  }
}

// ---------------------------------------------------------------- launch
extern "C" void kernel_launch(void* const* d_in, const int* in_sizes, int n_in,
                              void* d_out, int out_size, void* d_ws, size_t ws_size,
                              hipStream_t stream) {
  const float* x   = (const float*)d_in[0];
  const unsigned char* mask = (const unsigned char*)d_in[1];
  const float* Wq  = (const float*)d_in[2];
  const float* Wk  = (const float*)d_in[3];
  const float* Wv  = (const float*)d_in[4];
  const float* Wo  = (const float*)d_in[5];
  const float* bo  = (const float*)d_in[6];
  const float* g1  = (const float*)d_in[7];
  const float* b1  = (const float*)d_in[8];
  const float* g2  = (const float*)d_in[9];
  const float* b2  = (const float*)d_in[10];
  const float* W1  = (const float*)d_in[11];
  const float* bf1 = (const float*)d_in[12];
  const float* W2  = (const float*)d_in[13];
  const float* bf2 = (const float*)d_in[14];
  const float* dl  = (const float*)d_in[15];
  float* out = (float*)d_out;

  float* ws = (float*)d_ws;
  const size_t U = (size_t)BT * DD;  // 2097152 floats
  float* Qr  = ws;
  float* Kr  = ws + U;
  float* Vr  = ws + 2 * U;
  float* R3  = ws + 3 * U;
  float* R4  = ws + 4 * U;
  float* x2  = ws + 5 * U;
  bf16_t* Sstb = (bf16_t*)(ws + 6 * U);   // 2*16*NC*4096 bf16 = 8.4MB (fits in U floats)
  float* zst = ws + 8 * U;
  bf16_t* wall = (bf16_t*)(ws + 8 * U + 131072);
  bf16_t* Qb    = (bf16_t*)Qr;
  bf16_t* Kb    = (bf16_t*)Kr;
  bf16_t* Vb    = (bf16_t*)Vr;
  bf16_t* xnb   = (bf16_t*)R3;
  bf16_t* attnb = (bf16_t*)x2;
  bf16_t* h2b   = (bf16_t*)Qr;
  bf16_t* ffn1b = (bf16_t*)Kr;
  bf16_t* Wob = wall + 786432;
  bf16_t* W1b = wall + 1048576;
  bf16_t* W2b = wall + 2097152;
  float* Ps0 = R3;
  float* Ps1 = R4;

  ln_cast_kernel<<<BT + 1536, 256, 0, stream>>>(x, g1, b1, xnb, Wq, Wk, Wv, Wo, W1, W2, wall);
  mfma_gemm<0><<<384, 256, 0, stream>>>(xnb, wall, 512, 12, Qb, Kb, Vb,
                                        nullptr, nullptr, mask);
  chunk_summary_kernel<<<dim3(NC, 16), 256, 0, stream>>>(Kb, Vb, dl, Sstb, zst);
  scan_kernel<<<dim3(16, 2), 1024, 0, stream>>>(Sstb, zst, dl);
  chunk_attn_kernel<<<dim3(NC, 16), 256, 0, stream>>>(Qb, Kb, Vb, Sstb, zst, dl, attnb);
  mfma_gemm_pk<256><<<dim3(256, 2), 256, 0, stream>>>(attnb, Wob, 512, Ps0, Ps1);
  reduce_ln_kernel<<<BT, 256, 0, stream>>>(Ps0, Ps1, bo, x, x2, g2, b2, h2b);
  mfma_gemm<2><<<512, 256, 0, stream>>>(h2b, W1b, 512, 16, nullptr, nullptr, nullptr,
                                        ffn1b, bf1, nullptr);
  mfma_gemm_pk<1024><<<dim3(256, 2), 256, 0, stream>>>(ffn1b, W2b, 2048, Ps0, Ps1);
  reduce2_kernel<<<2048, 256, 0, stream>>>(Ps0, Ps1, bf2, x2, out);
}

// Round 11
// 216.572 us; speedup vs baseline: 2.7185x; 1.0121x over previous
//
#include <hip/hip_runtime.h>
#include <math.h>

#define BB 2
#define TT 2048
#define DD 512
#define FF 2048
#define HH 8
#define BT 4096      // BB*TT
#define NC 32        // TT/64 chunks
#define CK 64        // chunk size

typedef __bf16 bf16_t;
typedef bf16_t bf16x8 __attribute__((ext_vector_type(8)));
typedef bf16_t bf16x4 __attribute__((ext_vector_type(4)));
typedef float f32x4 __attribute__((ext_vector_type(4)));

typedef const __attribute__((address_space(1))) void* gas_p;
typedef __attribute__((address_space(3))) void* las_p;

__device__ __forceinline__ void async16(const void* g, void* l) {
  __builtin_amdgcn_global_load_lds((gas_p)g, (las_p)l, 16, 0, 0);
}

// Pipelined barrier: partial-vmcnt wait + s_barrier as ONE asm block with a
// "memory" clobber (compiler-level fence). lgkmcnt(0) drains this wave's
// ds_reads so the (i-1) stage may be overwritten after the barrier; vmcnt(N)
// keeps prefetch DMA in flight across the barrier.
#define PIPE_SYNC(vm) asm volatile("s_waitcnt lgkmcnt(0) vmcnt(" vm ")\n\ts_barrier" ::: "memory")

// ---------------------------------------------------------------- LN1 + weight cast fused
__global__ __launch_bounds__(256) void ln_cast_kernel(
    const float* __restrict__ x, const float* __restrict__ g, const float* __restrict__ bb,
    bf16_t* __restrict__ out,
    const float* __restrict__ Wq, const float* __restrict__ Wk,
    const float* __restrict__ Wv, const float* __restrict__ Wo,
    const float* __restrict__ W1, const float* __restrict__ W2,
    bf16_t* __restrict__ wdst) {
  int t = threadIdx.x;
  if (blockIdx.x >= BT) {
    size_t i = ((size_t)(blockIdx.x - BT) * 256 + t) * 8;
    const float* src; size_t off;
    if (i < 262144)       { src = Wq; off = i; }
    else if (i < 524288)  { src = Wk; off = i - 262144; }
    else if (i < 786432)  { src = Wv; off = i - 524288; }
    else if (i < 1048576) { src = Wo; off = i - 786432; }
    else if (i < 2097152) { src = W1; off = i - 1048576; }
    else                  { src = W2; off = i - 2097152; }
    float4 a = *(const float4*)(src + off);
    float4 b = *(const float4*)(src + off + 4);
    bf16x8 o;
    o[0] = (bf16_t)a.x; o[1] = (bf16_t)a.y; o[2] = (bf16_t)a.z; o[3] = (bf16_t)a.w;
    o[4] = (bf16_t)b.x; o[5] = (bf16_t)b.y; o[6] = (bf16_t)b.z; o[7] = (bf16_t)b.w;
    *(bf16x8*)(wdst + i) = o;
    return;
  }
  int row = blockIdx.x;
  const float* xr = x + (size_t)row * DD;
  float v0 = xr[t], v1 = xr[t + 256];
  float s = v0 + v1, sq = v0 * v0 + v1 * v1;
  for (int o = 32; o; o >>= 1) { s += __shfl_down(s, o); sq += __shfl_down(sq, o); }
  __shared__ float red[8];
  __shared__ float mv[2];
  int w = t >> 6;
  if ((t & 63) == 0) { red[w] = s; red[4 + w] = sq; }
  __syncthreads();
  if (t == 0) {
    float S = red[0] + red[1] + red[2] + red[3];
    float Q = red[4] + red[5] + red[6] + red[7];
    float m = S * (1.f / 512.f);
    float var = Q * (1.f / 512.f) - m * m;
    mv[0] = m; mv[1] = rsqrtf(var + 1e-5f);
  }
  __syncthreads();
  float m = mv[0], r = mv[1];
  out[(size_t)row * DD + t]       = (bf16_t)((v0 - m) * r * g[t] + bb[t]);
  out[(size_t)row * DD + t + 256] = (bf16_t)((v1 - m) * r * g[t + 256] + bb[t + 256]);
}

// ---------------------------------------------------------------- pipelined MFMA GEMM  C = A*B^T
// 128x128 block tile, 64x64 wave tile, BK=32, 3 LDS stages, depth-2 prefetch.
// LDS-staged epilogue: acc -> bf16 LDS tile (stride 136) -> coalesced bf16x8 stores.
// Tile is 128 wide and n0 % 128 == 0, so a tile never straddles a 512-col segment.
template<int MODE>
__global__ __launch_bounds__(256) void mfma_gemm(
    const bf16_t* __restrict__ A, const bf16_t* __restrict__ B, int K, int NT,
    bf16_t* __restrict__ Qo, bf16_t* __restrict__ Ko, bf16_t* __restrict__ Vo,
    bf16_t* __restrict__ Ob, const float* __restrict__ bias,
    const unsigned char* __restrict__ mask) {
  __shared__ __align__(16) bf16_t smem[3 * 8192];   // 48KB; epilogue reuses as 128x136 bf16 (34.8KB)
  int tid = threadIdx.x;
  int bid = blockIdx.x;
  int xcd = bid & 7;
  int tmp = bid >> 3;
  int nt = tmp % NT;
  int mt = (tmp / NT) * 8 + xcd;
  int n0 = nt * 128, m0 = mt * 128;
  int elt = tid * 8;
  int srow = elt >> 5, scol = elt & 31;
  const bf16_t* Ag = A + (size_t)(m0 + srow) * K + scol;
  const bf16_t* Bg = B + (size_t)(n0 + srow) * K + scol;
  size_t hstep = (size_t)64 * K;
  int NS = K >> 5;
#define ISSUE(s) { bf16_t* st = smem + ((s) % 3) * 8192; int k0 = (s) * 32; \
    async16(Ag + k0, st + elt); async16(Ag + k0 + hstep, st + 2048 + elt); \
    async16(Bg + k0, st + 4096 + elt); async16(Bg + k0 + hstep, st + 6144 + elt); }
  ISSUE(0); ISSUE(1);
  f32x4 acc[4][4] = {};
  int w = tid >> 6, l = tid & 63;
  int wm = (w >> 1) * 64, wn = (w & 1) * 64;
  int fr = l & 15, fk = (l >> 4) * 8;
  for (int i = 0; i < NS; i++) {
    if (i < NS - 1) PIPE_SYNC("4");
    else            PIPE_SYNC("0");
    if (i + 2 < NS) ISSUE(i + 2);
    const bf16_t* As = smem + (i % 3) * 8192;
    const bf16_t* Bs = As + 4096;
    bf16x8 af[4], bfr[4];
#pragma unroll
    for (int ii = 0; ii < 4; ii++) af[ii] = *(const bf16x8*)&As[(wm + ii * 16 + fr) * 32 + fk];
#pragma unroll
    for (int j = 0; j < 4; j++) bfr[j] = *(const bf16x8*)&Bs[(wn + j * 16 + fr) * 32 + fk];
#pragma unroll
    for (int ii = 0; ii < 4; ii++)
#pragma unroll
      for (int j = 0; j < 4; j++)
        acc[ii][j] = __builtin_amdgcn_mfma_f32_16x16x32_bf16(af[ii], bfr[j], acc[ii][j], 0, 0, 0);
  }
#undef ISSUE
  __syncthreads();   // all MFMA fragment reads done; smem reusable for C staging
  const int CST = 136;   // bf16 stride: 16B-aligned rows, row-group bank spread ~2-way
  int cn = l & 15, cr = (l >> 4) * 4;
  // select per-tile output pointer / activation
  bf16_t* outp;
  int ldc, ncol0;
  if (MODE == 0) {
    int seg = n0 >> 9;
    outp = seg == 0 ? Qo : (seg == 1 ? Ko : Vo);
    ldc = 512; ncol0 = n0 & 511;
  } else {
    outp = Ob; ldc = 2048; ncol0 = n0;
  }
#pragma unroll
  for (int i = 0; i < 4; i++) {
#pragma unroll
    for (int r = 0; r < 4; r++) {
      int mrow = wm + i * 16 + cr + r;
      float p = 1.f;
      if (MODE == 0) p = mask[m0 + mrow] ? 0.f : 1.f;
#pragma unroll
      for (int j = 0; j < 4; j++) {
        int ncol = wn + j * 16 + cn;
        float v = acc[i][j][r];
        float ov;
        if (MODE == 0) {
          int seg = n0 >> 9;
          float e = v > 0.f ? v + 1.f : expf(v);
          ov = seg == 0 ? e : (seg == 1 ? e * p : v * p);
        } else {
          float t2 = v + bias[ncol0 + ncol];
          ov = 0.5f * t2 * (1.f + erff(t2 * 0.70710678118654752f));
        }
        smem[mrow * CST + ncol] = (bf16_t)ov;
      }
    }
  }
  __syncthreads();
  // coalesced copy-out: 2048 bf16x8 vectors, 8 per thread
#pragma unroll
  for (int it = 0; it < 8; it++) {
    int vec = tid + it * 256;
    int row = vec >> 4;
    int col = (vec & 15) * 8;
    bf16x8 v8 = *(const bf16x8*)&smem[row * CST + col];
    *(bf16x8*)(outp + (size_t)(m0 + row) * ldc + ncol0 + col) = v8;
  }
}

// ---------------------------------------------------------------- pipelined split-K GEMM (N=512)
template<int KPER>
__global__ __launch_bounds__(256) void mfma_gemm_pk(
    const bf16_t* __restrict__ A, const bf16_t* __restrict__ B, int Kst,
    float* __restrict__ P0, float* __restrict__ P1) {
  __shared__ __align__(16) bf16_t smem[4 * 6144];
  int tid = threadIdx.x;
  int bid = blockIdx.x;
  int xcd = bid & 7;
  int tmp = bid >> 3;
  int nt = tmp & 7;
  int mt = (tmp >> 3) * 8 + xcd;
  int n0 = nt * 64, m0 = mt * 128;
  int kb = blockIdx.y * KPER;
  float* P = blockIdx.y ? P1 : P0;
  int elt = tid * 8;
  int arow = elt >> 5, acol = elt & 31;
  const bf16_t* Ag = A + (size_t)(m0 + arow) * Kst + acol;
  const bf16_t* Bg = B + (size_t)(n0 + arow) * Kst + acol;
  size_t hstep = (size_t)64 * Kst;
  const int NS = KPER >> 5;
#define ISSUE(s) { bf16_t* st = smem + ((s) & 3) * 6144; int k0 = kb + (s) * 32; \
    async16(Ag + k0, st + elt); async16(Ag + k0 + hstep, st + 2048 + elt); \
    async16(Bg + k0, st + 4096 + elt); }
  ISSUE(0); ISSUE(1); ISSUE(2);
  f32x4 acc[4][2] = {};
  int w = tid >> 6, l = tid & 63;
  int wm = (w >> 1) * 64, wn = (w & 1) * 32;
  int fr = l & 15, fk = (l >> 4) * 8;
  for (int i = 0; i < NS; i++) {
    int rem = NS - 1 - i;
    if (rem >= 2)      PIPE_SYNC("6");
    else if (rem == 1) PIPE_SYNC("3");
    else               PIPE_SYNC("0");
    if (i + 3 < NS) ISSUE(i + 3);
    const bf16_t* As = smem + (i & 3) * 6144;
    const bf16_t* Bs = As + 4096;
    bf16x8 af[4], bfr[2];
#pragma unroll
    for (int ii = 0; ii < 4; ii++) af[ii] = *(const bf16x8*)&As[(wm + ii * 16 + fr) * 32 + fk];
#pragma unroll
    for (int j = 0; j < 2; j++) bfr[j] = *(const bf16x8*)&Bs[(wn + j * 16 + fr) * 32 + fk];
#pragma unroll
    for (int ii = 0; ii < 4; ii++)
#pragma unroll
      for (int j = 0; j < 2; j++)
        acc[ii][j] = __builtin_amdgcn_mfma_f32_16x16x32_bf16(af[ii], bfr[j], acc[ii][j], 0, 0, 0);
  }
#undef ISSUE
  int cn = l & 15, cr = (l >> 4) * 4;
#pragma unroll
  for (int i = 0; i < 4; i++)
#pragma unroll
    for (int r = 0; r < 4; r++) {
      int m = m0 + wm + i * 16 + cr + r;
#pragma unroll
      for (int j = 0; j < 2; j++) {
        int n = n0 + wn + j * 16 + cn;
        P[(size_t)m * 512 + n] = acc[i][j][r];
      }
    }
}

// ---------------------------------------------------------------- reduce 2 partials + bias + resid (fp32 out)
__global__ __launch_bounds__(256) void reduce2_kernel(
    const float* __restrict__ P0, const float* __restrict__ P1,
    const float* __restrict__ bias, const float* __restrict__ resid,
    float* __restrict__ o) {
  size_t idx = ((size_t)blockIdx.x * 256 + threadIdx.x) * 4;
  int n = (int)(idx & 511);
  float4 a = *(const float4*)(P0 + idx);
  float4 b = *(const float4*)(P1 + idx);
  float4 rr = *(const float4*)(resid + idx);
  float4 bi = *(const float4*)(bias + n);
  *(float4*)(o + idx) = make_float4(a.x + b.x + bi.x + rr.x, a.y + b.y + bi.y + rr.y,
                                    a.z + b.z + bi.z + rr.z, a.w + b.w + bi.w + rr.w);
}

// ---------------------------------------------------------------- reduce2 + LayerNorm fused
__global__ __launch_bounds__(256) void reduce_ln_kernel(
    const float* __restrict__ P0, const float* __restrict__ P1,
    const float* __restrict__ bias, const float* __restrict__ resid,
    float* __restrict__ x2, const float* __restrict__ g, const float* __restrict__ bb,
    bf16_t* __restrict__ out) {
  int row = blockIdx.x;
  int t = threadIdx.x;
  size_t o0 = (size_t)row * DD + t;
  size_t o1 = o0 + 256;
  float v0 = P0[o0] + P1[o0] + bias[t] + resid[o0];
  float v1 = P0[o1] + P1[o1] + bias[t + 256] + resid[o1];
  x2[o0] = v0; x2[o1] = v1;
  float s = v0 + v1, sq = v0 * v0 + v1 * v1;
  for (int o = 32; o; o >>= 1) { s += __shfl_down(s, o); sq += __shfl_down(sq, o); }
  __shared__ float red[8];
  __shared__ float mv[2];
  int w = t >> 6;
  if ((t & 63) == 0) { red[w] = s; red[4 + w] = sq; }
  __syncthreads();
  if (t == 0) {
    float S = red[0] + red[1] + red[2] + red[3];
    float Q = red[4] + red[5] + red[6] + red[7];
    float m = S * (1.f / 512.f);
    float var = Q * (1.f / 512.f) - m * m;
    mv[0] = m; mv[1] = rsqrtf(var + 1e-5f);
  }
  __syncthreads();
  float m = mv[0], r = mv[1];
  out[o0] = (bf16_t)((v0 - m) * r * g[t] + bb[t]);
  out[o1] = (bf16_t)((v1 - m) * r * g[t + 256] + bb[t + 256]);
}

// ------------------------------------------------- Phase A: chunk summaries, both dirs (bf16 K/V in, bf16 state out)
__global__ __launch_bounds__(256) void chunk_summary_kernel(
    const bf16_t* __restrict__ Kb, const bf16_t* __restrict__ Vb,
    const float* __restrict__ dl, bf16_t* __restrict__ Sst, float* __restrict__ zst) {
  int chunk = blockIdx.x, bh = blockIdx.y;
  int b = bh >> 3, h = bh & 7;
  int t0 = chunk * CK;
  int tid = threadIdx.x;
  __shared__ __align__(16) float Ks[64][64];
  __shared__ __align__(16) float Vs[64][64];
  __shared__ float pw[72];
  float lam = 1.f / (1.f + expf(-dl[h]));
  if (tid <= 64) pw[tid] = powf(lam, (float)tid);
  int lrow = tid >> 2, lq = tid & 3;
  for (int q = 0; q < 2; q++) {
    int c = lq * 16 + q * 8;
    size_t g = ((size_t)(b * TT + t0 + lrow)) * DD + (size_t)h * 64 + c;
    bf16x8 k8 = *(const bf16x8*)(Kb + g);
    bf16x8 v8 = *(const bf16x8*)(Vb + g);
#pragma unroll
    for (int u = 0; u < 8; u++) { Ks[lrow][c + u] = (float)k8[u]; Vs[lrow][c + u] = (float)v8[u]; }
  }
  __syncthreads();
  int e1 = tid & 63;
  int e2b = (tid >> 6) * 16;
  float af_[16], ab_[16];
#pragma unroll
  for (int r = 0; r < 16; r++) { af_[r] = 0.f; ab_[r] = 0.f; }
  float zf = 0.f, zb = 0.f;
  for (int j = 0; j < 64; j++) {
    float kj = Ks[j][e1];
    float kf = pw[63 - j] * kj;
    float kb2 = pw[j] * kj;
    if (tid < 64) { zf += kf; zb += kb2; }
#pragma unroll
    for (int rr = 0; rr < 16; rr += 4) {
      float4 v4 = *(const float4*)&Vs[j][e2b + rr];
      af_[rr]     += kf * v4.x;  ab_[rr]     += kb2 * v4.x;
      af_[rr + 1] += kf * v4.y;  ab_[rr + 1] += kb2 * v4.y;
      af_[rr + 2] += kf * v4.z;  ab_[rr + 2] += kb2 * v4.z;
      af_[rr + 3] += kf * v4.w;  ab_[rr + 3] += kb2 * v4.w;
    }
  }
  size_t bf_ = (((size_t)bh * NC + chunk) * 64 + e1) * 64 + e2b;
  size_t bb_ = ((((size_t)16 + bh) * NC + chunk) * 64 + e1) * 64 + e2b;
  bf16x8 of0, of1, ob0, ob1;
#pragma unroll
  for (int u = 0; u < 8; u++) {
    of0[u] = (bf16_t)af_[u];     of1[u] = (bf16_t)af_[u + 8];
    ob0[u] = (bf16_t)ab_[u];     ob1[u] = (bf16_t)ab_[u + 8];
  }
  *(bf16x8*)(Sst + bf_) = of0;     *(bf16x8*)(Sst + bf_ + 8) = of1;
  *(bf16x8*)(Sst + bb_) = ob0;     *(bf16x8*)(Sst + bb_ + 8) = ob1;
  if (tid < 64) {
    zst[((size_t)bh * NC + chunk) * 64 + tid] = zf;
    zst[(((size_t)16 + bh) * NC + chunk) * 64 + tid] = zb;
  }
}

// ------------------------------------------------- Phase B: scan over chunks (bf16 state, fp32 register accum)
__global__ __launch_bounds__(1024) void scan_kernel(bf16_t* __restrict__ Sst,
                                                    float* __restrict__ zst,
                                                    const float* __restrict__ dl) {
  int bh = blockIdx.x, dir = blockIdx.y;
  int h = bh & 7;
  int tid = threadIdx.x;
  float lam = 1.f / (1.f + expf(-dl[h]));
  float lamC = powf(lam, 64.f);
  size_t base = ((size_t)dir * 16 + bh) * (size_t)NC * 4096 + (size_t)tid * 4;
  float s0 = 0.f, s1 = 0.f, s2 = 0.f, s3 = 0.f;
  for (int g = 0; g < 4; g++) {
    bf16x4 L[8];
#pragma unroll
    for (int i = 0; i < 8; i++) {
      int s = g * 8 + i;
      int c = dir ? (NC - 1 - s) : s;
      L[i] = *(bf16x4*)(Sst + base + (size_t)c * 4096);
    }
#pragma unroll
    for (int i = 0; i < 8; i++) {
      int s = g * 8 + i;
      int c = dir ? (NC - 1 - s) : s;
      s0 = s0 * lamC + (float)L[i][0];
      s1 = s1 * lamC + (float)L[i][1];
      s2 = s2 * lamC + (float)L[i][2];
      s3 = s3 * lamC + (float)L[i][3];
      bf16x4 o;
      o[0] = (bf16_t)s0; o[1] = (bf16_t)s1; o[2] = (bf16_t)s2; o[3] = (bf16_t)s3;
      *(bf16x4*)(Sst + base + (size_t)c * 4096) = o;
    }
  }
  if (tid < 64) {
    size_t zb = ((size_t)dir * 16 + bh) * (size_t)NC * 64 + tid;
    float z = 0.f;
    for (int g = 0; g < 4; g++) {
      float zL[8];
#pragma unroll
      for (int i = 0; i < 8; i++) {
        int s = g * 8 + i;
        int c = dir ? (NC - 1 - s) : s;
        zL[i] = zst[zb + (size_t)c * 64];
      }
#pragma unroll
      for (int i = 0; i < 8; i++) {
        int s = g * 8 + i;
        int c = dir ? (NC - 1 - s) : s;
        z = z * lamC + zL[i];
        zst[zb + (size_t)c * 64] = z;
      }
    }
  }
}

// ------------------------------------------------- Phase C: merged-direction chunk attention
// A_sum[i][j] = qk[i][j] * lam^|i-j| (exact merge of fwd+bwd masked scores incl. halved diagonals).
__global__ __launch_bounds__(256) void chunk_attn_kernel(
    const bf16_t* __restrict__ Qb, const bf16_t* __restrict__ Kb, const bf16_t* __restrict__ Vb,
    const bf16_t* __restrict__ Sst, const float* __restrict__ zst, const float* __restrict__ dl,
    bf16_t* __restrict__ attnb) {
  int chunk = blockIdx.x, bh = blockIdx.y;
  int b = bh >> 3, h = bh & 7;
  int t0 = chunk * CK;
  int tid = threadIdx.x;
  __shared__ __align__(16) float Qt[64][68];
  __shared__ __align__(16) float KtA[64][68];
  __shared__ __align__(16) float Vs[64][64];
  __shared__ __align__(16) bf16_t Spf[64][64];
  __shared__ __align__(16) bf16_t Spb[64][64];
  __shared__ float rowpart[64][16];
  __shared__ float zpf[64], zpb[64];
  __shared__ float den[64];
  __shared__ float pw[72];
  float lam = 1.f / (1.f + expf(-dl[h]));
  if (tid <= 64) pw[tid] = powf(lam, (float)tid);
  int lrow = tid >> 2, lq = tid & 3;
  for (int q = 0; q < 2; q++) {
    int c = lq * 16 + q * 8;
    size_t g = ((size_t)(b * TT + t0 + lrow)) * DD + (size_t)h * 64 + c;
    bf16x8 q8 = *(const bf16x8*)(Qb + g);
    bf16x8 k8 = *(const bf16x8*)(Kb + g);
    bf16x8 v8 = *(const bf16x8*)(Vb + g);
#pragma unroll
    for (int u = 0; u < 8; u++) {
      Qt[c + u][lrow] = (float)q8[u];
      KtA[c + u][lrow] = (float)k8[u];
      Vs[lrow][c + u] = (float)v8[u];
    }
  }
  {
    int c16 = lq * 16;
    if (chunk > 0) {
      const bf16_t* src = Sst + ((size_t)bh * NC + chunk - 1) * 4096 + (size_t)lrow * 64 + c16;
      *(bf16x8*)&Spf[lrow][c16] = *(const bf16x8*)src;
      *(bf16x8*)&Spf[lrow][c16 + 8] = *(const bf16x8*)(src + 8);
      if (tid < 64) zpf[tid] = zst[((size_t)bh * NC + chunk - 1) * 64 + tid];
    } else {
      bf16x8 z8 = {};
      *(bf16x8*)&Spf[lrow][c16] = z8;
      *(bf16x8*)&Spf[lrow][c16 + 8] = z8;
      if (tid < 64) zpf[tid] = 0.f;
    }
    if (chunk < NC - 1) {
      const bf16_t* src = Sst + (((size_t)16 + bh) * NC + chunk + 1) * 4096 + (size_t)lrow * 64 + c16;
      *(bf16x8*)&Spb[lrow][c16] = *(const bf16x8*)src;
      *(bf16x8*)&Spb[lrow][c16 + 8] = *(const bf16x8*)(src + 8);
      if (tid < 64) zpb[tid] = zst[(((size_t)16 + bh) * NC + chunk + 1) * 64 + tid];
    } else {
      bf16x8 z8 = {};
      *(bf16x8*)&Spb[lrow][c16] = z8;
      *(bf16x8*)&Spb[lrow][c16 + 8] = z8;
      if (tid < 64) zpb[tid] = 0.f;
    }
  }
  __syncthreads();
  int tx = tid & 15, ty = tid >> 4;
  int i0 = ty * 4, j0 = tx * 4;
  int e0 = tx * 4;
  float acc[4][4] = {};
  for (int d = 0; d < 64; d++) {
    float4 qf = *(const float4*)&Qt[d][i0];
    float4 kf = *(const float4*)&KtA[d][j0];
    float qa[4] = {qf.x, qf.y, qf.z, qf.w};
    float ka[4] = {kf.x, kf.y, kf.z, kf.w};
#pragma unroll
    for (int r = 0; r < 4; r++)
#pragma unroll
      for (int c = 0; c < 4; c++) acc[r][c] += qa[r] * ka[c];
  }
  __syncthreads();
  float rs[4] = {0.f, 0.f, 0.f, 0.f};
  float colv[4][4];
#pragma unroll
  for (int r = 0; r < 4; r++) {
    int i = i0 + r;
#pragma unroll
    for (int c = 0; c < 4; c++) {
      int j = j0 + c;
      int dd = i > j ? i - j : j - i;
      float v = acc[r][c] * pw[dd];
      rs[r] += v;
      colv[c][r] = v;
    }
  }
#pragma unroll
  for (int c = 0; c < 4; c++)
    *(float4*)&KtA[j0 + c][i0] = make_float4(colv[c][0], colv[c][1], colv[c][2], colv[c][3]);
#pragma unroll
  for (int r = 0; r < 4; r++) rowpart[i0 + r][tx] = rs[r];
  __syncthreads();
  float accY[4][4] = {}, accSf[4][4] = {}, accSb[4][4] = {};
  for (int j = 0; j < 64; j++) {
    float4 af = *(const float4*)&KtA[j][i0];
    float4 vf = *(const float4*)&Vs[j][e0];
    float aa[4] = {af.x, af.y, af.z, af.w};
    float vv[4] = {vf.x, vf.y, vf.z, vf.w};
#pragma unroll
    for (int r = 0; r < 4; r++)
#pragma unroll
      for (int c = 0; c < 4; c++) accY[r][c] += aa[r] * vv[c];
  }
  for (int d = 0; d < 64; d++) {
    float4 qf = *(const float4*)&Qt[d][i0];
    bf16x4 sf4 = *(const bf16x4*)&Spf[d][e0];
    bf16x4 sb4 = *(const bf16x4*)&Spb[d][e0];
    float qq[4] = {qf.x, qf.y, qf.z, qf.w};
    float sf[4] = {(float)sf4[0], (float)sf4[1], (float)sf4[2], (float)sf4[3]};
    float sb[4] = {(float)sb4[0], (float)sb4[1], (float)sb4[2], (float)sb4[3]};
#pragma unroll
    for (int r = 0; r < 4; r++)
#pragma unroll
      for (int c = 0; c < 4; c++) {
        accSf[r][c] += qq[r] * sf[c];
        accSb[r][c] += qq[r] * sb[c];
      }
  }
  if (tid < 64) {
    int i = tid;
    float s = 0.f;
#pragma unroll
    for (int xx = 0; xx < 16; xx++) s += rowpart[i][xx];
    float czf = 0.f, czb = 0.f;
    for (int d = 0; d < 64; d++) { czf += Qt[d][i] * zpf[d]; czb += Qt[d][i] * zpb[d]; }
    den[i] = s + pw[i + 1] * czf + pw[64 - i] * czb;
  }
  __syncthreads();
#pragma unroll
  for (int r = 0; r < 4; r++) {
    int i = i0 + r;
    float lrf = pw[i + 1], lrb = pw[64 - i];
    float inv = 1.f / fmaxf(den[i], 1e-6f);
    bf16x4 o;
#pragma unroll
    for (int c = 0; c < 4; c++)
      o[c] = (bf16_t)((accY[r][c] + lrf * accSf[r][c] + lrb * accSb[r][c]) * inv);
    *(bf16x4*)(attnb + ((size_t)(b * TT + t0 + i)) * DD + (size_t)h * 64 + e0) = o;
  }
}

// ---------------------------------------------------------------- launch
extern "C" void kernel_launch(void* const* d_in, const int* in_sizes, int n_in,
                              void* d_out, int out_size, void* d_ws, size_t ws_size,
                              hipStream_t stream) {
  const float* x   = (const float*)d_in[0];
  const unsigned char* mask = (const unsigned char*)d_in[1];
  const float* Wq  = (const float*)d_in[2];
  const float* Wk  = (const float*)d_in[3];
  const float* Wv  = (const float*)d_in[4];
  const float* Wo  = (const float*)d_in[5];
  const float* bo  = (const float*)d_in[6];
  const float* g1  = (const float*)d_in[7];
  const float* b1  = (const float*)d_in[8];
  const float* g2  = (const float*)d_in[9];
  const float* b2  = (const float*)d_in[10];
  const float* W1  = (const float*)d_in[11];
  const float* bf1 = (const float*)d_in[12];
  const float* W2  = (const float*)d_in[13];
  const float* bf2 = (const float*)d_in[14];
  const float* dl  = (const float*)d_in[15];
  float* out = (float*)d_out;

  float* ws = (float*)d_ws;
  const size_t U = (size_t)BT * DD;  // 2097152 floats
  float* Qr  = ws;
  float* Kr  = ws + U;
  float* Vr  = ws + 2 * U;
  float* R3  = ws + 3 * U;
  float* R4  = ws + 4 * U;
  float* x2  = ws + 5 * U;
  bf16_t* Sstb = (bf16_t*)(ws + 6 * U);
  float* zst = ws + 8 * U;
  bf16_t* wall = (bf16_t*)(ws + 8 * U + 131072);
  bf16_t* Qb    = (bf16_t*)Qr;
  bf16_t* Kb    = (bf16_t*)Kr;
  bf16_t* Vb    = (bf16_t*)Vr;
  bf16_t* xnb   = (bf16_t*)R3;
  bf16_t* attnb = (bf16_t*)x2;
  bf16_t* h2b   = (bf16_t*)Qr;
  bf16_t* ffn1b = (bf16_t*)Kr;
  bf16_t* Wob = wall + 786432;
  bf16_t* W1b = wall + 1048576;
  bf16_t* W2b = wall + 2097152;
  float* Ps0 = R3;
  float* Ps1 = R4;

  ln_cast_kernel<<<BT + 1536, 256, 0, stream>>>(x, g1, b1, xnb, Wq, Wk, Wv, Wo, W1, W2, wall);
  mfma_gemm<0><<<384, 256, 0, stream>>>(xnb, wall, 512, 12, Qb, Kb, Vb,
                                        nullptr, nullptr, mask);
  chunk_summary_kernel<<<dim3(NC, 16), 256, 0, stream>>>(Kb, Vb, dl, Sstb, zst);
  scan_kernel<<<dim3(16, 2), 1024, 0, stream>>>(Sstb, zst, dl);
  chunk_attn_kernel<<<dim3(NC, 16), 256, 0, stream>>>(Qb, Kb, Vb, Sstb, zst, dl, attnb);
  mfma_gemm_pk<256><<<dim3(256, 2), 256, 0, stream>>>(attnb, Wob, 512, Ps0, Ps1);
  reduce_ln_kernel<<<BT, 256, 0, stream>>>(Ps0, Ps1, bo, x, x2, g2, b2, h2b);
  mfma_gemm<2><<<512, 256, 0, stream>>>(h2b, W1b, 512, 16, nullptr, nullptr, nullptr,
                                        ffn1b, bf1, nullptr);
  mfma_gemm_pk<1024><<<dim3(256, 2), 256, 0, stream>>>(ffn1b, W2b, 2048, Ps0, Ps1);
  reduce2_kernel<<<2048, 256, 0, stream>>>(Ps0, Ps1, bf2, x2, out);
}

// Round 12
// 207.825 us; speedup vs baseline: 2.8329x; 1.0421x over previous
//
#include <hip/hip_runtime.h>
#include <math.h>

#define BB 2
#define TT 2048
#define DD 512
#define FF 2048
#define HH 8
#define BT 4096      // BB*TT
#define NC 32        // TT/64 chunks
#define CK 64        // chunk size

typedef __bf16 bf16_t;
typedef bf16_t bf16x8 __attribute__((ext_vector_type(8)));
typedef bf16_t bf16x4 __attribute__((ext_vector_type(4)));
typedef float f32x4 __attribute__((ext_vector_type(4)));

typedef const __attribute__((address_space(1))) void* gas_p;
typedef __attribute__((address_space(3))) void* las_p;

__device__ __forceinline__ void async16(const void* g, void* l) {
  __builtin_amdgcn_global_load_lds((gas_p)g, (las_p)l, 16, 0, 0);
}

#define PIPE_SYNC(vm) asm volatile("s_waitcnt lgkmcnt(0) vmcnt(" vm ")\n\ts_barrier" ::: "memory")

// ---------------------------------------------------------------- LN1 + weight cast fused
__global__ __launch_bounds__(256) void ln_cast_kernel(
    const float* __restrict__ x, const float* __restrict__ g, const float* __restrict__ bb,
    bf16_t* __restrict__ out,
    const float* __restrict__ Wq, const float* __restrict__ Wk,
    const float* __restrict__ Wv, const float* __restrict__ Wo,
    const float* __restrict__ W1, const float* __restrict__ W2,
    bf16_t* __restrict__ wdst) {
  int t = threadIdx.x;
  if (blockIdx.x >= BT) {
    size_t i = ((size_t)(blockIdx.x - BT) * 256 + t) * 8;
    const float* src; size_t off;
    if (i < 262144)       { src = Wq; off = i; }
    else if (i < 524288)  { src = Wk; off = i - 262144; }
    else if (i < 786432)  { src = Wv; off = i - 524288; }
    else if (i < 1048576) { src = Wo; off = i - 786432; }
    else if (i < 2097152) { src = W1; off = i - 1048576; }
    else                  { src = W2; off = i - 2097152; }
    float4 a = *(const float4*)(src + off);
    float4 b = *(const float4*)(src + off + 4);
    bf16x8 o;
    o[0] = (bf16_t)a.x; o[1] = (bf16_t)a.y; o[2] = (bf16_t)a.z; o[3] = (bf16_t)a.w;
    o[4] = (bf16_t)b.x; o[5] = (bf16_t)b.y; o[6] = (bf16_t)b.z; o[7] = (bf16_t)b.w;
    *(bf16x8*)(wdst + i) = o;
    return;
  }
  int row = blockIdx.x;
  const float* xr = x + (size_t)row * DD;
  float v0 = xr[t], v1 = xr[t + 256];
  float s = v0 + v1, sq = v0 * v0 + v1 * v1;
  for (int o = 32; o; o >>= 1) { s += __shfl_down(s, o); sq += __shfl_down(sq, o); }
  __shared__ float red[8];
  __shared__ float mv[2];
  int w = t >> 6;
  if ((t & 63) == 0) { red[w] = s; red[4 + w] = sq; }
  __syncthreads();
  if (t == 0) {
    float S = red[0] + red[1] + red[2] + red[3];
    float Q = red[4] + red[5] + red[6] + red[7];
    float m = S * (1.f / 512.f);
    float var = Q * (1.f / 512.f) - m * m;
    mv[0] = m; mv[1] = rsqrtf(var + 1e-5f);
  }
  __syncthreads();
  float m = mv[0], r = mv[1];
  out[(size_t)row * DD + t]       = (bf16_t)((v0 - m) * r * g[t] + bb[t]);
  out[(size_t)row * DD + t + 256] = (bf16_t)((v1 - m) * r * g[t + 256] + bb[t + 256]);
}

// ---------------------------------------------------------------- pipelined MFMA GEMM  C = A*B^T
template<int MODE>
__global__ __launch_bounds__(256) void mfma_gemm(
    const bf16_t* __restrict__ A, const bf16_t* __restrict__ B, int K, int NT,
    bf16_t* __restrict__ Qo, bf16_t* __restrict__ Ko, bf16_t* __restrict__ Vo,
    bf16_t* __restrict__ Ob, const float* __restrict__ bias,
    const unsigned char* __restrict__ mask) {
  __shared__ __align__(16) bf16_t smem[3 * 8192];
  int tid = threadIdx.x;
  int bid = blockIdx.x;
  int xcd = bid & 7;
  int tmp = bid >> 3;
  int nt = tmp % NT;
  int mt = (tmp / NT) * 8 + xcd;
  int n0 = nt * 128, m0 = mt * 128;
  int elt = tid * 8;
  int srow = elt >> 5, scol = elt & 31;
  const bf16_t* Ag = A + (size_t)(m0 + srow) * K + scol;
  const bf16_t* Bg = B + (size_t)(n0 + srow) * K + scol;
  size_t hstep = (size_t)64 * K;
  int NS = K >> 5;
#define ISSUE(s) { bf16_t* st = smem + ((s) % 3) * 8192; int k0 = (s) * 32; \
    async16(Ag + k0, st + elt); async16(Ag + k0 + hstep, st + 2048 + elt); \
    async16(Bg + k0, st + 4096 + elt); async16(Bg + k0 + hstep, st + 6144 + elt); }
  ISSUE(0); ISSUE(1);
  f32x4 acc[4][4] = {};
  int w = tid >> 6, l = tid & 63;
  int wm = (w >> 1) * 64, wn = (w & 1) * 64;
  int fr = l & 15, fk = (l >> 4) * 8;
  for (int i = 0; i < NS; i++) {
    if (i < NS - 1) PIPE_SYNC("4");
    else            PIPE_SYNC("0");
    if (i + 2 < NS) ISSUE(i + 2);
    const bf16_t* As = smem + (i % 3) * 8192;
    const bf16_t* Bs = As + 4096;
    bf16x8 af[4], bfr[4];
#pragma unroll
    for (int ii = 0; ii < 4; ii++) af[ii] = *(const bf16x8*)&As[(wm + ii * 16 + fr) * 32 + fk];
#pragma unroll
    for (int j = 0; j < 4; j++) bfr[j] = *(const bf16x8*)&Bs[(wn + j * 16 + fr) * 32 + fk];
#pragma unroll
    for (int ii = 0; ii < 4; ii++)
#pragma unroll
      for (int j = 0; j < 4; j++)
        acc[ii][j] = __builtin_amdgcn_mfma_f32_16x16x32_bf16(af[ii], bfr[j], acc[ii][j], 0, 0, 0);
  }
#undef ISSUE
  __syncthreads();
  const int CST = 136;
  int cn = l & 15, cr = (l >> 4) * 4;
  bf16_t* outp;
  int ldc, ncol0;
  if (MODE == 0) {
    int seg = n0 >> 9;
    outp = seg == 0 ? Qo : (seg == 1 ? Ko : Vo);
    ldc = 512; ncol0 = n0 & 511;
  } else {
    outp = Ob; ldc = 2048; ncol0 = n0;
  }
#pragma unroll
  for (int i = 0; i < 4; i++) {
#pragma unroll
    for (int r = 0; r < 4; r++) {
      int mrow = wm + i * 16 + cr + r;
      float p = 1.f;
      if (MODE == 0) p = mask[m0 + mrow] ? 0.f : 1.f;
#pragma unroll
      for (int j = 0; j < 4; j++) {
        int ncol = wn + j * 16 + cn;
        float v = acc[i][j][r];
        float ov;
        if (MODE == 0) {
          int seg = n0 >> 9;
          float e = v > 0.f ? v + 1.f : expf(v);
          ov = seg == 0 ? e : (seg == 1 ? e * p : v * p);
        } else {
          float t2 = v + bias[ncol0 + ncol];
          ov = 0.5f * t2 * (1.f + erff(t2 * 0.70710678118654752f));
        }
        smem[mrow * CST + ncol] = (bf16_t)ov;
      }
    }
  }
  __syncthreads();
#pragma unroll
  for (int it = 0; it < 8; it++) {
    int vec = tid + it * 256;
    int row = vec >> 4;
    int col = (vec & 15) * 8;
    bf16x8 v8 = *(const bf16x8*)&smem[row * CST + col];
    *(bf16x8*)(outp + (size_t)(m0 + row) * ldc + ncol0 + col) = v8;
  }
}

// ---------------------------------------------------------------- pipelined split-K GEMM (N=512)
template<int KPER>
__global__ __launch_bounds__(256) void mfma_gemm_pk(
    const bf16_t* __restrict__ A, const bf16_t* __restrict__ B, int Kst,
    float* __restrict__ P0, float* __restrict__ P1) {
  __shared__ __align__(16) bf16_t smem[4 * 6144];
  int tid = threadIdx.x;
  int bid = blockIdx.x;
  int xcd = bid & 7;
  int tmp = bid >> 3;
  int nt = tmp & 7;
  int mt = (tmp >> 3) * 8 + xcd;
  int n0 = nt * 64, m0 = mt * 128;
  int kb = blockIdx.y * KPER;
  float* P = blockIdx.y ? P1 : P0;
  int elt = tid * 8;
  int arow = elt >> 5, acol = elt & 31;
  const bf16_t* Ag = A + (size_t)(m0 + arow) * Kst + acol;
  const bf16_t* Bg = B + (size_t)(n0 + arow) * Kst + acol;
  size_t hstep = (size_t)64 * Kst;
  const int NS = KPER >> 5;
#define ISSUE(s) { bf16_t* st = smem + ((s) & 3) * 6144; int k0 = kb + (s) * 32; \
    async16(Ag + k0, st + elt); async16(Ag + k0 + hstep, st + 2048 + elt); \
    async16(Bg + k0, st + 4096 + elt); }
  ISSUE(0); ISSUE(1); ISSUE(2);
  f32x4 acc[4][2] = {};
  int w = tid >> 6, l = tid & 63;
  int wm = (w >> 1) * 64, wn = (w & 1) * 32;
  int fr = l & 15, fk = (l >> 4) * 8;
  for (int i = 0; i < NS; i++) {
    int rem = NS - 1 - i;
    if (rem >= 2)      PIPE_SYNC("6");
    else if (rem == 1) PIPE_SYNC("3");
    else               PIPE_SYNC("0");
    if (i + 3 < NS) ISSUE(i + 3);
    const bf16_t* As = smem + (i & 3) * 6144;
    const bf16_t* Bs = As + 4096;
    bf16x8 af[4], bfr[2];
#pragma unroll
    for (int ii = 0; ii < 4; ii++) af[ii] = *(const bf16x8*)&As[(wm + ii * 16 + fr) * 32 + fk];
#pragma unroll
    for (int j = 0; j < 2; j++) bfr[j] = *(const bf16x8*)&Bs[(wn + j * 16 + fr) * 32 + fk];
#pragma unroll
    for (int ii = 0; ii < 4; ii++)
#pragma unroll
      for (int j = 0; j < 2; j++)
        acc[ii][j] = __builtin_amdgcn_mfma_f32_16x16x32_bf16(af[ii], bfr[j], acc[ii][j], 0, 0, 0);
  }
#undef ISSUE
  int cn = l & 15, cr = (l >> 4) * 4;
#pragma unroll
  for (int i = 0; i < 4; i++)
#pragma unroll
    for (int r = 0; r < 4; r++) {
      int m = m0 + wm + i * 16 + cr + r;
#pragma unroll
      for (int j = 0; j < 2; j++) {
        int n = n0 + wn + j * 16 + cn;
        P[(size_t)m * 512 + n] = acc[i][j][r];
      }
    }
}

// ---------------------------------------------------------------- reduce 2 partials + bias + resid (fp32 out)
__global__ __launch_bounds__(256) void reduce2_kernel(
    const float* __restrict__ P0, const float* __restrict__ P1,
    const float* __restrict__ bias, const float* __restrict__ resid,
    float* __restrict__ o) {
  size_t idx = ((size_t)blockIdx.x * 256 + threadIdx.x) * 4;
  int n = (int)(idx & 511);
  float4 a = *(const float4*)(P0 + idx);
  float4 b = *(const float4*)(P1 + idx);
  float4 rr = *(const float4*)(resid + idx);
  float4 bi = *(const float4*)(bias + n);
  *(float4*)(o + idx) = make_float4(a.x + b.x + bi.x + rr.x, a.y + b.y + bi.y + rr.y,
                                    a.z + b.z + bi.z + rr.z, a.w + b.w + bi.w + rr.w);
}

// ---------------------------------------------------------------- reduce2 + LayerNorm fused
__global__ __launch_bounds__(256) void reduce_ln_kernel(
    const float* __restrict__ P0, const float* __restrict__ P1,
    const float* __restrict__ bias, const float* __restrict__ resid,
    float* __restrict__ x2, const float* __restrict__ g, const float* __restrict__ bb,
    bf16_t* __restrict__ out) {
  int row = blockIdx.x;
  int t = threadIdx.x;
  size_t o0 = (size_t)row * DD + t;
  size_t o1 = o0 + 256;
  float v0 = P0[o0] + P1[o0] + bias[t] + resid[o0];
  float v1 = P0[o1] + P1[o1] + bias[t + 256] + resid[o1];
  x2[o0] = v0; x2[o1] = v1;
  float s = v0 + v1, sq = v0 * v0 + v1 * v1;
  for (int o = 32; o; o >>= 1) { s += __shfl_down(s, o); sq += __shfl_down(sq, o); }
  __shared__ float red[8];
  __shared__ float mv[2];
  int w = t >> 6;
  if ((t & 63) == 0) { red[w] = s; red[4 + w] = sq; }
  __syncthreads();
  if (t == 0) {
    float S = red[0] + red[1] + red[2] + red[3];
    float Q = red[4] + red[5] + red[6] + red[7];
    float m = S * (1.f / 512.f);
    float var = Q * (1.f / 512.f) - m * m;
    mv[0] = m; mv[1] = rsqrtf(var + 1e-5f);
  }
  __syncthreads();
  float m = mv[0], r = mv[1];
  out[o0] = (bf16_t)((v0 - m) * r * g[t] + bb[t]);
  out[o1] = (bf16_t)((v1 - m) * r * g[t + 256] + bb[t + 256]);
}

// ------------------------------------------------- Phase A: chunk summaries (bf16 in, TRANSPOSED bf16 state out)
// Stores S^T[e2][e1] (= sum_j w_j V[j][e2] K[j][e1]) so attn can read B-fragments row-major.
__global__ __launch_bounds__(256) void chunk_summary_kernel(
    const bf16_t* __restrict__ Kb, const bf16_t* __restrict__ Vb,
    const float* __restrict__ dl, bf16_t* __restrict__ Sst, float* __restrict__ zst) {
  int chunk = blockIdx.x, bh = blockIdx.y;
  int b = bh >> 3, h = bh & 7;
  int t0 = chunk * CK;
  int tid = threadIdx.x;
  __shared__ __align__(16) float Ks[64][64];
  __shared__ __align__(16) float Vs[64][64];
  __shared__ float pw[72];
  float lam = 1.f / (1.f + expf(-dl[h]));
  if (tid <= 64) pw[tid] = powf(lam, (float)tid);
  int lrow = tid >> 2, lq = tid & 3;
  for (int q = 0; q < 2; q++) {
    int c = lq * 16 + q * 8;
    size_t g = ((size_t)(b * TT + t0 + lrow)) * DD + (size_t)h * 64 + c;
    bf16x8 k8 = *(const bf16x8*)(Kb + g);
    bf16x8 v8 = *(const bf16x8*)(Vb + g);
#pragma unroll
    for (int u = 0; u < 8; u++) { Ks[lrow][c + u] = (float)k8[u]; Vs[lrow][c + u] = (float)v8[u]; }
  }
  __syncthreads();
  int e1 = tid & 63;
  int e2b = (tid >> 6) * 16;
  float af_[16], ab_[16];
#pragma unroll
  for (int r = 0; r < 16; r++) { af_[r] = 0.f; ab_[r] = 0.f; }
  float zf = 0.f, zb = 0.f;
  for (int j = 0; j < 64; j++) {
    float kj = Ks[j][e1];
    float kf = pw[63 - j] * kj;
    float kb2 = pw[j] * kj;
    if (tid < 64) { zf += kf; zb += kb2; }
#pragma unroll
    for (int rr = 0; rr < 16; rr += 4) {
      float4 v4 = *(const float4*)&Vs[j][e2b + rr];
      af_[rr]     += kf * v4.x;  ab_[rr]     += kb2 * v4.x;
      af_[rr + 1] += kf * v4.y;  ab_[rr + 1] += kb2 * v4.y;
      af_[rr + 2] += kf * v4.z;  ab_[rr + 2] += kb2 * v4.z;
      af_[rr + 3] += kf * v4.w;  ab_[rr + 3] += kb2 * v4.w;
    }
  }
  // transposed store: row = e2 (v-dim), col = e1 (k-dim); lane-contiguous in e1 -> coalesced
  size_t bfr = ((size_t)bh * NC + chunk) * 4096;
  size_t bbr = (((size_t)16 + bh) * NC + chunk) * 4096;
#pragma unroll
  for (int r = 0; r < 16; r++) {
    Sst[bfr + (size_t)(e2b + r) * 64 + e1] = (bf16_t)af_[r];
    Sst[bbr + (size_t)(e2b + r) * 64 + e1] = (bf16_t)ab_[r];
  }
  if (tid < 64) {
    zst[((size_t)bh * NC + chunk) * 64 + tid] = zf;
    zst[(((size_t)16 + bh) * NC + chunk) * 64 + tid] = zb;
  }
}

// ------------------------------------------------- Phase B: scan over chunks (elementwise on 4096-state; layout-agnostic)
__global__ __launch_bounds__(1024) void scan_kernel(bf16_t* __restrict__ Sst,
                                                    float* __restrict__ zst,
                                                    const float* __restrict__ dl) {
  int bh = blockIdx.x, dir = blockIdx.y;
  int h = bh & 7;
  int tid = threadIdx.x;
  float lam = 1.f / (1.f + expf(-dl[h]));
  float lamC = powf(lam, 64.f);
  size_t base = ((size_t)dir * 16 + bh) * (size_t)NC * 4096 + (size_t)tid * 4;
  float s0 = 0.f, s1 = 0.f, s2 = 0.f, s3 = 0.f;
  for (int g = 0; g < 4; g++) {
    bf16x4 L[8];
#pragma unroll
    for (int i = 0; i < 8; i++) {
      int s = g * 8 + i;
      int c = dir ? (NC - 1 - s) : s;
      L[i] = *(bf16x4*)(Sst + base + (size_t)c * 4096);
    }
#pragma unroll
    for (int i = 0; i < 8; i++) {
      int s = g * 8 + i;
      int c = dir ? (NC - 1 - s) : s;
      s0 = s0 * lamC + (float)L[i][0];
      s1 = s1 * lamC + (float)L[i][1];
      s2 = s2 * lamC + (float)L[i][2];
      s3 = s3 * lamC + (float)L[i][3];
      bf16x4 o;
      o[0] = (bf16_t)s0; o[1] = (bf16_t)s1; o[2] = (bf16_t)s2; o[3] = (bf16_t)s3;
      *(bf16x4*)(Sst + base + (size_t)c * 4096) = o;
    }
  }
  if (tid < 64) {
    size_t zb = ((size_t)dir * 16 + bh) * (size_t)NC * 64 + tid;
    float z = 0.f;
    for (int g = 0; g < 4; g++) {
      float zL[8];
#pragma unroll
      for (int i = 0; i < 8; i++) {
        int s = g * 8 + i;
        int c = dir ? (NC - 1 - s) : s;
        zL[i] = zst[zb + (size_t)c * 64];
      }
#pragma unroll
      for (int i = 0; i < 8; i++) {
        int s = g * 8 + i;
        int c = dir ? (NC - 1 - s) : s;
        z = z * lamC + zL[i];
        zst[zb + (size_t)c * 64] = z;
      }
    }
  }
}

// ------------------------------------------------- Phase C: merged-direction chunk attention, MFMA
// A_sum[i][j] = (Q K^T)[i][j] * lam^|i-j|  (exact fwd+bwd merge). Four 64x64x64 matmuls on MFMA:
// qk = Q K^T, Y = A_sum V, Sf = Q Spf, Sb = Q Spb. Fragment layouts per working GEMM (m89/m91).
#define AST 72   // padded LDS stride (bf16): 16B-aligned rows, balanced bank classes
__global__ __launch_bounds__(256) void chunk_attn_kernel(
    const bf16_t* __restrict__ Qb, const bf16_t* __restrict__ Kb, const bf16_t* __restrict__ Vb,
    const bf16_t* __restrict__ Sst, const float* __restrict__ zst, const float* __restrict__ dl,
    bf16_t* __restrict__ attnb) {
  int chunk = blockIdx.x, bh = blockIdx.y;
  int b = bh >> 3, h = bh & 7;
  int t0 = chunk * CK;
  int tid = threadIdx.x;
  __shared__ __align__(16) bf16_t Qa[64 * AST];   // Q [i][d]
  __shared__ __align__(16) bf16_t KA[64 * AST];   // K [j][d], reused as A_sum [i][j]
  __shared__ __align__(16) bf16_t Vt[64 * AST];   // V^T [e][j]
  __shared__ __align__(16) bf16_t Sft[64 * AST];  // Spf^T [e][d]
  __shared__ __align__(16) bf16_t Sbt[64 * AST];  // Spb^T [e][d]
  __shared__ float rowpart[64][16];
  __shared__ float zpf[64], zpb[64];
  __shared__ float den[64];
  __shared__ float pw[72];
  float lam = 1.f / (1.f + expf(-dl[h]));
  if (tid <= 64) pw[tid] = powf(lam, (float)tid);
  int lrow = tid >> 2, lq = tid & 3;
  // stage Q/K row-major, V transposed
  for (int q = 0; q < 2; q++) {
    int c = lq * 16 + q * 8;
    size_t g = ((size_t)(b * TT + t0 + lrow)) * DD + (size_t)h * 64 + c;
    bf16x8 q8 = *(const bf16x8*)(Qb + g);
    bf16x8 k8 = *(const bf16x8*)(Kb + g);
    bf16x8 v8 = *(const bf16x8*)(Vb + g);
    *(bf16x8*)&Qa[lrow * AST + c] = q8;
    *(bf16x8*)&KA[lrow * AST + c] = k8;
#pragma unroll
    for (int u = 0; u < 8; u++) Vt[(c + u) * AST + lrow] = v8[u];
  }
  // stage transposed states (already stored transposed by summary)
  {
    int c16 = lq * 16;
    if (chunk > 0) {
      const bf16_t* src = Sst + ((size_t)bh * NC + chunk - 1) * 4096 + (size_t)lrow * 64 + c16;
      *(bf16x8*)&Sft[lrow * AST + c16] = *(const bf16x8*)src;
      *(bf16x8*)&Sft[lrow * AST + c16 + 8] = *(const bf16x8*)(src + 8);
      if (tid < 64) zpf[tid] = zst[((size_t)bh * NC + chunk - 1) * 64 + tid];
    } else {
      bf16x8 z8 = {};
      *(bf16x8*)&Sft[lrow * AST + c16] = z8;
      *(bf16x8*)&Sft[lrow * AST + c16 + 8] = z8;
      if (tid < 64) zpf[tid] = 0.f;
    }
    if (chunk < NC - 1) {
      const bf16_t* src = Sst + (((size_t)16 + bh) * NC + chunk + 1) * 4096 + (size_t)lrow * 64 + c16;
      *(bf16x8*)&Sbt[lrow * AST + c16] = *(const bf16x8*)src;
      *(bf16x8*)&Sbt[lrow * AST + c16 + 8] = *(const bf16x8*)(src + 8);
      if (tid < 64) zpb[tid] = zst[(((size_t)16 + bh) * NC + chunk + 1) * 64 + tid];
    } else {
      bf16x8 z8 = {};
      *(bf16x8*)&Sbt[lrow * AST + c16] = z8;
      *(bf16x8*)&Sbt[lrow * AST + c16 + 8] = z8;
      if (tid < 64) zpb[tid] = 0.f;
    }
  }
  __syncthreads();
  int w = tid >> 6, l = tid & 63;
  int fr = l & 15, fk = (l >> 4) * 8;    // A/B fragment indices
  int cr = (l >> 4) * 4, cn = l & 15;    // C fragment indices (m base, n)
  int ms = w * 16;                       // this wave's row strip
  // ---- qk = Q K^T (K=64 -> 2 MFMAs per 16x16 tile)
  bf16x8 qf0 = *(const bf16x8*)&Qa[(ms + fr) * AST + fk];
  bf16x8 qf1 = *(const bf16x8*)&Qa[(ms + fr) * AST + 32 + fk];
  f32x4 aqk[4] = {};
#pragma unroll
  for (int t = 0; t < 4; t++) {
    bf16x8 kf0 = *(const bf16x8*)&KA[(t * 16 + fr) * AST + fk];
    bf16x8 kf1 = *(const bf16x8*)&KA[(t * 16 + fr) * AST + 32 + fk];
    aqk[t] = __builtin_amdgcn_mfma_f32_16x16x32_bf16(qf0, kf0, aqk[t], 0, 0, 0);
    aqk[t] = __builtin_amdgcn_mfma_f32_16x16x32_bf16(qf1, kf1, aqk[t], 0, 0, 0);
  }
  __syncthreads();   // all K reads done; KA reusable as A_sum
  // ---- decay, rowsums, A_sum -> KA (bf16)
  float rs[4] = {0.f, 0.f, 0.f, 0.f};
#pragma unroll
  for (int t = 0; t < 4; t++) {
#pragma unroll
    for (int r = 0; r < 4; r++) {
      int i = ms + cr + r;
      int j = t * 16 + cn;
      int dd = i > j ? i - j : j - i;
      float v = aqk[t][r] * pw[dd];
      rs[r] += v;
      KA[i * AST + j] = (bf16_t)v;
    }
  }
#pragma unroll
  for (int r = 0; r < 4; r++) rowpart[ms + cr + r][cn] = rs[r];
  __syncthreads();   // A_sum + rowpart visible
  // ---- Y = A_sum V ; Sf = Q Spf ; Sb = Q Spb
  bf16x8 af0 = *(const bf16x8*)&KA[(ms + fr) * AST + fk];
  bf16x8 af1 = *(const bf16x8*)&KA[(ms + fr) * AST + 32 + fk];
  f32x4 aY[4] = {}, aSf[4] = {}, aSb[4] = {};
#pragma unroll
  for (int t = 0; t < 4; t++) {
    bf16x8 vf0 = *(const bf16x8*)&Vt[(t * 16 + fr) * AST + fk];
    bf16x8 vf1 = *(const bf16x8*)&Vt[(t * 16 + fr) * AST + 32 + fk];
    aY[t] = __builtin_amdgcn_mfma_f32_16x16x32_bf16(af0, vf0, aY[t], 0, 0, 0);
    aY[t] = __builtin_amdgcn_mfma_f32_16x16x32_bf16(af1, vf1, aY[t], 0, 0, 0);
    bf16x8 sf0 = *(const bf16x8*)&Sft[(t * 16 + fr) * AST + fk];
    bf16x8 sf1 = *(const bf16x8*)&Sft[(t * 16 + fr) * AST + 32 + fk];
    aSf[t] = __builtin_amdgcn_mfma_f32_16x16x32_bf16(qf0, sf0, aSf[t], 0, 0, 0);
    aSf[t] = __builtin_amdgcn_mfma_f32_16x16x32_bf16(qf1, sf1, aSf[t], 0, 0, 0);
    bf16x8 sb0 = *(const bf16x8*)&Sbt[(t * 16 + fr) * AST + fk];
    bf16x8 sb1 = *(const bf16x8*)&Sbt[(t * 16 + fr) * AST + 32 + fk];
    aSb[t] = __builtin_amdgcn_mfma_f32_16x16x32_bf16(qf0, sb0, aSb[t], 0, 0, 0);
    aSb[t] = __builtin_amdgcn_mfma_f32_16x16x32_bf16(qf1, sb1, aSb[t], 0, 0, 0);
  }
  // ---- den
  if (tid < 64) {
    int i = tid;
    float s = 0.f;
#pragma unroll
    for (int xx = 0; xx < 16; xx++) s += rowpart[i][xx];
    float czf = 0.f, czb = 0.f;
    for (int c = 0; c < 64; c += 8) {
      bf16x8 q8 = *(const bf16x8*)&Qa[i * AST + c];
#pragma unroll
      for (int u = 0; u < 8; u++) { czf += (float)q8[u] * zpf[c + u]; czb += (float)q8[u] * zpb[c + u]; }
    }
    den[i] = s + pw[i + 1] * czf + pw[64 - i] * czb;
  }
  __syncthreads();
  // ---- combine + write (C layout: row i = ms+cr+r, col e = t*16+cn)
#pragma unroll
  for (int t = 0; t < 4; t++) {
#pragma unroll
    for (int r = 0; r < 4; r++) {
      int i = ms + cr + r;
      int e = t * 16 + cn;
      float lrf = pw[i + 1], lrb = pw[64 - i];
      float inv = 1.f / fmaxf(den[i], 1e-6f);
      float val = (aY[t][r] + lrf * aSf[t][r] + lrb * aSb[t][r]) * inv;
      attnb[((size_t)(b * TT + t0 + i)) * DD + (size_t)h * 64 + e] = (bf16_t)val;
    }
  }
}

// ---------------------------------------------------------------- launch
extern "C" void kernel_launch(void* const* d_in, const int* in_sizes, int n_in,
                              void* d_out, int out_size, void* d_ws, size_t ws_size,
                              hipStream_t stream) {
  const float* x   = (const float*)d_in[0];
  const unsigned char* mask = (const unsigned char*)d_in[1];
  const float* Wq  = (const float*)d_in[2];
  const float* Wk  = (const float*)d_in[3];
  const float* Wv  = (const float*)d_in[4];
  const float* Wo  = (const float*)d_in[5];
  const float* bo  = (const float*)d_in[6];
  const float* g1  = (const float*)d_in[7];
  const float* b1  = (const float*)d_in[8];
  const float* g2  = (const float*)d_in[9];
  const float* b2  = (const float*)d_in[10];
  const float* W1  = (const float*)d_in[11];
  const float* bf1 = (const float*)d_in[12];
  const float* W2  = (const float*)d_in[13];
  const float* bf2 = (const float*)d_in[14];
  const float* dl  = (const float*)d_in[15];
  float* out = (float*)d_out;

  float* ws = (float*)d_ws;
  const size_t U = (size_t)BT * DD;  // 2097152 floats
  float* Qr  = ws;
  float* Kr  = ws + U;
  float* Vr  = ws + 2 * U;
  float* R3  = ws + 3 * U;
  float* R4  = ws + 4 * U;
  float* x2  = ws + 5 * U;
  bf16_t* Sstb = (bf16_t*)(ws + 6 * U);
  float* zst = ws + 8 * U;
  bf16_t* wall = (bf16_t*)(ws + 8 * U + 131072);
  bf16_t* Qb    = (bf16_t*)Qr;
  bf16_t* Kb    = (bf16_t*)Kr;
  bf16_t* Vb    = (bf16_t*)Vr;
  bf16_t* xnb   = (bf16_t*)R3;
  bf16_t* attnb = (bf16_t*)x2;
  bf16_t* h2b   = (bf16_t*)Qr;
  bf16_t* ffn1b = (bf16_t*)Kr;
  bf16_t* Wob = wall + 786432;
  bf16_t* W1b = wall + 1048576;
  bf16_t* W2b = wall + 2097152;
  float* Ps0 = R3;
  float* Ps1 = R4;

  ln_cast_kernel<<<BT + 1536, 256, 0, stream>>>(x, g1, b1, xnb, Wq, Wk, Wv, Wo, W1, W2, wall);
  mfma_gemm<0><<<384, 256, 0, stream>>>(xnb, wall, 512, 12, Qb, Kb, Vb,
                                        nullptr, nullptr, mask);
  chunk_summary_kernel<<<dim3(NC, 16), 256, 0, stream>>>(Kb, Vb, dl, Sstb, zst);
  scan_kernel<<<dim3(16, 2), 1024, 0, stream>>>(Sstb, zst, dl);
  chunk_attn_kernel<<<dim3(NC, 16), 256, 0, stream>>>(Qb, Kb, Vb, Sstb, zst, dl, attnb);
  mfma_gemm_pk<256><<<dim3(256, 2), 256, 0, stream>>>(attnb, Wob, 512, Ps0, Ps1);
  reduce_ln_kernel<<<BT, 256, 0, stream>>>(Ps0, Ps1, bo, x, x2, g2, b2, h2b);
  mfma_gemm<2><<<512, 256, 0, stream>>>(h2b, W1b, 512, 16, nullptr, nullptr, nullptr,
                                        ffn1b, bf1, nullptr);
  mfma_gemm_pk<1024><<<dim3(256, 2), 256, 0, stream>>>(ffn1b, W2b, 2048, Ps0, Ps1);
  reduce2_kernel<<<2048, 256, 0, stream>>>(Ps0, Ps1, bf2, x2, out);
}

// Round 13
// 198.934 us; speedup vs baseline: 2.9596x; 1.0447x over previous
//
#include <hip/hip_runtime.h>
#include <math.h>

#define BB 2
#define TT 2048
#define DD 512
#define FF 2048
#define HH 8
#define BT 4096      // BB*TT
#define NC 32        // TT/64 chunks
#define CK 64        // chunk size

typedef __bf16 bf16_t;
typedef bf16_t bf16x8 __attribute__((ext_vector_type(8)));
typedef bf16_t bf16x4 __attribute__((ext_vector_type(4)));
typedef float f32x4 __attribute__((ext_vector_type(4)));

typedef const __attribute__((address_space(1))) void* gas_p;
typedef __attribute__((address_space(3))) void* las_p;

__device__ __forceinline__ void async16(const void* g, void* l) {
  __builtin_amdgcn_global_load_lds((gas_p)g, (las_p)l, 16, 0, 0);
}

#define PIPE_SYNC(vm) asm volatile("s_waitcnt lgkmcnt(0) vmcnt(" vm ")\n\ts_barrier" ::: "memory")

// ---------------------------------------------------------------- LN1 + weight cast fused
__global__ __launch_bounds__(256) void ln_cast_kernel(
    const float* __restrict__ x, const float* __restrict__ g, const float* __restrict__ bb,
    bf16_t* __restrict__ out,
    const float* __restrict__ Wq, const float* __restrict__ Wk,
    const float* __restrict__ Wv, const float* __restrict__ Wo,
    const float* __restrict__ W1, const float* __restrict__ W2,
    bf16_t* __restrict__ wdst) {
  int t = threadIdx.x;
  if (blockIdx.x >= BT) {
    size_t i = ((size_t)(blockIdx.x - BT) * 256 + t) * 8;
    const float* src; size_t off;
    if (i < 262144)       { src = Wq; off = i; }
    else if (i < 524288)  { src = Wk; off = i - 262144; }
    else if (i < 786432)  { src = Wv; off = i - 524288; }
    else if (i < 1048576) { src = Wo; off = i - 786432; }
    else if (i < 2097152) { src = W1; off = i - 1048576; }
    else                  { src = W2; off = i - 2097152; }
    float4 a = *(const float4*)(src + off);
    float4 b = *(const float4*)(src + off + 4);
    bf16x8 o;
    o[0] = (bf16_t)a.x; o[1] = (bf16_t)a.y; o[2] = (bf16_t)a.z; o[3] = (bf16_t)a.w;
    o[4] = (bf16_t)b.x; o[5] = (bf16_t)b.y; o[6] = (bf16_t)b.z; o[7] = (bf16_t)b.w;
    *(bf16x8*)(wdst + i) = o;
    return;
  }
  int row = blockIdx.x;
  const float* xr = x + (size_t)row * DD;
  float v0 = xr[t], v1 = xr[t + 256];
  float s = v0 + v1, sq = v0 * v0 + v1 * v1;
  for (int o = 32; o; o >>= 1) { s += __shfl_down(s, o); sq += __shfl_down(sq, o); }
  __shared__ float red[8];
  __shared__ float mv[2];
  int w = t >> 6;
  if ((t & 63) == 0) { red[w] = s; red[4 + w] = sq; }
  __syncthreads();
  if (t == 0) {
    float S = red[0] + red[1] + red[2] + red[3];
    float Q = red[4] + red[5] + red[6] + red[7];
    float m = S * (1.f / 512.f);
    float var = Q * (1.f / 512.f) - m * m;
    mv[0] = m; mv[1] = rsqrtf(var + 1e-5f);
  }
  __syncthreads();
  float m = mv[0], r = mv[1];
  out[(size_t)row * DD + t]       = (bf16_t)((v0 - m) * r * g[t] + bb[t]);
  out[(size_t)row * DD + t + 256] = (bf16_t)((v1 - m) * r * g[t + 256] + bb[t + 256]);
}

// ---------------------------------------------------------------- pipelined MFMA GEMM  C = A*B^T
template<int MODE>
__global__ __launch_bounds__(256) void mfma_gemm(
    const bf16_t* __restrict__ A, const bf16_t* __restrict__ B, int K, int NT,
    bf16_t* __restrict__ Qo, bf16_t* __restrict__ Ko, bf16_t* __restrict__ Vo,
    bf16_t* __restrict__ Ob, const float* __restrict__ bias,
    const unsigned char* __restrict__ mask) {
  __shared__ __align__(16) bf16_t smem[3 * 8192];
  int tid = threadIdx.x;
  int bid = blockIdx.x;
  int xcd = bid & 7;
  int tmp = bid >> 3;
  int nt = tmp % NT;
  int mt = (tmp / NT) * 8 + xcd;
  int n0 = nt * 128, m0 = mt * 128;
  int elt = tid * 8;
  int srow = elt >> 5, scol = elt & 31;
  const bf16_t* Ag = A + (size_t)(m0 + srow) * K + scol;
  const bf16_t* Bg = B + (size_t)(n0 + srow) * K + scol;
  size_t hstep = (size_t)64 * K;
  int NS = K >> 5;
#define ISSUE(s) { bf16_t* st = smem + ((s) % 3) * 8192; int k0 = (s) * 32; \
    async16(Ag + k0, st + elt); async16(Ag + k0 + hstep, st + 2048 + elt); \
    async16(Bg + k0, st + 4096 + elt); async16(Bg + k0 + hstep, st + 6144 + elt); }
  ISSUE(0); ISSUE(1);
  f32x4 acc[4][4] = {};
  int w = tid >> 6, l = tid & 63;
  int wm = (w >> 1) * 64, wn = (w & 1) * 64;
  int fr = l & 15, fk = (l >> 4) * 8;
  for (int i = 0; i < NS; i++) {
    if (i < NS - 1) PIPE_SYNC("4");
    else            PIPE_SYNC("0");
    if (i + 2 < NS) ISSUE(i + 2);
    const bf16_t* As = smem + (i % 3) * 8192;
    const bf16_t* Bs = As + 4096;
    bf16x8 af[4], bfr[4];
#pragma unroll
    for (int ii = 0; ii < 4; ii++) af[ii] = *(const bf16x8*)&As[(wm + ii * 16 + fr) * 32 + fk];
#pragma unroll
    for (int j = 0; j < 4; j++) bfr[j] = *(const bf16x8*)&Bs[(wn + j * 16 + fr) * 32 + fk];
#pragma unroll
    for (int ii = 0; ii < 4; ii++)
#pragma unroll
      for (int j = 0; j < 4; j++)
        acc[ii][j] = __builtin_amdgcn_mfma_f32_16x16x32_bf16(af[ii], bfr[j], acc[ii][j], 0, 0, 0);
  }
#undef ISSUE
  __syncthreads();
  const int CST = 136;
  int cn = l & 15, cr = (l >> 4) * 4;
  bf16_t* outp;
  int ldc, ncol0;
  if (MODE == 0) {
    int seg = n0 >> 9;
    outp = seg == 0 ? Qo : (seg == 1 ? Ko : Vo);
    ldc = 512; ncol0 = n0 & 511;
  } else {
    outp = Ob; ldc = 2048; ncol0 = n0;
  }
#pragma unroll
  for (int i = 0; i < 4; i++) {
#pragma unroll
    for (int r = 0; r < 4; r++) {
      int mrow = wm + i * 16 + cr + r;
      float p = 1.f;
      if (MODE == 0) p = mask[m0 + mrow] ? 0.f : 1.f;
#pragma unroll
      for (int j = 0; j < 4; j++) {
        int ncol = wn + j * 16 + cn;
        float v = acc[i][j][r];
        float ov;
        if (MODE == 0) {
          int seg = n0 >> 9;
          float e = v > 0.f ? v + 1.f : expf(v);
          ov = seg == 0 ? e : (seg == 1 ? e * p : v * p);
        } else {
          float t2 = v + bias[ncol0 + ncol];
          ov = 0.5f * t2 * (1.f + erff(t2 * 0.70710678118654752f));
        }
        smem[mrow * CST + ncol] = (bf16_t)ov;
      }
    }
  }
  __syncthreads();
#pragma unroll
  for (int it = 0; it < 8; it++) {
    int vec = tid + it * 256;
    int row = vec >> 4;
    int col = (vec & 15) * 8;
    bf16x8 v8 = *(const bf16x8*)&smem[row * CST + col];
    *(bf16x8*)(outp + (size_t)(m0 + row) * ldc + ncol0 + col) = v8;
  }
}

// ---------------------------------------------------------------- pipelined split-K GEMM (N=512), bf16 partials
template<int KPER>
__global__ __launch_bounds__(256) void mfma_gemm_pk(
    const bf16_t* __restrict__ A, const bf16_t* __restrict__ B, int Kst,
    bf16_t* __restrict__ P0, bf16_t* __restrict__ P1) {
  __shared__ __align__(16) bf16_t smem[4 * 6144];
  int tid = threadIdx.x;
  int bid = blockIdx.x;
  int xcd = bid & 7;
  int tmp = bid >> 3;
  int nt = tmp & 7;
  int mt = (tmp >> 3) * 8 + xcd;
  int n0 = nt * 64, m0 = mt * 128;
  int kb = blockIdx.y * KPER;
  bf16_t* P = blockIdx.y ? P1 : P0;
  int elt = tid * 8;
  int arow = elt >> 5, acol = elt & 31;
  const bf16_t* Ag = A + (size_t)(m0 + arow) * Kst + acol;
  const bf16_t* Bg = B + (size_t)(n0 + arow) * Kst + acol;
  size_t hstep = (size_t)64 * Kst;
  const int NS = KPER >> 5;
#define ISSUE(s) { bf16_t* st = smem + ((s) & 3) * 6144; int k0 = kb + (s) * 32; \
    async16(Ag + k0, st + elt); async16(Ag + k0 + hstep, st + 2048 + elt); \
    async16(Bg + k0, st + 4096 + elt); }
  ISSUE(0); ISSUE(1); ISSUE(2);
  f32x4 acc[4][2] = {};
  int w = tid >> 6, l = tid & 63;
  int wm = (w >> 1) * 64, wn = (w & 1) * 32;
  int fr = l & 15, fk = (l >> 4) * 8;
  for (int i = 0; i < NS; i++) {
    int rem = NS - 1 - i;
    if (rem >= 2)      PIPE_SYNC("6");
    else if (rem == 1) PIPE_SYNC("3");
    else               PIPE_SYNC("0");
    if (i + 3 < NS) ISSUE(i + 3);
    const bf16_t* As = smem + (i & 3) * 6144;
    const bf16_t* Bs = As + 4096;
    bf16x8 af[4], bfr[2];
#pragma unroll
    for (int ii = 0; ii < 4; ii++) af[ii] = *(const bf16x8*)&As[(wm + ii * 16 + fr) * 32 + fk];
#pragma unroll
    for (int j = 0; j < 2; j++) bfr[j] = *(const bf16x8*)&Bs[(wn + j * 16 + fr) * 32 + fk];
#pragma unroll
    for (int ii = 0; ii < 4; ii++)
#pragma unroll
      for (int j = 0; j < 2; j++)
        acc[ii][j] = __builtin_amdgcn_mfma_f32_16x16x32_bf16(af[ii], bfr[j], acc[ii][j], 0, 0, 0);
  }
#undef ISSUE
  __syncthreads();   // all fragment reads done; smem reusable for C staging
  const int PST = 72;   // bf16 stride for 128x64 C tile (18.4 KB)
  int cn = l & 15, cr = (l >> 4) * 4;
#pragma unroll
  for (int i = 0; i < 4; i++)
#pragma unroll
    for (int r = 0; r < 4; r++) {
      int mrow = wm + i * 16 + cr + r;
#pragma unroll
      for (int j = 0; j < 2; j++) {
        int ncol = wn + j * 16 + cn;
        smem[mrow * PST + ncol] = (bf16_t)acc[i][j][r];
      }
    }
  __syncthreads();
  // coalesced copy-out: 128x64 = 1024 bf16x8 vectors, 4 per thread
#pragma unroll
  for (int it = 0; it < 4; it++) {
    int vec = tid + it * 256;
    int row = vec >> 3;
    int col = (vec & 7) * 8;
    bf16x8 v8 = *(const bf16x8*)&smem[row * PST + col];
    *(bf16x8*)(P + (size_t)(m0 + row) * 512 + n0 + col) = v8;
  }
}

// ---------------------------------------------------------------- reduce 2 bf16 partials + bias + resid (fp32 out)
__global__ __launch_bounds__(256) void reduce2_kernel(
    const bf16_t* __restrict__ P0, const bf16_t* __restrict__ P1,
    const float* __restrict__ bias, const float* __restrict__ resid,
    float* __restrict__ o) {
  size_t idx = ((size_t)blockIdx.x * 256 + threadIdx.x) * 4;
  int n = (int)(idx & 511);
  bf16x4 a4 = *(const bf16x4*)(P0 + idx);
  bf16x4 b4 = *(const bf16x4*)(P1 + idx);
  float4 rr = *(const float4*)(resid + idx);
  float4 bi = *(const float4*)(bias + n);
  *(float4*)(o + idx) = make_float4(
      (float)a4[0] + (float)b4[0] + bi.x + rr.x,
      (float)a4[1] + (float)b4[1] + bi.y + rr.y,
      (float)a4[2] + (float)b4[2] + bi.z + rr.z,
      (float)a4[3] + (float)b4[3] + bi.w + rr.w);
}

// ---------------------------------------------------------------- reduce2 + LayerNorm fused (bf16 partials)
__global__ __launch_bounds__(256) void reduce_ln_kernel(
    const bf16_t* __restrict__ P0, const bf16_t* __restrict__ P1,
    const float* __restrict__ bias, const float* __restrict__ resid,
    float* __restrict__ x2, const float* __restrict__ g, const float* __restrict__ bb,
    bf16_t* __restrict__ out) {
  int row = blockIdx.x;
  int t = threadIdx.x;
  size_t o0 = (size_t)row * DD + t;
  size_t o1 = o0 + 256;
  float v0 = (float)P0[o0] + (float)P1[o0] + bias[t] + resid[o0];
  float v1 = (float)P0[o1] + (float)P1[o1] + bias[t + 256] + resid[o1];
  x2[o0] = v0; x2[o1] = v1;
  float s = v0 + v1, sq = v0 * v0 + v1 * v1;
  for (int o = 32; o; o >>= 1) { s += __shfl_down(s, o); sq += __shfl_down(sq, o); }
  __shared__ float red[8];
  __shared__ float mv[2];
  int w = t >> 6;
  if ((t & 63) == 0) { red[w] = s; red[4 + w] = sq; }
  __syncthreads();
  if (t == 0) {
    float S = red[0] + red[1] + red[2] + red[3];
    float Q = red[4] + red[5] + red[6] + red[7];
    float m = S * (1.f / 512.f);
    float var = Q * (1.f / 512.f) - m * m;
    mv[0] = m; mv[1] = rsqrtf(var + 1e-5f);
  }
  __syncthreads();
  float m = mv[0], r = mv[1];
  out[o0] = (bf16_t)((v0 - m) * r * g[t] + bb[t]);
  out[o1] = (bf16_t)((v1 - m) * r * g[t + 256] + bb[t + 256]);
}

// ------------------------------------------------- Phase A: chunk summaries (bf16 in, TRANSPOSED bf16 state out)
__global__ __launch_bounds__(256) void chunk_summary_kernel(
    const bf16_t* __restrict__ Kb, const bf16_t* __restrict__ Vb,
    const float* __restrict__ dl, bf16_t* __restrict__ Sst, float* __restrict__ zst) {
  int chunk = blockIdx.x, bh = blockIdx.y;
  int b = bh >> 3, h = bh & 7;
  int t0 = chunk * CK;
  int tid = threadIdx.x;
  __shared__ __align__(16) float Ks[64][64];
  __shared__ __align__(16) float Vs[64][64];
  __shared__ float pw[72];
  float lam = 1.f / (1.f + expf(-dl[h]));
  if (tid <= 64) pw[tid] = powf(lam, (float)tid);
  int lrow = tid >> 2, lq = tid & 3;
  for (int q = 0; q < 2; q++) {
    int c = lq * 16 + q * 8;
    size_t g = ((size_t)(b * TT + t0 + lrow)) * DD + (size_t)h * 64 + c;
    bf16x8 k8 = *(const bf16x8*)(Kb + g);
    bf16x8 v8 = *(const bf16x8*)(Vb + g);
#pragma unroll
    for (int u = 0; u < 8; u++) { Ks[lrow][c + u] = (float)k8[u]; Vs[lrow][c + u] = (float)v8[u]; }
  }
  __syncthreads();
  int e1 = tid & 63;
  int e2b = (tid >> 6) * 16;
  float af_[16], ab_[16];
#pragma unroll
  for (int r = 0; r < 16; r++) { af_[r] = 0.f; ab_[r] = 0.f; }
  float zf = 0.f, zb = 0.f;
  for (int j = 0; j < 64; j++) {
    float kj = Ks[j][e1];
    float kf = pw[63 - j] * kj;
    float kb2 = pw[j] * kj;
    if (tid < 64) { zf += kf; zb += kb2; }
#pragma unroll
    for (int rr = 0; rr < 16; rr += 4) {
      float4 v4 = *(const float4*)&Vs[j][e2b + rr];
      af_[rr]     += kf * v4.x;  ab_[rr]     += kb2 * v4.x;
      af_[rr + 1] += kf * v4.y;  ab_[rr + 1] += kb2 * v4.y;
      af_[rr + 2] += kf * v4.z;  ab_[rr + 2] += kb2 * v4.z;
      af_[rr + 3] += kf * v4.w;  ab_[rr + 3] += kb2 * v4.w;
    }
  }
  size_t bfr = ((size_t)bh * NC + chunk) * 4096;
  size_t bbr = (((size_t)16 + bh) * NC + chunk) * 4096;
#pragma unroll
  for (int r = 0; r < 16; r++) {
    Sst[bfr + (size_t)(e2b + r) * 64 + e1] = (bf16_t)af_[r];
    Sst[bbr + (size_t)(e2b + r) * 64 + e1] = (bf16_t)ab_[r];
  }
  if (tid < 64) {
    zst[((size_t)bh * NC + chunk) * 64 + tid] = zf;
    zst[(((size_t)16 + bh) * NC + chunk) * 64 + tid] = zb;
  }
}

// ------------------------------------------------- Phase B: scan over chunks
__global__ __launch_bounds__(1024) void scan_kernel(bf16_t* __restrict__ Sst,
                                                    float* __restrict__ zst,
                                                    const float* __restrict__ dl) {
  int bh = blockIdx.x, dir = blockIdx.y;
  int h = bh & 7;
  int tid = threadIdx.x;
  float lam = 1.f / (1.f + expf(-dl[h]));
  float lamC = powf(lam, 64.f);
  size_t base = ((size_t)dir * 16 + bh) * (size_t)NC * 4096 + (size_t)tid * 4;
  float s0 = 0.f, s1 = 0.f, s2 = 0.f, s3 = 0.f;
  for (int g = 0; g < 4; g++) {
    bf16x4 L[8];
#pragma unroll
    for (int i = 0; i < 8; i++) {
      int s = g * 8 + i;
      int c = dir ? (NC - 1 - s) : s;
      L[i] = *(bf16x4*)(Sst + base + (size_t)c * 4096);
    }
#pragma unroll
    for (int i = 0; i < 8; i++) {
      int s = g * 8 + i;
      int c = dir ? (NC - 1 - s) : s;
      s0 = s0 * lamC + (float)L[i][0];
      s1 = s1 * lamC + (float)L[i][1];
      s2 = s2 * lamC + (float)L[i][2];
      s3 = s3 * lamC + (float)L[i][3];
      bf16x4 o;
      o[0] = (bf16_t)s0; o[1] = (bf16_t)s1; o[2] = (bf16_t)s2; o[3] = (bf16_t)s3;
      *(bf16x4*)(Sst + base + (size_t)c * 4096) = o;
    }
  }
  if (tid < 64) {
    size_t zb = ((size_t)dir * 16 + bh) * (size_t)NC * 64 + tid;
    float z = 0.f;
    for (int g = 0; g < 4; g++) {
      float zL[8];
#pragma unroll
      for (int i = 0; i < 8; i++) {
        int s = g * 8 + i;
        int c = dir ? (NC - 1 - s) : s;
        zL[i] = zst[zb + (size_t)c * 64];
      }
#pragma unroll
      for (int i = 0; i < 8; i++) {
        int s = g * 8 + i;
        int c = dir ? (NC - 1 - s) : s;
        z = z * lamC + zL[i];
        zst[zb + (size_t)c * 64] = z;
      }
    }
  }
}

// ------------------------------------------------- Phase C: merged-direction chunk attention, MFMA
#define AST 72
__global__ __launch_bounds__(256) void chunk_attn_kernel(
    const bf16_t* __restrict__ Qb, const bf16_t* __restrict__ Kb, const bf16_t* __restrict__ Vb,
    const bf16_t* __restrict__ Sst, const float* __restrict__ zst, const float* __restrict__ dl,
    bf16_t* __restrict__ attnb) {
  int chunk = blockIdx.x, bh = blockIdx.y;
  int b = bh >> 3, h = bh & 7;
  int t0 = chunk * CK;
  int tid = threadIdx.x;
  __shared__ __align__(16) bf16_t Qa[64 * AST];
  __shared__ __align__(16) bf16_t KA[64 * AST];
  __shared__ __align__(16) bf16_t Vt[64 * AST];
  __shared__ __align__(16) bf16_t Sft[64 * AST];
  __shared__ __align__(16) bf16_t Sbt[64 * AST];
  __shared__ float rowpart[64][16];
  __shared__ float zpf[64], zpb[64];
  __shared__ float den[64];
  __shared__ float pw[72];
  float lam = 1.f / (1.f + expf(-dl[h]));
  if (tid <= 64) pw[tid] = powf(lam, (float)tid);
  int lrow = tid >> 2, lq = tid & 3;
  for (int q = 0; q < 2; q++) {
    int c = lq * 16 + q * 8;
    size_t g = ((size_t)(b * TT + t0 + lrow)) * DD + (size_t)h * 64 + c;
    bf16x8 q8 = *(const bf16x8*)(Qb + g);
    bf16x8 k8 = *(const bf16x8*)(Kb + g);
    bf16x8 v8 = *(const bf16x8*)(Vb + g);
    *(bf16x8*)&Qa[lrow * AST + c] = q8;
    *(bf16x8*)&KA[lrow * AST + c] = k8;
#pragma unroll
    for (int u = 0; u < 8; u++) Vt[(c + u) * AST + lrow] = v8[u];
  }
  {
    int c16 = lq * 16;
    if (chunk > 0) {
      const bf16_t* src = Sst + ((size_t)bh * NC + chunk - 1) * 4096 + (size_t)lrow * 64 + c16;
      *(bf16x8*)&Sft[lrow * AST + c16] = *(const bf16x8*)src;
      *(bf16x8*)&Sft[lrow * AST + c16 + 8] = *(const bf16x8*)(src + 8);
      if (tid < 64) zpf[tid] = zst[((size_t)bh * NC + chunk - 1) * 64 + tid];
    } else {
      bf16x8 z8 = {};
      *(bf16x8*)&Sft[lrow * AST + c16] = z8;
      *(bf16x8*)&Sft[lrow * AST + c16 + 8] = z8;
      if (tid < 64) zpf[tid] = 0.f;
    }
    if (chunk < NC - 1) {
      const bf16_t* src = Sst + (((size_t)16 + bh) * NC + chunk + 1) * 4096 + (size_t)lrow * 64 + c16;
      *(bf16x8*)&Sbt[lrow * AST + c16] = *(const bf16x8*)src;
      *(bf16x8*)&Sbt[lrow * AST + c16 + 8] = *(const bf16x8*)(src + 8);
      if (tid < 64) zpb[tid] = zst[(((size_t)16 + bh) * NC + chunk + 1) * 64 + tid];
    } else {
      bf16x8 z8 = {};
      *(bf16x8*)&Sbt[lrow * AST + c16] = z8;
      *(bf16x8*)&Sbt[lrow * AST + c16 + 8] = z8;
      if (tid < 64) zpb[tid] = 0.f;
    }
  }
  __syncthreads();
  int w = tid >> 6, l = tid & 63;
  int fr = l & 15, fk = (l >> 4) * 8;
  int cr = (l >> 4) * 4, cn = l & 15;
  int ms = w * 16;
  bf16x8 qf0 = *(const bf16x8*)&Qa[(ms + fr) * AST + fk];
  bf16x8 qf1 = *(const bf16x8*)&Qa[(ms + fr) * AST + 32 + fk];
  f32x4 aqk[4] = {};
#pragma unroll
  for (int t = 0; t < 4; t++) {
    bf16x8 kf0 = *(const bf16x8*)&KA[(t * 16 + fr) * AST + fk];
    bf16x8 kf1 = *(const bf16x8*)&KA[(t * 16 + fr) * AST + 32 + fk];
    aqk[t] = __builtin_amdgcn_mfma_f32_16x16x32_bf16(qf0, kf0, aqk[t], 0, 0, 0);
    aqk[t] = __builtin_amdgcn_mfma_f32_16x16x32_bf16(qf1, kf1, aqk[t], 0, 0, 0);
  }
  __syncthreads();
  float rs[4] = {0.f, 0.f, 0.f, 0.f};
#pragma unroll
  for (int t = 0; t < 4; t++) {
#pragma unroll
    for (int r = 0; r < 4; r++) {
      int i = ms + cr + r;
      int j = t * 16 + cn;
      int dd = i > j ? i - j : j - i;
      float v = aqk[t][r] * pw[dd];
      rs[r] += v;
      KA[i * AST + j] = (bf16_t)v;
    }
  }
#pragma unroll
  for (int r = 0; r < 4; r++) rowpart[ms + cr + r][cn] = rs[r];
  __syncthreads();
  bf16x8 af0 = *(const bf16x8*)&KA[(ms + fr) * AST + fk];
  bf16x8 af1 = *(const bf16x8*)&KA[(ms + fr) * AST + 32 + fk];
  f32x4 aY[4] = {}, aSf[4] = {}, aSb[4] = {};
#pragma unroll
  for (int t = 0; t < 4; t++) {
    bf16x8 vf0 = *(const bf16x8*)&Vt[(t * 16 + fr) * AST + fk];
    bf16x8 vf1 = *(const bf16x8*)&Vt[(t * 16 + fr) * AST + 32 + fk];
    aY[t] = __builtin_amdgcn_mfma_f32_16x16x32_bf16(af0, vf0, aY[t], 0, 0, 0);
    aY[t] = __builtin_amdgcn_mfma_f32_16x16x32_bf16(af1, vf1, aY[t], 0, 0, 0);
    bf16x8 sf0 = *(const bf16x8*)&Sft[(t * 16 + fr) * AST + fk];
    bf16x8 sf1 = *(const bf16x8*)&Sft[(t * 16 + fr) * AST + 32 + fk];
    aSf[t] = __builtin_amdgcn_mfma_f32_16x16x32_bf16(qf0, sf0, aSf[t], 0, 0, 0);
    aSf[t] = __builtin_amdgcn_mfma_f32_16x16x32_bf16(qf1, sf1, aSf[t], 0, 0, 0);
    bf16x8 sb0 = *(const bf16x8*)&Sbt[(t * 16 + fr) * AST + fk];
    bf16x8 sb1 = *(const bf16x8*)&Sbt[(t * 16 + fr) * AST + 32 + fk];
    aSb[t] = __builtin_amdgcn_mfma_f32_16x16x32_bf16(qf0, sb0, aSb[t], 0, 0, 0);
    aSb[t] = __builtin_amdgcn_mfma_f32_16x16x32_bf16(qf1, sb1, aSb[t], 0, 0, 0);
  }
  if (tid < 64) {
    int i = tid;
    float s = 0.f;
#pragma unroll
    for (int xx = 0; xx < 16; xx++) s += rowpart[i][xx];
    float czf = 0.f, czb = 0.f;
    for (int c = 0; c < 64; c += 8) {
      bf16x8 q8 = *(const bf16x8*)&Qa[i * AST + c];
#pragma unroll
      for (int u = 0; u < 8; u++) { czf += (float)q8[u] * zpf[c + u]; czb += (float)q8[u] * zpb[c + u]; }
    }
    den[i] = s + pw[i + 1] * czf + pw[64 - i] * czb;
  }
  __syncthreads();
#pragma unroll
  for (int t = 0; t < 4; t++) {
#pragma unroll
    for (int r = 0; r < 4; r++) {
      int i = ms + cr + r;
      int e = t * 16 + cn;
      float lrf = pw[i + 1], lrb = pw[64 - i];
      float inv = 1.f / fmaxf(den[i], 1e-6f);
      float val = (aY[t][r] + lrf * aSf[t][r] + lrb * aSb[t][r]) * inv;
      attnb[((size_t)(b * TT + t0 + i)) * DD + (size_t)h * 64 + e] = (bf16_t)val;
    }
  }
}

// ---------------------------------------------------------------- launch
extern "C" void kernel_launch(void* const* d_in, const int* in_sizes, int n_in,
                              void* d_out, int out_size, void* d_ws, size_t ws_size,
                              hipStream_t stream) {
  const float* x   = (const float*)d_in[0];
  const unsigned char* mask = (const unsigned char*)d_in[1];
  const float* Wq  = (const float*)d_in[2];
  const float* Wk  = (const float*)d_in[3];
  const float* Wv  = (const float*)d_in[4];
  const float* Wo  = (const float*)d_in[5];
  const float* bo  = (const float*)d_in[6];
  const float* g1  = (const float*)d_in[7];
  const float* b1  = (const float*)d_in[8];
  const float* g2  = (const float*)d_in[9];
  const float* b2  = (const float*)d_in[10];
  const float* W1  = (const float*)d_in[11];
  const float* bf1 = (const float*)d_in[12];
  const float* W2  = (const float*)d_in[13];
  const float* bf2 = (const float*)d_in[14];
  const float* dl  = (const float*)d_in[15];
  float* out = (float*)d_out;

  float* ws = (float*)d_ws;
  const size_t U = (size_t)BT * DD;  // 2097152 floats
  float* Qr  = ws;
  float* Kr  = ws + U;
  float* Vr  = ws + 2 * U;
  float* R3  = ws + 3 * U;
  float* R4  = ws + 4 * U;
  float* x2  = ws + 5 * U;
  bf16_t* Sstb = (bf16_t*)(ws + 6 * U);
  float* zst = ws + 8 * U;
  bf16_t* wall = (bf16_t*)(ws + 8 * U + 131072);
  bf16_t* Qb    = (bf16_t*)Qr;
  bf16_t* Kb    = (bf16_t*)Kr;
  bf16_t* Vb    = (bf16_t*)Vr;
  bf16_t* xnb   = (bf16_t*)R3;
  bf16_t* attnb = (bf16_t*)x2;
  bf16_t* h2b   = (bf16_t*)Qr;
  bf16_t* ffn1b = (bf16_t*)Kr;
  bf16_t* Wob = wall + 786432;
  bf16_t* W1b = wall + 1048576;
  bf16_t* W2b = wall + 2097152;
  bf16_t* Ps0 = (bf16_t*)R3;    // xnb dead after QKV; 4MB bf16 each
  bf16_t* Ps1 = (bf16_t*)R4;

  ln_cast_kernel<<<BT + 1536, 256, 0, stream>>>(x, g1, b1, xnb, Wq, Wk, Wv, Wo, W1, W2, wall);
  mfma_gemm<0><<<384, 256, 0, stream>>>(xnb, wall, 512, 12, Qb, Kb, Vb,
                                        nullptr, nullptr, mask);
  chunk_summary_kernel<<<dim3(NC, 16), 256, 0, stream>>>(Kb, Vb, dl, Sstb, zst);
  scan_kernel<<<dim3(16, 2), 1024, 0, stream>>>(Sstb, zst, dl);
  chunk_attn_kernel<<<dim3(NC, 16), 256, 0, stream>>>(Qb, Kb, Vb, Sstb, zst, dl, attnb);
  mfma_gemm_pk<256><<<dim3(256, 2), 256, 0, stream>>>(attnb, Wob, 512, Ps0, Ps1);
  reduce_ln_kernel<<<BT, 256, 0, stream>>>(Ps0, Ps1, bo, x, x2, g2, b2, h2b);
  mfma_gemm<2><<<512, 256, 0, stream>>>(h2b, W1b, 512, 16, nullptr, nullptr, nullptr,
                                        ffn1b, bf1, nullptr);
  mfma_gemm_pk<1024><<<dim3(256, 2), 256, 0, stream>>>(ffn1b, W2b, 2048, Ps0, Ps1);
  reduce2_kernel<<<2048, 256, 0, stream>>>(Ps0, Ps1, bf2, x2, out);
}